// Round 1
// baseline (347.963 us; speedup 1.0000x reference)
//
#include <hip/hip_runtime.h>

#define EPSV 1e-5f
constexpr int CIN_  = 64;
constexpr int CMID_ = 32;
constexpr int COUT_ = 64;
constexpr int NPTS  = 16384;
constexpr int MGRID = 65536;
constexpr int ZD = 11, YD = 200, XD = 176;

// ---------------------------------------------------------------------------
// ws layout (bytes):
//   [0,    512)  accIn  : float[2][2][32]   (k, {sum,sumsq}, ch)
//   [512, 1536)  accOut : float[2][2][64]   (k, {sum,sumsq}, ch)
//   [1536, +4,194,304)      fraw : float[2][16384][32]
//   then  +4,194,560        fpad : float[2][16385][32]   (row 0 = zeros)
//   then  +9,216            pf   : float[8][32] ++ float[64][32]
//   then  +16,777,216       nf   : float[2][65536][32]
// total ~25.2 MB
// ---------------------------------------------------------------------------

// Stage A1: fraw[k] = features @ W_in[k]^T ; accumulate per-channel sum/sumsq
__global__ __launch_bounds__(256) void k_fin(const float* __restrict__ features,
                                             const float* __restrict__ Win,
                                             float* __restrict__ fraw,
                                             float* __restrict__ accIn) {
    int k = blockIdx.y;
    int t = threadIdx.x;
    int c = t & 31, pl = t >> 5;
    int pt = blockIdx.x * 8 + pl;
    const float* W  = Win + (k * CMID_ + c) * CIN_;
    const float* fr = features + pt * CIN_;
    float acc = 0.f;
#pragma unroll
    for (int i = 0; i < CIN_; ++i) acc += fr[i] * W[i];
    fraw[(k * NPTS + pt) * CMID_ + c] = acc;

    __shared__ float s[256], sq[256];
    s[t] = acc; sq[t] = acc * acc;
    __syncthreads();
    if (t < 128) { s[t] += s[t + 128]; sq[t] += sq[t + 128]; } __syncthreads();
    if (t < 64)  { s[t] += s[t + 64];  sq[t] += sq[t + 64];  } __syncthreads();
    if (t < 32) {
        float ssum = s[t] + s[t + 32];
        float ssq  = sq[t] + sq[t + 32];
        atomicAdd(&accIn[(k * 2 + 0) * 32 + c], ssum);
        atomicAdd(&accIn[(k * 2 + 1) * 32 + c], ssq);
    }
}

// Stage A2: fpad[k][0] = 0 ; fpad[k][p+1] = BN(fraw[k][p])
__global__ __launch_bounds__(256) void k_fpad(const float* __restrict__ fraw,
                                              const float* __restrict__ accIn,
                                              const float* __restrict__ g_in,
                                              const float* __restrict__ b_in,
                                              float* __restrict__ fpad) {
    int idx = blockIdx.x * 256 + threadIdx.x;
    if (idx >= 2 * (NPTS + 1) * CMID_) return;
    int c  = idx & 31;
    int rk = idx >> 5;                 // k*(NPTS+1) + row
    int k   = rk / (NPTS + 1);
    int row = rk % (NPTS + 1);
    float v = 0.f;
    if (row > 0) {
        float sum   = accIn[(k * 2 + 0) * 32 + c];
        float sumsq = accIn[(k * 2 + 1) * 32 + c];
        float mu  = sum / (float)NPTS;
        float var = sumsq / (float)NPTS - mu * mu;
        var = fmaxf(var, 0.f);
        float x = fraw[(k * NPTS + row - 1) * CMID_ + c];
        v = (x - mu) * rsqrtf(var + EPSV) * g_in[k * CMID_ + c] + b_in[k * CMID_ + c];
    }
    fpad[idx] = v;
}

// Stage B: pf[k] = BN_over_offsets(off_xyz @ W_pos[k]^T)
__global__ __launch_bounds__(256) void k_pf(const float* __restrict__ Wpos,
                                            const float* __restrict__ g_pos,
                                            const float* __restrict__ b_pos,
                                            float* __restrict__ pf) {
    __shared__ float praw[64 * 32];
    int t = threadIdx.x;
    int pfoff = 0;
    for (int k = 0; k < 2; ++k) {
        int r = k + 1, s = 2 * r, noff = s * s * s;
        for (int idx = t; idx < noff * 32; idx += 256) {
            int j = idx >> 5, c = idx & 31;
            int xi = j % s, yi = (j / s) % s, zi = j / (s * s);
            float xv = (float)(xi - r), yv = (float)(yi - r), zv = (float)(zi - r);
            const float* W = Wpos + (k * CMID_ + c) * 3;
            praw[idx] = xv * W[0] + yv * W[1] + zv * W[2];
        }
        __syncthreads();
        if (t < 32) {
            float sum = 0.f, sq = 0.f;
            for (int j = 0; j < noff; ++j) { float v = praw[j * 32 + t]; sum += v; sq += v * v; }
            float mu  = sum / (float)noff;
            float var = fmaxf(sq / (float)noff - mu * mu, 0.f);
            float rs  = rsqrtf(var + EPSV);
            float g = g_pos[k * CMID_ + t], b = b_pos[k * CMID_ + t];
            for (int j = 0; j < noff; ++j)
                pf[pfoff + j * 32 + t] = (praw[j * 32 + t] - mu) * rs * g + b;
        }
        __syncthreads();
        pfoff += noff * 32;
    }
}

// Stage C: nf[k][m][c] = max_j relu(fpad[k][vm[...]+1][c] + pf[k][j][c])
template <int R>
__global__ __launch_bounds__(256) void k_gather(const int* __restrict__ new_coords,
                                                const int* __restrict__ vm,
                                                const float* __restrict__ fpad_k,
                                                const float* __restrict__ pf_k,
                                                float* __restrict__ nf_k) {
    constexpr int S = 2 * R, NOFF = S * S * S;
    __shared__ float pfs[NOFF * 32];
    int t = threadIdx.x;
    for (int i = t; i < NOFF * 32; i += 256) pfs[i] = pf_k[i];
    __syncthreads();
    int c  = t & 31;
    int pt = blockIdx.x * 8 + (t >> 5);
    int b  = new_coords[pt * 4 + 0];
    int xc = new_coords[pt * 4 + 1];
    int yc = new_coords[pt * 4 + 2];
    int zc = new_coords[pt * 4 + 3];
    float best = 0.f;   // relu(...) >= 0 so init 0 is exact
#pragma unroll 4
    for (int j = 0; j < NOFF; ++j) {
        int xi = j & (S - 1), yi = (j >> (R == 1 ? 1 : 2)) & (S - 1), zi = j >> (R == 1 ? 2 : 4);
        // NOTE reference quirk: x-mesh offset is added to z coord, z-mesh to x coord
        int zq = zc + (xi - R); zq = zq < 0 ? 0 : (zq > ZD - 1 ? ZD - 1 : zq);
        int yq = yc + (yi - R); yq = yq < 0 ? 0 : (yq > YD - 1 ? YD - 1 : yq);
        int xq = xc + (zi - R); xq = xq < 0 ? 0 : (xq > XD - 1 ? XD - 1 : xq);
        int pidx = vm[((b * ZD + zq) * YD + yq) * XD + xq];
        float gf = fpad_k[(pidx + 1) * CMID_ + c];
        float v = gf + pfs[j * 32 + c];
        v = v > 0.f ? v : 0.f;
        best = v > best ? v : best;
    }
    nf_k[pt * CMID_ + c] = best;
}

// Stage D1: per-channel sum/sumsq of y = nf @ W_out[k]^T
__global__ __launch_bounds__(256) void k_out_stats(const float* __restrict__ nf_k,
                                                   const float* __restrict__ Wout_k,
                                                   float* __restrict__ accOut_k) {
    __shared__ float Ws[COUT_ * CMID_];
    __shared__ float nfs[4 * CMID_];
    int t = threadIdx.x;
    for (int i = t; i < COUT_ * CMID_; i += 256) Ws[i] = Wout_k[i];
    int c = t & 63, pl = t >> 6;
    float sum = 0.f, sq = 0.f;
    int base = blockIdx.x * 64;
    for (int it = 0; it < 16; ++it) {
        __syncthreads();
        if (t < 128) nfs[t] = nf_k[(base + it * 4) * CMID_ + t];
        __syncthreads();
        float y = 0.f;
#pragma unroll
        for (int i = 0; i < CMID_; ++i) y += nfs[pl * CMID_ + i] * Ws[c * CMID_ + i];
        sum += y; sq += y * y;
    }
    __shared__ float rs_[256], rq_[256];
    rs_[t] = sum; rq_[t] = sq;
    __syncthreads();
    if (t < 128) { rs_[t] += rs_[t + 128]; rq_[t] += rq_[t + 128]; } __syncthreads();
    if (t < 64) {
        float fs = rs_[t] + rs_[t + 64];
        float fq = rq_[t] + rq_[t + 64];
        atomicAdd(&accOut_k[c],      fs);
        atomicAdd(&accOut_k[64 + c], fq);
    }
}

// Stage D2: out[:, col_off + c] = relu(BN(nf @ W_out[k]^T))
__global__ __launch_bounds__(256) void k_out_write(const float* __restrict__ nf_k,
                                                   const float* __restrict__ Wout_k,
                                                   const float* __restrict__ accOut_k,
                                                   const float* __restrict__ g_out_k,
                                                   const float* __restrict__ b_out_k,
                                                   float* __restrict__ out, int col_off) {
    __shared__ float Ws[COUT_ * CMID_];
    __shared__ float nfs[4 * CMID_];
    int t = threadIdx.x;
    for (int i = t; i < COUT_ * CMID_; i += 256) Ws[i] = Wout_k[i];
    int c = t & 63, pl = t >> 6;
    float mu  = accOut_k[c] / (float)MGRID;
    float var = fmaxf(accOut_k[64 + c] / (float)MGRID - mu * mu, 0.f);
    float rs  = rsqrtf(var + EPSV);
    float g = g_out_k[c], bb = b_out_k[c];
    int base = blockIdx.x * 64;
    for (int it = 0; it < 16; ++it) {
        __syncthreads();
        if (t < 128) nfs[t] = nf_k[(base + it * 4) * CMID_ + t];
        __syncthreads();
        float y = 0.f;
#pragma unroll
        for (int i = 0; i < CMID_; ++i) y += nfs[pl * CMID_ + i] * Ws[c * CMID_ + i];
        float o = (y - mu) * rs * g + bb;
        o = o > 0.f ? o : 0.f;
        out[(base + it * 4 + pl) * 128 + col_off + c] = o;
    }
}

extern "C" void kernel_launch(void* const* d_in, const int* in_sizes, int n_in,
                              void* d_out, int out_size, void* d_ws, size_t ws_size,
                              hipStream_t stream) {
    const int*   new_coords = (const int*)d_in[4];
    const float* features   = (const float*)d_in[5];
    const int*   vm         = (const int*)d_in[6];
    const float* W_in  = (const float*)d_in[7];
    const float* g_in  = (const float*)d_in[8];
    const float* b_in  = (const float*)d_in[9];
    const float* W_pos = (const float*)d_in[10];
    const float* g_pos = (const float*)d_in[11];
    const float* b_pos = (const float*)d_in[12];
    const float* W_out = (const float*)d_in[13];
    const float* g_out = (const float*)d_in[14];
    const float* b_out = (const float*)d_in[15];
    float* out = (float*)d_out;

    char* ws = (char*)d_ws;
    float* accIn  = (float*)(ws);
    float* accOut = (float*)(ws + 512);
    size_t off = 1536;
    float* fraw = (float*)(ws + off); off += (size_t)2 * NPTS * CMID_ * 4;
    float* fpad = (float*)(ws + off); off += (size_t)2 * (NPTS + 1) * CMID_ * 4;
    float* pf   = (float*)(ws + off); off += (size_t)(8 + 64) * 32 * 4;
    float* nf   = (float*)(ws + off);

    hipMemsetAsync(ws, 0, 1536, stream);

    dim3 gA(NPTS / 8, 2);
    k_fin<<<gA, 256, 0, stream>>>(features, W_in, fraw, accIn);

    int totPad = 2 * (NPTS + 1) * CMID_;
    k_fpad<<<(totPad + 255) / 256, 256, 0, stream>>>(fraw, accIn, g_in, b_in, fpad);

    k_pf<<<1, 256, 0, stream>>>(W_pos, g_pos, b_pos, pf);

    k_gather<1><<<MGRID / 8, 256, 0, stream>>>(new_coords, vm, fpad, pf, nf);
    k_gather<2><<<MGRID / 8, 256, 0, stream>>>(new_coords, vm,
                                               fpad + (size_t)(NPTS + 1) * CMID_,
                                               pf + 8 * 32,
                                               nf + (size_t)MGRID * CMID_);

    k_out_stats<<<MGRID / 64, 256, 0, stream>>>(nf, W_out, accOut);
    k_out_stats<<<MGRID / 64, 256, 0, stream>>>(nf + (size_t)MGRID * CMID_,
                                                W_out + COUT_ * CMID_, accOut + 128);

    k_out_write<<<MGRID / 64, 256, 0, stream>>>(nf, W_out, accOut, g_out, b_out, out, 0);
    k_out_write<<<MGRID / 64, 256, 0, stream>>>(nf + (size_t)MGRID * CMID_,
                                                W_out + COUT_ * CMID_, accOut + 128,
                                                g_out + 64, b_out + 64, out, 64);
}

// Round 2
// 202.967 us; speedup vs baseline: 1.7144x; 1.7144x over previous
//
#include <hip/hip_runtime.h>

#define EPSV 1e-5f
constexpr int CIN_  = 64;
constexpr int CMID_ = 32;
constexpr int COUT_ = 64;
constexpr int NPTS  = 16384;
constexpr int MGRID = 65536;
constexpr int ZD = 11, YD = 200, XD = 176;

// ---------------------------------------------------------------------------
// ws layout (bytes), overlays exploit kernel ordering:
//   [0, 512)        ss_in  : float[2][2][32]  (scale, shift per k)
//   [512, 1536)     ss_out : float[2][2][64]
//   [1536, +4.19M)  fraw   : float[2][16384][32]      } pOut overlays fraw
//                   pOut   : float[2][1024][128] (1MB) } (fraw dead after k_fpad)
//   then +4.19M     fpad   : float[2][16385][32]
//   then +9216      pf     : float[8][32] ++ float[64][32]
//   then +16.78M    nf     : float[2][65536][32]      } pIn overlays nf head
//                   pIn    : float[2][512][64] (256KB)} (pIn dead before gather)
// total ~25.2 MB (same as round 1)
// ---------------------------------------------------------------------------

// Stage A1: fraw[k] = features @ W_in[k]^T ; per-block partial sum/sumsq
__global__ __launch_bounds__(256) void k_fin(const float* __restrict__ features,
                                             const float* __restrict__ Win,
                                             float* __restrict__ fraw,
                                             float* __restrict__ pIn) {
    __shared__ float Ws[32 * 65];
    __shared__ float Fs[32 * 65];
    __shared__ float s_[256], q_[256];
    int k = blockIdx.y;
    int t = threadIdx.x;
    int base_pt = blockIdx.x * 32;
    // coalesced staging, padded stride 65 -> conflict-free reads
    for (int idx = t; idx < 2048; idx += 256) {
        int r = idx >> 6, i = idx & 63;
        Ws[r * 65 + i] = Win[k * 2048 + idx];
        Fs[r * 65 + i] = features[base_pt * 64 + idx];
    }
    __syncthreads();
    int c = t & 31, pl = t >> 5;
    float ssum = 0.f, ssq = 0.f;
    for (int it = 0; it < 4; ++it) {
        int row = it * 8 + pl;
        float acc = 0.f;
#pragma unroll
        for (int i = 0; i < CIN_; ++i) acc += Fs[row * 65 + i] * Ws[c * 65 + i];
        fraw[((size_t)k * NPTS + base_pt + row) * CMID_ + c] = acc;
        ssum += acc; ssq += acc * acc;
    }
    s_[t] = ssum; q_[t] = ssq;
    __syncthreads();
    if (t < 128) { s_[t] += s_[t + 128]; q_[t] += q_[t + 128]; } __syncthreads();
    if (t < 64)  { s_[t] += s_[t + 64];  q_[t] += q_[t + 64];  } __syncthreads();
    if (t < 32) {
        float fs = s_[t] + s_[t + 32];
        float fq = q_[t] + q_[t + 32];
        float* pb = pIn + ((size_t)k * 512 + blockIdx.x) * 64;
        pb[t] = fs;
        pb[32 + t] = fq;
    }
}

// Reduce pIn -> scale/shift per (k, c)
__global__ __launch_bounds__(256) void k_reduce_in(const float* __restrict__ pIn,
                                                   const float* __restrict__ g_in,
                                                   const float* __restrict__ b_in,
                                                   float* __restrict__ ss_in) {
    __shared__ float sm[256];
    int t = threadIdx.x;
    float sum = 0.f;
    if (t < 128) {
        int k = t >> 6, cc = t & 63;
        for (int b = 0; b < 512; ++b) sum += pIn[((size_t)k * 512 + b) * 64 + cc];
    }
    sm[t] = sum;
    __syncthreads();
    if (t < 64) {
        int k = t >> 5, c = t & 31;
        float sv = sm[k * 64 + c];
        float sq = sm[k * 64 + 32 + c];
        float mu  = sv / (float)NPTS;
        float var = fmaxf(sq / (float)NPTS - mu * mu, 0.f);
        float rs  = rsqrtf(var + EPSV);
        float scale = g_in[k * CMID_ + c] * rs;
        float shift = b_in[k * CMID_ + c] - mu * scale;
        ss_in[k * 64 + c]      = scale;
        ss_in[k * 64 + 32 + c] = shift;
    }
}

// Stage A2: fpad[k][0]=0 ; fpad[k][p+1] = fraw*scale+shift
__global__ __launch_bounds__(256) void k_fpad(const float* __restrict__ fraw,
                                              const float* __restrict__ ss_in,
                                              float* __restrict__ fpad) {
    int idx = blockIdx.x * 256 + threadIdx.x;
    if (idx >= 2 * (NPTS + 1) * CMID_) return;
    int c  = idx & 31;
    int rk = idx >> 5;
    int k   = rk / (NPTS + 1);
    int row = rk % (NPTS + 1);
    float v = 0.f;
    if (row > 0) {
        float x = fraw[((size_t)k * NPTS + row - 1) * CMID_ + c];
        v = x * ss_in[k * 64 + c] + ss_in[k * 64 + 32 + c];
    }
    fpad[idx] = v;
}

// Stage B: pf[k] = BN_over_offsets(off_xyz @ W_pos[k]^T)
__global__ __launch_bounds__(256) void k_pf(const float* __restrict__ Wpos,
                                            const float* __restrict__ g_pos,
                                            const float* __restrict__ b_pos,
                                            float* __restrict__ pf) {
    __shared__ float praw[64 * 32];
    int t = threadIdx.x;
    int pfoff = 0;
    for (int k = 0; k < 2; ++k) {
        int r = k + 1, s = 2 * r, noff = s * s * s;
        for (int idx = t; idx < noff * 32; idx += 256) {
            int j = idx >> 5, c = idx & 31;
            int xi = j % s, yi = (j / s) % s, zi = j / (s * s);
            float xv = (float)(xi - r), yv = (float)(yi - r), zv = (float)(zi - r);
            const float* W = Wpos + (k * CMID_ + c) * 3;
            praw[idx] = xv * W[0] + yv * W[1] + zv * W[2];
        }
        __syncthreads();
        if (t < 32) {
            float sum = 0.f, sq = 0.f;
            for (int j = 0; j < noff; ++j) { float v = praw[j * 32 + t]; sum += v; sq += v * v; }
            float mu  = sum / (float)noff;
            float var = fmaxf(sq / (float)noff - mu * mu, 0.f);
            float rs  = rsqrtf(var + EPSV);
            float g = g_pos[k * CMID_ + t], b = b_pos[k * CMID_ + t];
            for (int j = 0; j < noff; ++j)
                pf[pfoff + j * 32 + t] = (praw[j * 32 + t] - mu) * rs * g + b;
        }
        __syncthreads();
        pfoff += noff * 32;
    }
}

// Stage C: nf[k][m][c] = max_j relu(fpad[k][vm[...]+1][c] + pf[k][j][c])
// 8 lanes x float4 per point, 32 points/block
template <int R>
__global__ __launch_bounds__(256) void k_gather(const int* __restrict__ new_coords,
                                                const int* __restrict__ vm,
                                                const float* __restrict__ fpad_k,
                                                const float* __restrict__ pf_k,
                                                float* __restrict__ nf_k) {
    constexpr int S = 2 * R, NOFF = S * S * S;
    __shared__ float pfs[NOFF * 32];
    int t = threadIdx.x;
    for (int i = t; i < NOFF * 32; i += 256) pfs[i] = pf_k[i];
    __syncthreads();
    int c4 = t & 7;
    int pt = blockIdx.x * 32 + (t >> 3);
    int4 cc = reinterpret_cast<const int4*>(new_coords)[pt];
    int b = cc.x, xc = cc.y, yc = cc.z, zc = cc.w;
    float4 best = make_float4(0.f, 0.f, 0.f, 0.f);
#pragma unroll 8
    for (int j = 0; j < NOFF; ++j) {
        int xi = j & (S - 1), yi = (j >> (R == 1 ? 1 : 2)) & (S - 1), zi = j >> (R == 1 ? 2 : 4);
        // reference quirk: x-mesh offset added to z coord, z-mesh to x coord
        int zq = zc + (xi - R); zq = zq < 0 ? 0 : (zq > ZD - 1 ? ZD - 1 : zq);
        int yq = yc + (yi - R); yq = yq < 0 ? 0 : (yq > YD - 1 ? YD - 1 : yq);
        int xq = xc + (zi - R); xq = xq < 0 ? 0 : (xq > XD - 1 ? XD - 1 : xq);
        int pidx = vm[((b * ZD + zq) * YD + yq) * XD + xq];
        float4 gf = reinterpret_cast<const float4*>(fpad_k + (size_t)(pidx + 1) * CMID_)[c4];
        const float4 pv = *reinterpret_cast<const float4*>(&pfs[j * 32 + c4 * 4]);
        float v0 = gf.x + pv.x; v0 = v0 > 0.f ? v0 : 0.f; best.x = v0 > best.x ? v0 : best.x;
        float v1 = gf.y + pv.y; v1 = v1 > 0.f ? v1 : 0.f; best.y = v1 > best.y ? v1 : best.y;
        float v2 = gf.z + pv.z; v2 = v2 > 0.f ? v2 : 0.f; best.z = v2 > best.z ? v2 : best.z;
        float v3 = gf.w + pv.w; v3 = v3 > 0.f ? v3 : 0.f; best.w = v3 > best.w ? v3 : best.w;
    }
    reinterpret_cast<float4*>(nf_k + (size_t)pt * CMID_)[c4] = best;
}

// Stage D1: per-block partial sum/sumsq of y = nf @ W_out[k]^T
__global__ __launch_bounds__(256) void k_out_stats(const float* __restrict__ nf_k,
                                                   const float* __restrict__ Wout_k,
                                                   float* __restrict__ pOut_k) {
    __shared__ float Wls[64 * 33];
    __shared__ float s_[256], q_[256];
    int t = threadIdx.x;
    for (int idx = t; idx < 2048; idx += 256) {
        int cc = idx >> 5, i = idx & 31;
        Wls[cc * 33 + i] = Wout_k[idx];
    }
    __syncthreads();
    int c = t & 63, pl = t >> 6;
    float w[32];
#pragma unroll
    for (int i = 0; i < 32; ++i) w[i] = Wls[c * 33 + i];
    int base = blockIdx.x * 64;
    float sum = 0.f, sq = 0.f;
    for (int it = 0; it < 16; ++it) {
        int pt = base + it * 4 + pl;
        const float4* nr = reinterpret_cast<const float4*>(nf_k + (size_t)pt * CMID_);
        float y = 0.f;
#pragma unroll
        for (int i4 = 0; i4 < 8; ++i4) {
            float4 v = nr[i4];
            y += v.x * w[i4 * 4] + v.y * w[i4 * 4 + 1] + v.z * w[i4 * 4 + 2] + v.w * w[i4 * 4 + 3];
        }
        sum += y; sq += y * y;
    }
    s_[t] = sum; q_[t] = sq;
    __syncthreads();
    if (t < 128) { s_[t] += s_[t + 128]; q_[t] += q_[t + 128]; } __syncthreads();
    if (t < 64) {
        float fs = s_[t] + s_[t + 64];
        float fq = q_[t] + q_[t + 64];
        pOut_k[blockIdx.x * 128 + t]      = fs;
        pOut_k[blockIdx.x * 128 + 64 + t] = fq;
    }
}

// Reduce pOut -> scale/shift per (k, c)
__global__ __launch_bounds__(256) void k_out_reduce(const float* __restrict__ pOut,
                                                    const float* __restrict__ g_out,
                                                    const float* __restrict__ b_out,
                                                    float* __restrict__ ss_out) {
    __shared__ float sm[256];
    int t = threadIdx.x;
    int k = t >> 7, cc = t & 127;
    float sum = 0.f;
    for (int b = 0; b < 1024; ++b) sum += pOut[((size_t)k * 1024 + b) * 128 + cc];
    sm[t] = sum;
    __syncthreads();
    if (t < 128) {
        int kk = t >> 6, c = t & 63;
        float sv = sm[kk * 128 + c];
        float sq = sm[kk * 128 + 64 + c];
        float mu  = sv / (float)MGRID;
        float var = fmaxf(sq / (float)MGRID - mu * mu, 0.f);
        float rs  = rsqrtf(var + EPSV);
        float scale = g_out[kk * COUT_ + c] * rs;
        float shift = b_out[kk * COUT_ + c] - mu * scale;
        ss_out[kk * 128 + c]      = scale;
        ss_out[kk * 128 + 64 + c] = shift;
    }
}

// Stage D2: out[:, col_off + c] = relu(y*scale + shift)
__global__ __launch_bounds__(256) void k_out_write(const float* __restrict__ nf_k,
                                                   const float* __restrict__ Wout_k,
                                                   const float* __restrict__ ss_out_k,
                                                   float* __restrict__ out, int col_off) {
    __shared__ float Wls[64 * 33];
    int t = threadIdx.x;
    for (int idx = t; idx < 2048; idx += 256) {
        int cc = idx >> 5, i = idx & 31;
        Wls[cc * 33 + i] = Wout_k[idx];
    }
    __syncthreads();
    int c = t & 63, pl = t >> 6;
    float w[32];
#pragma unroll
    for (int i = 0; i < 32; ++i) w[i] = Wls[c * 33 + i];
    float scale = ss_out_k[c], shift = ss_out_k[64 + c];
    int base = blockIdx.x * 64;
    for (int it = 0; it < 16; ++it) {
        int pt = base + it * 4 + pl;
        const float4* nr = reinterpret_cast<const float4*>(nf_k + (size_t)pt * CMID_);
        float y = 0.f;
#pragma unroll
        for (int i4 = 0; i4 < 8; ++i4) {
            float4 v = nr[i4];
            y += v.x * w[i4 * 4] + v.y * w[i4 * 4 + 1] + v.z * w[i4 * 4 + 2] + v.w * w[i4 * 4 + 3];
        }
        float o = y * scale + shift;
        o = o > 0.f ? o : 0.f;
        out[(size_t)pt * 128 + col_off + c] = o;
    }
}

extern "C" void kernel_launch(void* const* d_in, const int* in_sizes, int n_in,
                              void* d_out, int out_size, void* d_ws, size_t ws_size,
                              hipStream_t stream) {
    const int*   new_coords = (const int*)d_in[4];
    const float* features   = (const float*)d_in[5];
    const int*   vm         = (const int*)d_in[6];
    const float* W_in  = (const float*)d_in[7];
    const float* g_in  = (const float*)d_in[8];
    const float* b_in  = (const float*)d_in[9];
    const float* W_pos = (const float*)d_in[10];
    const float* g_pos = (const float*)d_in[11];
    const float* b_pos = (const float*)d_in[12];
    const float* W_out = (const float*)d_in[13];
    const float* g_out = (const float*)d_in[14];
    const float* b_out = (const float*)d_in[15];
    float* out = (float*)d_out;

    char* ws = (char*)d_ws;
    float* ss_in  = (float*)(ws);
    float* ss_out = (float*)(ws + 512);
    size_t off = 1536;
    float* fraw = (float*)(ws + off);
    float* pOut = (float*)(ws + off);            // overlays fraw (dead after k_fpad)
    off += (size_t)2 * NPTS * CMID_ * 4;
    float* fpad = (float*)(ws + off); off += (size_t)2 * (NPTS + 1) * CMID_ * 4;
    float* pf   = (float*)(ws + off); off += (size_t)(8 + 64) * 32 * 4;
    float* nf   = (float*)(ws + off);
    float* pIn  = (float*)(ws + off);            // overlays nf head (dead before gather)

    dim3 gA(NPTS / 32, 2);
    k_fin<<<gA, 256, 0, stream>>>(features, W_in, fraw, pIn);
    k_reduce_in<<<1, 256, 0, stream>>>(pIn, g_in, b_in, ss_in);

    int totPad = 2 * (NPTS + 1) * CMID_;
    k_fpad<<<(totPad + 255) / 256, 256, 0, stream>>>(fraw, ss_in, fpad);

    k_pf<<<1, 256, 0, stream>>>(W_pos, g_pos, b_pos, pf);

    k_gather<1><<<MGRID / 32, 256, 0, stream>>>(new_coords, vm, fpad, pf, nf);
    k_gather<2><<<MGRID / 32, 256, 0, stream>>>(new_coords, vm,
                                                fpad + (size_t)(NPTS + 1) * CMID_,
                                                pf + 8 * 32,
                                                nf + (size_t)MGRID * CMID_);

    k_out_stats<<<MGRID / 64, 256, 0, stream>>>(nf, W_out, pOut);
    k_out_stats<<<MGRID / 64, 256, 0, stream>>>(nf + (size_t)MGRID * CMID_,
                                                W_out + COUT_ * CMID_,
                                                pOut + (size_t)1024 * 128);
    k_out_reduce<<<1, 256, 0, stream>>>(pOut, g_out, b_out, ss_out);

    k_out_write<<<MGRID / 64, 256, 0, stream>>>(nf, W_out, ss_out, out, 0);
    k_out_write<<<MGRID / 64, 256, 0, stream>>>(nf + (size_t)MGRID * CMID_,
                                                W_out + COUT_ * CMID_,
                                                ss_out + 128, out, 64);
}

// Round 3
// 179.300 us; speedup vs baseline: 1.9407x; 1.1320x over previous
//
#include <hip/hip_runtime.h>

#define EPSV 1e-5f
constexpr int CIN_  = 64;
constexpr int CMID_ = 32;
constexpr int COUT_ = 64;
constexpr int NPTS  = 16384;
constexpr int MGRID = 65536;
constexpr int ZD = 11, YD = 200, XD = 176;
constexpr int NVOX = 2 * ZD * YD * XD;   // 774400

typedef _Float16 h2 __attribute__((ext_vector_type(2)));
struct alignas(16) H8 { h2 a, b, c, d; };

// ---------------------------------------------------------------------------
// ws layout (bytes):
//   [0, 512)     ss_in  : float[2][2][32]
//   [512, 1536)  ss_out : float[2][2][64]
//   1536         fraw   : float[2][16384][32] (4MB)   } pOut overlays (1MB)
//   +4,194,304   fpad_h : _Float16[2][16385][32] (2MB)
//   +2,097,280   pf     : float[8+64][32] (9216B)
//   +9,216       nf     : float[2][65536][32] (16.8MB) } pIn overlays (128KB)
//   +16,777,216  vm16   : short[774400] (1.5MB)
// total ~24.6 MB
// ---------------------------------------------------------------------------

// Compress voxel2point map to int16 (values in [-1, 16383])
__global__ __launch_bounds__(256) void k_vm16(const int* __restrict__ vm,
                                              short* __restrict__ vm16) {
    int i = blockIdx.x * 256 + threadIdx.x;          // handles 8 ints
    if (i >= NVOX / 8) return;
    int4 v0 = reinterpret_cast<const int4*>(vm)[i * 2];
    int4 v1 = reinterpret_cast<const int4*>(vm)[i * 2 + 1];
    uint4 o;
    o.x = (v0.x & 0xffff) | (v0.y << 16);
    o.y = (v0.z & 0xffff) | (v0.w << 16);
    o.z = (v1.x & 0xffff) | (v1.y << 16);
    o.w = (v1.z & 0xffff) | (v1.w << 16);
    reinterpret_cast<uint4*>(vm16)[i] = o;
}

// Stage A1: fraw[k] = features @ W_in[k]^T ; per-block partial sum/sumsq
__global__ __launch_bounds__(256) void k_fin(const float* __restrict__ features,
                                             const float* __restrict__ Win,
                                             float* __restrict__ fraw,
                                             float* __restrict__ pIn) {
    __shared__ float Wls[32 * 68];
    __shared__ float s_[256], q_[256];
    int k = blockIdx.y;
    int t = threadIdx.x;
    for (int idx = t; idx < 2048; idx += 256) {
        int r = idx >> 6, i = idx & 63;
        Wls[r * 68 + i] = Win[k * 2048 + idx];
    }
    __syncthreads();
    int c = t & 31, g = t >> 5;
    float w[64];
#pragma unroll
    for (int i4 = 0; i4 < 16; ++i4) {
        float4 wv = *reinterpret_cast<const float4*>(&Wls[c * 68 + i4 * 4]);
        w[i4 * 4] = wv.x; w[i4 * 4 + 1] = wv.y; w[i4 * 4 + 2] = wv.z; w[i4 * 4 + 3] = wv.w;
    }
    int base = blockIdx.x * 64;
    float ssum = 0.f, ssq = 0.f;
    for (int it = 0; it < 8; ++it) {
        int pt = base + it * 8 + g;
        const float4* fr = reinterpret_cast<const float4*>(features + (size_t)pt * 64);
        float y = 0.f;
#pragma unroll
        for (int i4 = 0; i4 < 16; ++i4) {
            float4 v = fr[i4];
            y += v.x * w[i4 * 4] + v.y * w[i4 * 4 + 1] + v.z * w[i4 * 4 + 2] + v.w * w[i4 * 4 + 3];
        }
        fraw[((size_t)k * NPTS + pt) * CMID_ + c] = y;
        ssum += y; ssq += y * y;
    }
    s_[t] = ssum; q_[t] = ssq;
    __syncthreads();
    if (t < 32) {
        float fs = 0.f, fq = 0.f;
#pragma unroll
        for (int gg = 0; gg < 8; ++gg) { fs += s_[gg * 32 + t]; fq += q_[gg * 32 + t]; }
        float* pb = pIn + ((size_t)k * 256 + blockIdx.x) * 64;
        pb[t] = fs;
        pb[32 + t] = fq;
    }
}

// Reduce pIn -> scale/shift per (k, c)
__global__ __launch_bounds__(256) void k_reduce_in(const float* __restrict__ pIn,
                                                   const float* __restrict__ g_in,
                                                   const float* __restrict__ b_in,
                                                   float* __restrict__ ss_in) {
    __shared__ float sm[256];
    int t = threadIdx.x;
    float sum = 0.f;
    if (t < 128) {
        int k = t >> 6, cc = t & 63;
        for (int b = 0; b < 256; ++b) sum += pIn[((size_t)k * 256 + b) * 64 + cc];
    }
    sm[t] = sum;
    __syncthreads();
    if (t < 64) {
        int k = t >> 5, c = t & 31;
        float sv = sm[k * 64 + c];
        float sq = sm[k * 64 + 32 + c];
        float mu  = sv / (float)NPTS;
        float var = fmaxf(sq / (float)NPTS - mu * mu, 0.f);
        float rs  = rsqrtf(var + EPSV);
        float scale = g_in[k * CMID_ + c] * rs;
        float shift = b_in[k * CMID_ + c] - mu * scale;
        ss_in[k * 64 + c]      = scale;
        ss_in[k * 64 + 32 + c] = shift;
    }
}

// Stage A2: fpad_h[k][0]=0 ; fpad_h[k][p+1] = fp16(fraw*scale+shift)
__global__ __launch_bounds__(256) void k_fpad(const float* __restrict__ fraw,
                                              const float* __restrict__ ss_in,
                                              _Float16* __restrict__ fpad_h) {
    int k = blockIdx.y;
    int gid = blockIdx.x * 256 + threadIdx.x;        // one 8-channel chunk
    if (gid >= (NPTS + 1) * 4) return;
    int row = gid >> 2, q = gid & 3;
    H8 o;
    if (row == 0) {
        h2 z; z.x = (_Float16)0.f; z.y = (_Float16)0.f;
        o.a = z; o.b = z; o.c = z; o.d = z;
    } else {
        const float* fp = fraw + ((size_t)k * NPTS + row - 1) * CMID_ + q * 8;
        float4 v0 = *reinterpret_cast<const float4*>(fp);
        float4 v1 = *reinterpret_cast<const float4*>(fp + 4);
        float ov[8];
        float vv[8] = {v0.x, v0.y, v0.z, v0.w, v1.x, v1.y, v1.z, v1.w};
#pragma unroll
        for (int i = 0; i < 8; ++i) {
            int ch = q * 8 + i;
            ov[i] = vv[i] * ss_in[k * 64 + ch] + ss_in[k * 64 + 32 + ch];
        }
        o.a.x = (_Float16)ov[0]; o.a.y = (_Float16)ov[1];
        o.b.x = (_Float16)ov[2]; o.b.y = (_Float16)ov[3];
        o.c.x = (_Float16)ov[4]; o.c.y = (_Float16)ov[5];
        o.d.x = (_Float16)ov[6]; o.d.y = (_Float16)ov[7];
    }
    *reinterpret_cast<H8*>(fpad_h + ((size_t)k * (NPTS + 1) + row) * CMID_ + q * 8) = o;
}

// Stage B: pf[k] = BN_over_offsets(off_xyz @ W_pos[k]^T)  (f32)
__global__ __launch_bounds__(256) void k_pf(const float* __restrict__ Wpos,
                                            const float* __restrict__ g_pos,
                                            const float* __restrict__ b_pos,
                                            float* __restrict__ pf) {
    __shared__ float praw[64 * 32];
    int t = threadIdx.x;
    int pfoff = 0;
    for (int k = 0; k < 2; ++k) {
        int r = k + 1, s = 2 * r, noff = s * s * s;
        for (int idx = t; idx < noff * 32; idx += 256) {
            int j = idx >> 5, c = idx & 31;
            int xi = j % s, yi = (j / s) % s, zi = j / (s * s);
            float xv = (float)(xi - r), yv = (float)(yi - r), zv = (float)(zi - r);
            const float* W = Wpos + (k * CMID_ + c) * 3;
            praw[idx] = xv * W[0] + yv * W[1] + zv * W[2];
        }
        __syncthreads();
        if (t < 32) {
            float sum = 0.f, sq = 0.f;
            for (int j = 0; j < noff; ++j) { float v = praw[j * 32 + t]; sum += v; sq += v * v; }
            float mu  = sum / (float)noff;
            float var = fmaxf(sq / (float)noff - mu * mu, 0.f);
            float rs  = rsqrtf(var + EPSV);
            float g = g_pos[k * CMID_ + t], b = b_pos[k * CMID_ + t];
            for (int j = 0; j < noff; ++j)
                pf[pfoff + j * 32 + t] = (praw[j * 32 + t] - mu) * rs * g + b;
        }
        __syncthreads();
        pfoff += noff * 32;
    }
}

// Stage C: nf[m][c] = max_j relu(fpad[vm+1][c] + pf[j][c]) ; fp16 math
// 4 lanes x 16B per point, 64 points/block
template <int R>
__global__ __launch_bounds__(256) void k_gather(const int* __restrict__ new_coords,
                                                const short* __restrict__ vm16,
                                                const _Float16* __restrict__ fpad_k,
                                                const float* __restrict__ pf_k,
                                                float* __restrict__ nf_k) {
    constexpr int S = 2 * R, NOFF = S * S * S, LOGS = (R == 1 ? 1 : 2);
    __shared__ __align__(16) _Float16 pfs[NOFF * 32];
    int t = threadIdx.x;
    for (int i = t; i < NOFF * 16; i += 256) {
        h2 v; v.x = (_Float16)pf_k[2 * i]; v.y = (_Float16)pf_k[2 * i + 1];
        *reinterpret_cast<h2*>(&pfs[2 * i]) = v;
    }
    __syncthreads();
    int c4 = t & 3;
    int pt = blockIdx.x * 64 + (t >> 2);
    int4 cc = reinterpret_cast<const int4*>(new_coords)[pt];
    int b = cc.x, xc = cc.y, yc = cc.z, zc = cc.w;
    // reference quirk: x-mesh offset -> z coord, z-mesh -> x coord
    int P[S], Q[S], Rr[S];
#pragma unroll
    for (int u = 0; u < S; ++u) {
        int zq = min(max(zc + u - R, 0), ZD - 1);
        int yq = min(max(yc + u - R, 0), YD - 1);
        int xq = min(max(xc + u - R, 0), XD - 1);
        P[u]  = (b * ZD + zq) * (YD * XD);
        Q[u]  = yq * XD;
        Rr[u] = xq;
    }
    h2 z; z.x = (_Float16)0.f; z.y = (_Float16)0.f;
    h2 b0 = z, b1 = z, b2 = z, b3 = z;   // best >= 0 so relu folds into max
#pragma unroll
    for (int j = 0; j < NOFF; ++j) {
        int xi = j & (S - 1), yi = (j >> LOGS) & (S - 1), zi = j >> (2 * LOGS);
        int pidx = (int)vm16[P[xi] + Q[yi] + Rr[zi]];
        H8 gv = *reinterpret_cast<const H8*>(fpad_k + ((size_t)(pidx + 1)) * CMID_ + c4 * 8);
        H8 pv = *reinterpret_cast<const H8*>(&pfs[j * 32 + c4 * 8]);
        b0 = __builtin_elementwise_max(b0, gv.a + pv.a);
        b1 = __builtin_elementwise_max(b1, gv.b + pv.b);
        b2 = __builtin_elementwise_max(b2, gv.c + pv.c);
        b3 = __builtin_elementwise_max(b3, gv.d + pv.d);
    }
    float4 lo = make_float4((float)b0.x, (float)b0.y, (float)b1.x, (float)b1.y);
    float4 hi = make_float4((float)b2.x, (float)b2.y, (float)b3.x, (float)b3.y);
    float* dst = nf_k + (size_t)pt * CMID_ + c4 * 8;
    *reinterpret_cast<float4*>(dst)     = lo;
    *reinterpret_cast<float4*>(dst + 4) = hi;
}

// Stage D1: per-block partial sum/sumsq of y = nf @ W_out[k]^T
__global__ __launch_bounds__(256) void k_out_stats(const float* __restrict__ nf,
                                                   const float* __restrict__ Wout,
                                                   float* __restrict__ pOut) {
    __shared__ float Wls[64 * 33];
    __shared__ float s_[256], q_[256];
    int k = blockIdx.y;
    const float* nf_k = nf + (size_t)k * MGRID * CMID_;
    int t = threadIdx.x;
    for (int idx = t; idx < 2048; idx += 256) {
        int cc = idx >> 5, i = idx & 31;
        Wls[cc * 33 + i] = Wout[k * 2048 + idx];
    }
    __syncthreads();
    int c = t & 63, pl = t >> 6;
    float w[32];
#pragma unroll
    for (int i = 0; i < 32; ++i) w[i] = Wls[c * 33 + i];
    int base = blockIdx.x * 64;
    float sum = 0.f, sq = 0.f;
    for (int it = 0; it < 16; ++it) {
        int pt = base + it * 4 + pl;
        const float4* nr = reinterpret_cast<const float4*>(nf_k + (size_t)pt * CMID_);
        float y = 0.f;
#pragma unroll
        for (int i4 = 0; i4 < 8; ++i4) {
            float4 v = nr[i4];
            y += v.x * w[i4 * 4] + v.y * w[i4 * 4 + 1] + v.z * w[i4 * 4 + 2] + v.w * w[i4 * 4 + 3];
        }
        sum += y; sq += y * y;
    }
    s_[t] = sum; q_[t] = sq;
    __syncthreads();
    if (t < 128) { s_[t] += s_[t + 128]; q_[t] += q_[t + 128]; } __syncthreads();
    if (t < 64) {
        float fs = s_[t] + s_[t + 64];
        float fq = q_[t] + q_[t + 64];
        pOut[((size_t)k * 1024 + blockIdx.x) * 128 + t]      = fs;
        pOut[((size_t)k * 1024 + blockIdx.x) * 128 + 64 + t] = fq;
    }
}

// Reduce pOut -> scale/shift per (k, c)
__global__ __launch_bounds__(256) void k_out_reduce(const float* __restrict__ pOut,
                                                    const float* __restrict__ g_out,
                                                    const float* __restrict__ b_out,
                                                    float* __restrict__ ss_out) {
    __shared__ float sm[256];
    int t = threadIdx.x;
    int k = t >> 7, cc = t & 127;
    float sum = 0.f;
    for (int b = 0; b < 1024; ++b) sum += pOut[((size_t)k * 1024 + b) * 128 + cc];
    sm[t] = sum;
    __syncthreads();
    if (t < 128) {
        int kk = t >> 6, c = t & 63;
        float sv = sm[kk * 128 + c];
        float sq = sm[kk * 128 + 64 + c];
        float mu  = sv / (float)MGRID;
        float var = fmaxf(sq / (float)MGRID - mu * mu, 0.f);
        float rs  = rsqrtf(var + EPSV);
        float scale = g_out[kk * COUT_ + c] * rs;
        float shift = b_out[kk * COUT_ + c] - mu * scale;
        ss_out[kk * 128 + c]      = scale;
        ss_out[kk * 128 + 64 + c] = shift;
    }
}

// Stage D2: out[:, k*64 + c] = relu(y*scale + shift)
__global__ __launch_bounds__(256) void k_out_write(const float* __restrict__ nf,
                                                   const float* __restrict__ Wout,
                                                   const float* __restrict__ ss_out,
                                                   float* __restrict__ out) {
    __shared__ float Wls[64 * 33];
    int k = blockIdx.y;
    const float* nf_k = nf + (size_t)k * MGRID * CMID_;
    int t = threadIdx.x;
    for (int idx = t; idx < 2048; idx += 256) {
        int cc = idx >> 5, i = idx & 31;
        Wls[cc * 33 + i] = Wout[k * 2048 + idx];
    }
    __syncthreads();
    int c = t & 63, pl = t >> 6;
    float w[32];
#pragma unroll
    for (int i = 0; i < 32; ++i) w[i] = Wls[c * 33 + i];
    float scale = ss_out[k * 128 + c], shift = ss_out[k * 128 + 64 + c];
    int base = blockIdx.x * 64;
    for (int it = 0; it < 16; ++it) {
        int pt = base + it * 4 + pl;
        const float4* nr = reinterpret_cast<const float4*>(nf_k + (size_t)pt * CMID_);
        float y = 0.f;
#pragma unroll
        for (int i4 = 0; i4 < 8; ++i4) {
            float4 v = nr[i4];
            y += v.x * w[i4 * 4] + v.y * w[i4 * 4 + 1] + v.z * w[i4 * 4 + 2] + v.w * w[i4 * 4 + 3];
        }
        float o = y * scale + shift;
        o = o > 0.f ? o : 0.f;
        out[(size_t)pt * 128 + k * 64 + c] = o;
    }
}

extern "C" void kernel_launch(void* const* d_in, const int* in_sizes, int n_in,
                              void* d_out, int out_size, void* d_ws, size_t ws_size,
                              hipStream_t stream) {
    const int*   new_coords = (const int*)d_in[4];
    const float* features   = (const float*)d_in[5];
    const int*   vm         = (const int*)d_in[6];
    const float* W_in  = (const float*)d_in[7];
    const float* g_in  = (const float*)d_in[8];
    const float* b_in  = (const float*)d_in[9];
    const float* W_pos = (const float*)d_in[10];
    const float* g_pos = (const float*)d_in[11];
    const float* b_pos = (const float*)d_in[12];
    const float* W_out = (const float*)d_in[13];
    const float* g_out = (const float*)d_in[14];
    const float* b_out = (const float*)d_in[15];
    float* out = (float*)d_out;

    char* ws = (char*)d_ws;
    float* ss_in  = (float*)(ws);
    float* ss_out = (float*)(ws + 512);
    size_t off = 1536;
    float* fraw = (float*)(ws + off);
    float* pOut = (float*)(ws + off);                    // overlays fraw
    off += (size_t)2 * NPTS * CMID_ * 4;
    _Float16* fpad_h = (_Float16*)(ws + off); off += (size_t)2 * (NPTS + 1) * CMID_ * 2;
    float* pf   = (float*)(ws + off); off += (size_t)(8 + 64) * 32 * 4;
    float* nf   = (float*)(ws + off);
    float* pIn  = (float*)(ws + off);                    // overlays nf head
    off += (size_t)2 * MGRID * CMID_ * 4;
    short* vm16 = (short*)(ws + off);

    k_vm16<<<(NVOX / 8 + 255) / 256, 256, 0, stream>>>(vm, vm16);

    dim3 gA(NPTS / 64, 2);
    k_fin<<<gA, 256, 0, stream>>>(features, W_in, fraw, pIn);
    k_reduce_in<<<1, 256, 0, stream>>>(pIn, g_in, b_in, ss_in);

    dim3 gP(((NPTS + 1) * 4 + 255) / 256, 2);
    k_fpad<<<gP, 256, 0, stream>>>(fraw, ss_in, fpad_h);

    k_pf<<<1, 256, 0, stream>>>(W_pos, g_pos, b_pos, pf);

    k_gather<1><<<MGRID / 64, 256, 0, stream>>>(new_coords, vm16, fpad_h, pf, nf);
    k_gather<2><<<MGRID / 64, 256, 0, stream>>>(new_coords, vm16,
                                                fpad_h + (size_t)(NPTS + 1) * CMID_,
                                                pf + 8 * 32,
                                                nf + (size_t)MGRID * CMID_);

    dim3 gO(MGRID / 64, 2);
    k_out_stats<<<gO, 256, 0, stream>>>(nf, W_out, pOut);
    k_out_reduce<<<1, 256, 0, stream>>>(pOut, g_out, b_out, ss_out);
    k_out_write<<<gO, 256, 0, stream>>>(nf, W_out, ss_out, out);
}

// Round 4
// 133.407 us; speedup vs baseline: 2.6083x; 1.3440x over previous
//
#include <hip/hip_runtime.h>

#define EPSV 1e-5f
constexpr int NPTS  = 16384;
constexpr int MGRID = 65536;
constexpr int ZD = 11, YD = 200, XD = 176;
constexpr int NVOX = 2 * ZD * YD * XD;          // 774400
constexpr int NB_VM = (NVOX / 8 + 255) / 256;   // 379 blocks for vm16 compress

typedef _Float16 h2 __attribute__((ext_vector_type(2)));
struct alignas(16) H8 { h2 a, b, c, d; };       // 8 fp16 channels

// ---------------------------------------------------------------------------
// ws layout (bytes):
//   0          ss_in  : float[2][{scale,shift}][32]        (512 B)
//   512        ss_out : float[2][{scale,shift}][64]        (1 KB)
//   1536       pIn    : float[2][256][64]                  (128 KB)
//   132608     pOut   : float[2][1024][128]                (1 MB)
//   1181184    fraw_h : _Float16[2][16385][32]  raw, row0=pad (2 MB)
//   3278464    pf     : float[8+64][32]                    (9216 B)
//   3287680    vm16   : short[774400]                      (1.5 MB)
//   4836480    nf_h   : _Float16[2][65536][32]             (8.4 MB)
// total ~13.2 MB
// ---------------------------------------------------------------------------

// L1: fused prelude — vm16 compress | fin matmul (raw fp16 + stats partials) | pf
__global__ __launch_bounds__(256) void k_pre(
    const int* __restrict__ vm, const float* __restrict__ features,
    const float* __restrict__ Win, const float* __restrict__ Wpos,
    const float* __restrict__ g_pos, const float* __restrict__ b_pos,
    short* __restrict__ vm16, _Float16* __restrict__ fraw_h,
    float* __restrict__ pIn, float* __restrict__ pf)
{
    __shared__ float smem[2688];
    int bid = blockIdx.x, t = threadIdx.x;

    if (bid < NB_VM) {                       // ---- vm -> int16 (8 ints/thread)
        int i = bid * 256 + t;
        if (i < NVOX / 8) {
            int4 v0 = ((const int4*)vm)[i * 2];
            int4 v1 = ((const int4*)vm)[i * 2 + 1];
            uint4 o;
            o.x = (v0.x & 0xffff) | (v0.y << 16);
            o.y = (v0.z & 0xffff) | (v0.w << 16);
            o.z = (v1.x & 0xffff) | (v1.y << 16);
            o.w = (v1.z & 0xffff) | (v1.w << 16);
            ((uint4*)vm16)[i] = o;
        }
        return;
    }
    if (bid < NB_VM + 512) {                 // ---- fin: raw y fp16 + partials
        int b2 = bid - NB_VM;
        int k = b2 >> 8, bx = b2 & 255;
        float* Wls = smem;                   // [32][68]
        float* s_  = smem + 2176;
        float* q_  = smem + 2432;
        for (int idx = t; idx < 2048; idx += 256)
            Wls[(idx >> 6) * 68 + (idx & 63)] = Win[k * 2048 + idx];
        __syncthreads();
        int c = t & 31, g = t >> 5;
        float w[64];
#pragma unroll
        for (int i4 = 0; i4 < 16; ++i4) {
            float4 wv = *(const float4*)&Wls[c * 68 + i4 * 4];
            w[i4 * 4] = wv.x; w[i4 * 4 + 1] = wv.y; w[i4 * 4 + 2] = wv.z; w[i4 * 4 + 3] = wv.w;
        }
        int base = bx * 64;
        float ssum = 0.f, ssq = 0.f;
        for (int it = 0; it < 8; ++it) {
            int pt = base + it * 8 + g;
            const float4* fr = (const float4*)(features + (size_t)pt * 64);
            float y = 0.f;
#pragma unroll
            for (int i4 = 0; i4 < 16; ++i4) {
                float4 v = fr[i4];
                y += v.x * w[i4 * 4] + v.y * w[i4 * 4 + 1] + v.z * w[i4 * 4 + 2] + v.w * w[i4 * 4 + 3];
            }
            fraw_h[((size_t)k * (NPTS + 1) + pt + 1) * 32 + c] = (_Float16)y;
            ssum += y; ssq += y * y;
        }
        s_[t] = ssum; q_[t] = ssq;
        __syncthreads();
        if (t < 32) {
            float fs = 0.f, fq = 0.f;
#pragma unroll
            for (int gg = 0; gg < 8; ++gg) { fs += s_[gg * 32 + t]; fq += q_[gg * 32 + t]; }
            float* pb = pIn + ((size_t)k * 256 + bx) * 64;
            pb[t] = fs; pb[32 + t] = fq;
        }
        return;
    }
    // ---- pf: BN over offsets of off_xyz @ W_pos^T (f32, 1 block)
    float* praw = smem;
    int pfoff = 0;
    for (int k = 0; k < 2; ++k) {
        int r = k + 1, s = 2 * r, noff = s * s * s;
        for (int idx = t; idx < noff * 32; idx += 256) {
            int j = idx >> 5, c = idx & 31;
            int xi = j % s, yi = (j / s) % s, zi = j / (s * s);
            const float* W = Wpos + (k * 32 + c) * 3;
            praw[idx] = (float)(xi - r) * W[0] + (float)(yi - r) * W[1] + (float)(zi - r) * W[2];
        }
        __syncthreads();
        if (t < 32) {
            float sum = 0.f, sq = 0.f;
            for (int j = 0; j < noff; ++j) { float v = praw[j * 32 + t]; sum += v; sq += v * v; }
            float mu  = sum / (float)noff;
            float var = fmaxf(sq / (float)noff - mu * mu, 0.f);
            float rs  = rsqrtf(var + EPSV);
            float g = g_pos[k * 32 + t], b = b_pos[k * 32 + t];
            for (int j = 0; j < noff; ++j)
                pf[pfoff + j * 32 + t] = (praw[j * 32 + t] - mu) * rs * g + b;
        }
        __syncthreads();
        pfoff += noff * 32;
    }
}

// L2: reduce partials -> scale/shift ; write pad row fp16(-shift/scale)
__global__ __launch_bounds__(256) void k_reduce_in(
    const float* __restrict__ pIn, const float* __restrict__ g_in,
    const float* __restrict__ b_in, float* __restrict__ ss_in,
    _Float16* __restrict__ fraw_h)
{
    __shared__ float sm[256];
    int t = threadIdx.x;
    float sum = 0.f;
    if (t < 128) {
        int k = t >> 6, cc = t & 63;
        for (int b = 0; b < 256; ++b) sum += pIn[((size_t)k * 256 + b) * 64 + cc];
    }
    sm[t] = sum;
    __syncthreads();
    if (t < 64) {
        int k = t >> 5, c = t & 31;
        float sv = sm[k * 64 + c], sq = sm[k * 64 + 32 + c];
        float mu  = sv / (float)NPTS;
        float var = fmaxf(sq / (float)NPTS - mu * mu, 0.f);
        float rs  = rsqrtf(var + EPSV);
        float scale = g_in[k * 32 + c] * rs;
        float shift = b_in[k * 32 + c] - mu * scale;
        ss_in[k * 64 + c]      = scale;
        ss_in[k * 64 + 32 + c] = shift;
        float pad = (scale != 0.f) ? (-shift / scale) : 0.f;
        pad = fminf(fmaxf(pad, -60000.f), 60000.f);
        fraw_h[(size_t)k * (NPTS + 1) * 32 + c] = (_Float16)pad;   // row 0
    }
}

// L3: fused gather + relu-max + out-matmul stats partials
template <int R>
__device__ __forceinline__ void gather_body(
    int k, const int* __restrict__ nc, const short* __restrict__ vm16,
    const _Float16* __restrict__ fraw_h, const float* __restrict__ pf,
    const float* __restrict__ ss_in, const float* __restrict__ Wout,
    _Float16* __restrict__ nf_h, float* __restrict__ pOut, char* smem)
{
    constexpr int S = 2 * R, NOFF = S * S * S, LOGS = (R == 1 ? 1 : 2);
    _Float16* psum = (_Float16*)smem;                 // [NOFF*32] fp16 (shift+pf)
    _Float16* nfl  = (_Float16*)(smem + 4096);        // [64][32] fp16
    float* Wls = (float*)(smem + 8192);               // [64][33]
    float* s_  = (float*)(smem + 8192 + 8448);        // [256]
    float* q_  = s_ + 256;                            // [256]
    int t = threadIdx.x, bx = blockIdx.x;
    const _Float16* fr = fraw_h + (size_t)k * (NPTS + 1) * 32;
    const float* pfk = pf + (R == 2 ? 256 : 0);
    for (int i = t; i < NOFF * 32; i += 256)
        psum[i] = (_Float16)(pfk[i] + ss_in[k * 64 + 32 + (i & 31)]);
    for (int idx = t; idx < 2048; idx += 256)
        Wls[(idx >> 5) * 33 + (idx & 31)] = Wout[k * 2048 + idx];
    __syncthreads();

    int c4 = t & 3, lp = t >> 2;
    int pt = bx * 64 + lp;
    int4 cc = ((const int4*)nc)[pt];
    int bb = cc.x, xc = cc.y, yc = cc.z, zc = cc.w;
    // reference quirk: mesh-x offset -> z coord, mesh-z -> x coord
    int P[S], Q[S], Rr[S];
#pragma unroll
    for (int u = 0; u < S; ++u) {
        int zq = min(max(zc + u - R, 0), ZD - 1);
        int yq = min(max(yc + u - R, 0), YD - 1);
        int xq = min(max(xc + u - R, 0), XD - 1);
        P[u]  = (bb * ZD + zq) * (YD * XD);
        Q[u]  = yq * XD;
        Rr[u] = xq;
    }
    h2 sc[4];
#pragma unroll
    for (int i = 0; i < 4; ++i) {
        sc[i].x = (_Float16)ss_in[k * 64 + c4 * 8 + 2 * i];
        sc[i].y = (_Float16)ss_in[k * 64 + c4 * 8 + 2 * i + 1];
    }
    h2 z; z.x = (_Float16)0.f; z.y = (_Float16)0.f;
    h2 b0 = z, b1 = z, b2 = z, b3 = z;                // relu folds into max (best>=0)
#pragma unroll
    for (int j = 0; j < NOFF; ++j) {
        int xi = j & (S - 1), yi = (j >> LOGS) & (S - 1), zi = j >> (2 * LOGS);
        int pidx = (int)vm16[P[xi] + Q[yi] + Rr[zi]];
        H8 gv = *(const H8*)(fr + ((size_t)(pidx + 1)) * 32 + c4 * 8);
        H8 pv = *(const H8*)(psum + j * 32 + c4 * 8);
        b0 = __builtin_elementwise_max(b0, gv.a * sc[0] + pv.a);
        b1 = __builtin_elementwise_max(b1, gv.b * sc[1] + pv.b);
        b2 = __builtin_elementwise_max(b2, gv.c * sc[2] + pv.c);
        b3 = __builtin_elementwise_max(b3, gv.d * sc[3] + pv.d);
    }
    H8 ob; ob.a = b0; ob.b = b1; ob.c = b2; ob.d = b3;
    *(H8*)(nf_h + ((size_t)k * MGRID + pt) * 32 + c4 * 8) = ob;
    *(H8*)(nfl + lp * 32 + c4 * 8) = ob;
    __syncthreads();

    // stats: y = nf . W_out[c], per-block sum/sumsq partials
    int c = t & 63, pl = t >> 6;
    float w[32];
#pragma unroll
    for (int i = 0; i < 32; ++i) w[i] = Wls[c * 33 + i];
    float sum = 0.f, sq = 0.f;
    for (int i = 0; i < 16; ++i) {
        int pr = pl * 16 + i;
        const H8* row = (const H8*)(nfl + pr * 32);
        H8 r0 = row[0], r1 = row[1], r2 = row[2], r3 = row[3];
        h2 hh[16] = {r0.a, r0.b, r0.c, r0.d, r1.a, r1.b, r1.c, r1.d,
                     r2.a, r2.b, r2.c, r2.d, r3.a, r3.b, r3.c, r3.d};
        float y = 0.f;
#pragma unroll
        for (int q8 = 0; q8 < 16; ++q8)
            y += (float)hh[q8].x * w[2 * q8] + (float)hh[q8].y * w[2 * q8 + 1];
        sum += y; sq += y * y;
    }
    s_[t] = sum; q_[t] = sq;
    __syncthreads();
    if (t < 128) { s_[t] += s_[t + 128]; q_[t] += q_[t + 128]; }
    __syncthreads();
    if (t < 64) {
        pOut[((size_t)k * 1024 + bx) * 128 + t]      = s_[t] + s_[t + 64];
        pOut[((size_t)k * 1024 + bx) * 128 + 64 + t] = q_[t] + q_[t + 64];
    }
}

__global__ __launch_bounds__(256) void k_gather(
    const int* __restrict__ nc, const short* __restrict__ vm16,
    const _Float16* __restrict__ fraw_h, const float* __restrict__ pf,
    const float* __restrict__ ss_in, const float* __restrict__ Wout,
    _Float16* __restrict__ nf_h, float* __restrict__ pOut)
{
    __shared__ __align__(16) char smem[8192 + 8448 + 2048];
    if (blockIdx.y == 0)
        gather_body<1>(0, nc, vm16, fraw_h, pf, ss_in, Wout, nf_h, pOut, smem);
    else
        gather_body<2>(1, nc, vm16, fraw_h, pf, ss_in, Wout, nf_h, pOut, smem);
}

// L4: reduce pOut -> scale/shift per (k, c)
__global__ __launch_bounds__(256) void k_out_reduce(
    const float* __restrict__ pOut, const float* __restrict__ g_out,
    const float* __restrict__ b_out, float* __restrict__ ss_out)
{
    __shared__ float sm[256];
    int t = threadIdx.x;
    int k = t >> 7, cc = t & 127;
    float sum = 0.f;
    for (int b = 0; b < 1024; ++b) sum += pOut[((size_t)k * 1024 + b) * 128 + cc];
    sm[t] = sum;
    __syncthreads();
    if (t < 128) {
        int kk = t >> 6, c = t & 63;
        float sv = sm[kk * 128 + c];
        float sq = sm[kk * 128 + 64 + c];
        float mu  = sv / (float)MGRID;
        float var = fmaxf(sq / (float)MGRID - mu * mu, 0.f);
        float rs  = rsqrtf(var + EPSV);
        float scale = g_out[kk * 64 + c] * rs;
        float shift = b_out[kk * 64 + c] - mu * scale;
        ss_out[kk * 128 + c]      = scale;
        ss_out[kk * 128 + 64 + c] = shift;
    }
}

// L5: out[:, k*64+c] = relu(y*scale + shift)
__global__ __launch_bounds__(256) void k_out_write(
    const _Float16* __restrict__ nf_h, const float* __restrict__ Wout,
    const float* __restrict__ ss_out, float* __restrict__ out)
{
    __shared__ float Wls[64 * 33];
    int k = blockIdx.y, t = threadIdx.x;
    for (int idx = t; idx < 2048; idx += 256)
        Wls[(idx >> 5) * 33 + (idx & 31)] = Wout[k * 2048 + idx];
    __syncthreads();
    int c = t & 63, pl = t >> 6;
    float w[32];
#pragma unroll
    for (int i = 0; i < 32; ++i) w[i] = Wls[c * 33 + i];
    float scale = ss_out[k * 128 + c], shift = ss_out[k * 128 + 64 + c];
    int base = blockIdx.x * 64;
    for (int it = 0; it < 16; ++it) {
        int pt = base + it * 4 + pl;
        const H8* row = (const H8*)(nf_h + ((size_t)k * MGRID + pt) * 32);
        H8 r0 = row[0], r1 = row[1], r2 = row[2], r3 = row[3];
        h2 hh[16] = {r0.a, r0.b, r0.c, r0.d, r1.a, r1.b, r1.c, r1.d,
                     r2.a, r2.b, r2.c, r2.d, r3.a, r3.b, r3.c, r3.d};
        float y = 0.f;
#pragma unroll
        for (int q8 = 0; q8 < 16; ++q8)
            y += (float)hh[q8].x * w[2 * q8] + (float)hh[q8].y * w[2 * q8 + 1];
        float o = y * scale + shift;
        o = o > 0.f ? o : 0.f;
        out[(size_t)pt * 128 + k * 64 + c] = o;
    }
}

extern "C" void kernel_launch(void* const* d_in, const int* in_sizes, int n_in,
                              void* d_out, int out_size, void* d_ws, size_t ws_size,
                              hipStream_t stream) {
    const int*   new_coords = (const int*)d_in[4];
    const float* features   = (const float*)d_in[5];
    const int*   vm         = (const int*)d_in[6];
    const float* W_in  = (const float*)d_in[7];
    const float* g_in  = (const float*)d_in[8];
    const float* b_in  = (const float*)d_in[9];
    const float* W_pos = (const float*)d_in[10];
    const float* g_pos = (const float*)d_in[11];
    const float* b_pos = (const float*)d_in[12];
    const float* W_out = (const float*)d_in[13];
    const float* g_out = (const float*)d_in[14];
    const float* b_out = (const float*)d_in[15];
    float* out = (float*)d_out;

    char* ws = (char*)d_ws;
    float*     ss_in  = (float*)(ws);
    float*     ss_out = (float*)(ws + 512);
    float*     pIn    = (float*)(ws + 1536);
    float*     pOut   = (float*)(ws + 132608);
    _Float16*  fraw_h = (_Float16*)(ws + 1181184);
    float*     pf     = (float*)(ws + 3278464);
    short*     vm16   = (short*)(ws + 3287680);
    _Float16*  nf_h   = (_Float16*)(ws + 4836480);

    k_pre<<<NB_VM + 512 + 1, 256, 0, stream>>>(vm, features, W_in, W_pos, g_pos, b_pos,
                                               vm16, fraw_h, pIn, pf);
    k_reduce_in<<<1, 256, 0, stream>>>(pIn, g_in, b_in, ss_in, fraw_h);

    dim3 gG(MGRID / 64, 2);
    k_gather<<<gG, 256, 0, stream>>>(new_coords, vm16, fraw_h, pf, ss_in, W_out, nf_h, pOut);

    k_out_reduce<<<1, 256, 0, stream>>>(pOut, g_out, b_out, ss_out);

    dim3 gW(MGRID / 64, 2);
    k_out_write<<<gW, 256, 0, stream>>>(nf_h, W_out, ss_out, out);
}

// Round 5
// 110.808 us; speedup vs baseline: 3.1402x; 1.2039x over previous
//
#include <hip/hip_runtime.h>

#define EPSV 1e-5f
constexpr int NPTS  = 16384;
constexpr int MGRID = 65536;
constexpr int ZD = 11, YD = 200, XD = 176;
constexpr int NVOX = 2 * ZD * YD * XD;          // 774400
constexpr int NB_VM = (NVOX / 8 + 255) / 256;   // 379 blocks for vm16 compress

typedef _Float16 h2 __attribute__((ext_vector_type(2)));
struct alignas(16) H8 { h2 a, b, c, d; };       // 8 fp16 channels

// ---------------------------------------------------------------------------
// ws layout (bytes):
//   0          ss_in  : float[2][{scale,shift}][32]        (512 B)
//   512        ss_out : float[2][{scale,shift}][64]        (1 KB)
//   1536       pIn    : float[2][256][64]                  (128 KB)
//   132608     pOut   : float[2][1024][128]                (1 MB)
//   1181184    fraw_h : _Float16[2][16385][32]  raw, row0=pad (2 MB)
//   3278464    pf     : float[8+64][32]                    (9216 B)
//   3287680    vm16   : short[774400]                      (1.5 MB)
//   4836480    nf_h   : _Float16[2][65536][32]             (8.4 MB)
// ---------------------------------------------------------------------------

__device__ __forceinline__ h2 shfl_xor_h2(h2 v, int m) {
    union { h2 h; int i; } u; u.h = v;
    u.i = __shfl_xor(u.i, m, 64);
    return u.h;
}

// L1: fused prelude — vm16 compress | fin matmul (raw fp16 + stats partials) | pf
__global__ __launch_bounds__(256) void k_pre(
    const int* __restrict__ vm, const float* __restrict__ features,
    const float* __restrict__ Win, const float* __restrict__ Wpos,
    const float* __restrict__ g_pos, const float* __restrict__ b_pos,
    short* __restrict__ vm16, _Float16* __restrict__ fraw_h,
    float* __restrict__ pIn, float* __restrict__ pf)
{
    __shared__ float smem[2688];
    int bid = blockIdx.x, t = threadIdx.x;

    if (bid < NB_VM) {                       // ---- vm -> int16 (8 ints/thread)
        int i = bid * 256 + t;
        if (i < NVOX / 8) {
            int4 v0 = ((const int4*)vm)[i * 2];
            int4 v1 = ((const int4*)vm)[i * 2 + 1];
            uint4 o;
            o.x = (v0.x & 0xffff) | (v0.y << 16);
            o.y = (v0.z & 0xffff) | (v0.w << 16);
            o.z = (v1.x & 0xffff) | (v1.y << 16);
            o.w = (v1.z & 0xffff) | (v1.w << 16);
            ((uint4*)vm16)[i] = o;
        }
        return;
    }
    if (bid < NB_VM + 512) {                 // ---- fin: raw y fp16 + partials
        int b2 = bid - NB_VM;
        int k = b2 >> 8, bx = b2 & 255;
        float* Wls = smem;                   // [32][68]
        float* s_  = smem + 2176;
        float* q_  = smem + 2432;
        for (int idx = t; idx < 2048; idx += 256)
            Wls[(idx >> 6) * 68 + (idx & 63)] = Win[k * 2048 + idx];
        __syncthreads();
        int c = t & 31, g = t >> 5;
        float w[64];
#pragma unroll
        for (int i4 = 0; i4 < 16; ++i4) {
            float4 wv = *(const float4*)&Wls[c * 68 + i4 * 4];
            w[i4 * 4] = wv.x; w[i4 * 4 + 1] = wv.y; w[i4 * 4 + 2] = wv.z; w[i4 * 4 + 3] = wv.w;
        }
        int base = bx * 64;
        float ssum = 0.f, ssq = 0.f;
        for (int it = 0; it < 8; ++it) {
            int pt = base + it * 8 + g;
            const float4* fr = (const float4*)(features + (size_t)pt * 64);
            float y = 0.f;
#pragma unroll
            for (int i4 = 0; i4 < 16; ++i4) {
                float4 v = fr[i4];
                y += v.x * w[i4 * 4] + v.y * w[i4 * 4 + 1] + v.z * w[i4 * 4 + 2] + v.w * w[i4 * 4 + 3];
            }
            fraw_h[((size_t)k * (NPTS + 1) + pt + 1) * 32 + c] = (_Float16)y;
            ssum += y; ssq += y * y;
        }
        s_[t] = ssum; q_[t] = ssq;
        __syncthreads();
        if (t < 32) {
            float fs = 0.f, fq = 0.f;
#pragma unroll
            for (int gg = 0; gg < 8; ++gg) { fs += s_[gg * 32 + t]; fq += q_[gg * 32 + t]; }
            float* pb = pIn + ((size_t)k * 256 + bx) * 64;
            pb[t] = fs; pb[32 + t] = fq;
        }
        return;
    }
    // ---- pf: BN over offsets of off_xyz @ W_pos^T (f32, 1 block)
    float* praw = smem;
    int pfoff = 0;
    for (int k = 0; k < 2; ++k) {
        int r = k + 1, s = 2 * r, noff = s * s * s;
        for (int idx = t; idx < noff * 32; idx += 256) {
            int j = idx >> 5, c = idx & 31;
            int xi = j % s, yi = (j / s) % s, zi = j / (s * s);
            const float* W = Wpos + (k * 32 + c) * 3;
            praw[idx] = (float)(xi - r) * W[0] + (float)(yi - r) * W[1] + (float)(zi - r) * W[2];
        }
        __syncthreads();
        if (t < 32) {
            float sum = 0.f, sq = 0.f;
            for (int j = 0; j < noff; ++j) { float v = praw[j * 32 + t]; sum += v; sq += v * v; }
            float mu  = sum / (float)noff;
            float var = fmaxf(sq / (float)noff - mu * mu, 0.f);
            float rs  = rsqrtf(var + EPSV);
            float g = g_pos[k * 32 + t], b = b_pos[k * 32 + t];
            for (int j = 0; j < noff; ++j)
                pf[pfoff + j * 32 + t] = (praw[j * 32 + t] - mu) * rs * g + b;
        }
        __syncthreads();
        pfoff += noff * 32;
    }
}

// L2: parallel reduce pIn -> scale/shift ; one block per (k, c)
__global__ __launch_bounds__(256) void k_reduce_in(
    const float* __restrict__ pIn, const float* __restrict__ g_in,
    const float* __restrict__ b_in, float* __restrict__ ss_in,
    _Float16* __restrict__ fraw_h)
{
    __shared__ float ss[256], qq[256];
    int b = blockIdx.x;          // 64 blocks: k = b>>5, c = b&31
    int k = b >> 5, c = b & 31;
    int t = threadIdx.x;
    ss[t] = pIn[((size_t)k * 256 + t) * 64 + c];
    qq[t] = pIn[((size_t)k * 256 + t) * 64 + 32 + c];
    __syncthreads();
    if (t < 128) { ss[t] += ss[t + 128]; qq[t] += qq[t + 128]; } __syncthreads();
    if (t < 64)  { ss[t] += ss[t + 64];  qq[t] += qq[t + 64];  } __syncthreads();
    if (t < 32)  { ss[t] += ss[t + 32];  qq[t] += qq[t + 32];  } __syncthreads();
    if (t == 0) {
        float sv = 0.f, sq = 0.f;
#pragma unroll
        for (int i = 0; i < 32; ++i) { sv += ss[i]; sq += qq[i]; }
        float mu  = sv / (float)NPTS;
        float var = fmaxf(sq / (float)NPTS - mu * mu, 0.f);
        float rs  = rsqrtf(var + EPSV);
        float scale = g_in[k * 32 + c] * rs;
        float shift = b_in[k * 32 + c] - mu * scale;
        ss_in[k * 64 + c]      = scale;
        ss_in[k * 64 + 32 + c] = shift;
        float pad = (scale != 0.f) ? (-shift / scale) : 0.f;
        pad = fminf(fmaxf(pad, -60000.f), 60000.f);
        fraw_h[(size_t)k * (NPTS + 1) * 32 + c] = (_Float16)pad;   // row 0
    }
}

// L3: fused gather + relu-max + out-matmul stats partials.
// 1024 threads: 64 points x (4 j-groups x 4 chan-chunks).
template <int R>
__device__ __forceinline__ void gather_body(
    int k, const int* __restrict__ nc, const short* __restrict__ vm16,
    const _Float16* __restrict__ fraw_h, const float* __restrict__ pf,
    const float* __restrict__ ss_in, const float* __restrict__ Wout,
    _Float16* __restrict__ nf_h, float* __restrict__ pOut, char* smem)
{
    constexpr int S = 2 * R, NOFF = S * S * S, JPL = NOFF / 4;  // j per lane
    _Float16* psum = (_Float16*)smem;                 // [NOFF*32] fp16 (shift+pf)
    _Float16* nfl  = (_Float16*)(smem + 4096);        // [64][32] fp16
    float* Wls = (float*)(smem + 8192);               // [64][33]
    float* s_  = (float*)smem;                        // overlays psum (dead)
    float* q_  = (float*)(smem + 16640);              // [1024]
    int t = threadIdx.x, bx = blockIdx.x;
    const _Float16* fr = fraw_h + (size_t)k * (NPTS + 1) * 32;
    const float* pfk = pf + (R == 2 ? 256 : 0);
    float shv_base = ss_in[k * 64 + 32 + 0];  (void)shv_base;
    for (int i = t; i < NOFF * 32; i += 1024)
        psum[i] = (_Float16)(pfk[i] + ss_in[k * 64 + 32 + (i & 31)]);
    for (int idx = t; idx < 2048; idx += 1024)
        Wls[(idx >> 5) * 33 + (idx & 31)] = Wout[k * 2048 + idx];
    __syncthreads();

    int c4 = t & 3, jg = (t >> 2) & 3, lp = t >> 4;
    int pt = bx * 64 + lp;
    int4 cc = ((const int4*)nc)[pt];
    int bb = cc.x, xc = cc.y, yc = cc.z, zc = cc.w;
    // reference quirk: mesh-x offset -> z coord, mesh-z -> x coord
    int P[S], Q[S];
#pragma unroll
    for (int u = 0; u < S; ++u) {
        int zq = min(max(zc + u - R, 0), ZD - 1);
        int yq = min(max(yc + u - R, 0), YD - 1);
        P[u] = (bb * ZD + zq) * (YD * XD);
        Q[u] = yq * XD;
    }
    h2 sc[4];
#pragma unroll
    for (int i = 0; i < 4; ++i) {
        sc[i].x = (_Float16)ss_in[k * 64 + c4 * 8 + 2 * i];
        sc[i].y = (_Float16)ss_in[k * 64 + c4 * 8 + 2 * i + 1];
    }
    h2 z; z.x = (_Float16)0.f; z.y = (_Float16)0.f;
    h2 b0 = z, b1 = z, b2 = z, b3 = z;                // relu folds into max
    int pidx[JPL];
    if (R == 2) {
        int Rx = min(max(xc + jg - R, 0), XD - 1);    // zi = jg
#pragma unroll
        for (int jj = 0; jj < JPL; ++jj)
            pidx[jj] = (int)vm16[P[jj & 3] + Q[jj >> 2] + Rx];
    } else {
        int Rx = min(max(xc + (jg >> 1) - R, 0), XD - 1);   // zi = jg>>1
        int Qy = Q[jg & 1];                                  // yi = jg&1
#pragma unroll
        for (int jj = 0; jj < JPL; ++jj)
            pidx[jj] = (int)vm16[P[jj] + Qy + Rx];
    }
#pragma unroll
    for (int jj = 0; jj < JPL; ++jj) {
        int j = jg * JPL + jj;
        H8 gv = *(const H8*)(fr + ((size_t)(pidx[jj] + 1)) * 32 + c4 * 8);
        H8 pv = *(const H8*)(psum + j * 32 + c4 * 8);
        b0 = __builtin_elementwise_max(b0, gv.a * sc[0] + pv.a);
        b1 = __builtin_elementwise_max(b1, gv.b * sc[1] + pv.b);
        b2 = __builtin_elementwise_max(b2, gv.c * sc[2] + pv.c);
        b3 = __builtin_elementwise_max(b3, gv.d * sc[3] + pv.d);
    }
    // combine over jg (lane bits 2,3)
    b0 = __builtin_elementwise_max(b0, shfl_xor_h2(b0, 4));
    b1 = __builtin_elementwise_max(b1, shfl_xor_h2(b1, 4));
    b2 = __builtin_elementwise_max(b2, shfl_xor_h2(b2, 4));
    b3 = __builtin_elementwise_max(b3, shfl_xor_h2(b3, 4));
    b0 = __builtin_elementwise_max(b0, shfl_xor_h2(b0, 8));
    b1 = __builtin_elementwise_max(b1, shfl_xor_h2(b1, 8));
    b2 = __builtin_elementwise_max(b2, shfl_xor_h2(b2, 8));
    b3 = __builtin_elementwise_max(b3, shfl_xor_h2(b3, 8));
    if (jg == 0) {
        H8 ob; ob.a = b0; ob.b = b1; ob.c = b2; ob.d = b3;
        *(H8*)(nf_h + ((size_t)k * MGRID + pt) * 32 + c4 * 8) = ob;
        *(H8*)(nfl + lp * 32 + c4 * 8) = ob;
    }
    __syncthreads();

    // stats: y = nf . W_out[c]; c = t&63, point-group pg = t>>6 (4 pts each)
    int c = t & 63, pg = t >> 6;
    float w[32];
#pragma unroll
    for (int i = 0; i < 32; ++i) w[i] = Wls[c * 33 + i];
    float sum = 0.f, sq = 0.f;
#pragma unroll
    for (int i = 0; i < 4; ++i) {
        int pr = pg * 4 + i;
        const H8* row = (const H8*)(nfl + pr * 32);
        H8 r0 = row[0], r1 = row[1], r2 = row[2], r3 = row[3];
        h2 hh[16] = {r0.a, r0.b, r0.c, r0.d, r1.a, r1.b, r1.c, r1.d,
                     r2.a, r2.b, r2.c, r2.d, r3.a, r3.b, r3.c, r3.d};
        float y = 0.f;
#pragma unroll
        for (int q8 = 0; q8 < 16; ++q8)
            y += (float)hh[q8].x * w[2 * q8] + (float)hh[q8].y * w[2 * q8 + 1];
        sum += y; sq += y * y;
    }
    s_[t] = sum; q_[t] = sq;
    __syncthreads();
    if (t < 512) { s_[t] += s_[t + 512]; q_[t] += q_[t + 512]; } __syncthreads();
    if (t < 256) { s_[t] += s_[t + 256]; q_[t] += q_[t + 256]; } __syncthreads();
    if (t < 128) { s_[t] += s_[t + 128]; q_[t] += q_[t + 128]; } __syncthreads();
    if (t < 64) {
        pOut[((size_t)k * 1024 + bx) * 128 + t]      = s_[t] + s_[t + 64];
        pOut[((size_t)k * 1024 + bx) * 128 + 64 + t] = q_[t] + q_[t + 64];
    }
}

__global__ __launch_bounds__(1024) void k_gather(
    const int* __restrict__ nc, const short* __restrict__ vm16,
    const _Float16* __restrict__ fraw_h, const float* __restrict__ pf,
    const float* __restrict__ ss_in, const float* __restrict__ Wout,
    _Float16* __restrict__ nf_h, float* __restrict__ pOut)
{
    __shared__ __align__(16) char smem[16640 + 4096];
    if (blockIdx.y == 0)
        gather_body<1>(0, nc, vm16, fraw_h, pf, ss_in, Wout, nf_h, pOut, smem);
    else
        gather_body<2>(1, nc, vm16, fraw_h, pf, ss_in, Wout, nf_h, pOut, smem);
}

// L4: parallel reduce pOut -> scale/shift ; one block per (k, c)
__global__ __launch_bounds__(256) void k_out_reduce(
    const float* __restrict__ pOut, const float* __restrict__ g_out,
    const float* __restrict__ b_out, float* __restrict__ ss_out)
{
    __shared__ float ss[256], qq[256];
    int b = blockIdx.x;          // 128 blocks: k = b>>6, c = b&63
    int k = b >> 6, c = b & 63;
    int t = threadIdx.x;
    float sv = 0.f, sq = 0.f;
#pragma unroll
    for (int i = 0; i < 4; ++i) {
        size_t row = (size_t)k * 1024 + t + i * 256;
        sv += pOut[row * 128 + c];
        sq += pOut[row * 128 + 64 + c];
    }
    ss[t] = sv; qq[t] = sq;
    __syncthreads();
    if (t < 128) { ss[t] += ss[t + 128]; qq[t] += qq[t + 128]; } __syncthreads();
    if (t < 64)  { ss[t] += ss[t + 64];  qq[t] += qq[t + 64];  } __syncthreads();
    if (t < 32)  { ss[t] += ss[t + 32];  qq[t] += qq[t + 32];  } __syncthreads();
    if (t == 0) {
        float fs = 0.f, fq = 0.f;
#pragma unroll
        for (int i = 0; i < 32; ++i) { fs += ss[i]; fq += qq[i]; }
        float mu  = fs / (float)MGRID;
        float var = fmaxf(fq / (float)MGRID - mu * mu, 0.f);
        float rs  = rsqrtf(var + EPSV);
        float scale = g_out[k * 64 + c] * rs;
        float shift = b_out[k * 64 + c] - mu * scale;
        ss_out[k * 128 + c]      = scale;
        ss_out[k * 128 + 64 + c] = shift;
    }
}

// L5: out[:, k*64+c] = relu(y*scale + shift)
__global__ __launch_bounds__(256) void k_out_write(
    const _Float16* __restrict__ nf_h, const float* __restrict__ Wout,
    const float* __restrict__ ss_out, float* __restrict__ out)
{
    __shared__ float Wls[64 * 33];
    int k = blockIdx.y, t = threadIdx.x;
    for (int idx = t; idx < 2048; idx += 256)
        Wls[(idx >> 5) * 33 + (idx & 31)] = Wout[k * 2048 + idx];
    __syncthreads();
    int c = t & 63, pl = t >> 6;
    float w[32];
#pragma unroll
    for (int i = 0; i < 32; ++i) w[i] = Wls[c * 33 + i];
    float scale = ss_out[k * 128 + c], shift = ss_out[k * 128 + 64 + c];
    int base = blockIdx.x * 64;
    for (int it = 0; it < 16; ++it) {
        int pt = base + it * 4 + pl;
        const H8* row = (const H8*)(nf_h + ((size_t)k * MGRID + pt) * 32);
        H8 r0 = row[0], r1 = row[1], r2 = row[2], r3 = row[3];
        h2 hh[16] = {r0.a, r0.b, r0.c, r0.d, r1.a, r1.b, r1.c, r1.d,
                     r2.a, r2.b, r2.c, r2.d, r3.a, r3.b, r3.c, r3.d};
        float y = 0.f;
#pragma unroll
        for (int q8 = 0; q8 < 16; ++q8)
            y += (float)hh[q8].x * w[2 * q8] + (float)hh[q8].y * w[2 * q8 + 1];
        float o = y * scale + shift;
        o = o > 0.f ? o : 0.f;
        out[(size_t)pt * 128 + k * 64 + c] = o;
    }
}

extern "C" void kernel_launch(void* const* d_in, const int* in_sizes, int n_in,
                              void* d_out, int out_size, void* d_ws, size_t ws_size,
                              hipStream_t stream) {
    const int*   new_coords = (const int*)d_in[4];
    const float* features   = (const float*)d_in[5];
    const int*   vm         = (const int*)d_in[6];
    const float* W_in  = (const float*)d_in[7];
    const float* g_in  = (const float*)d_in[8];
    const float* b_in  = (const float*)d_in[9];
    const float* W_pos = (const float*)d_in[10];
    const float* g_pos = (const float*)d_in[11];
    const float* b_pos = (const float*)d_in[12];
    const float* W_out = (const float*)d_in[13];
    const float* g_out = (const float*)d_in[14];
    const float* b_out = (const float*)d_in[15];
    float* out = (float*)d_out;

    char* ws = (char*)d_ws;
    float*     ss_in  = (float*)(ws);
    float*     ss_out = (float*)(ws + 512);
    float*     pIn    = (float*)(ws + 1536);
    float*     pOut   = (float*)(ws + 132608);
    _Float16*  fraw_h = (_Float16*)(ws + 1181184);
    float*     pf     = (float*)(ws + 3278464);
    short*     vm16   = (short*)(ws + 3287680);
    _Float16*  nf_h   = (_Float16*)(ws + 4836480);

    k_pre<<<NB_VM + 512 + 1, 256, 0, stream>>>(vm, features, W_in, W_pos, g_pos, b_pos,
                                               vm16, fraw_h, pIn, pf);
    k_reduce_in<<<64, 256, 0, stream>>>(pIn, g_in, b_in, ss_in, fraw_h);

    dim3 gG(MGRID / 64, 2);
    k_gather<<<gG, 1024, 0, stream>>>(new_coords, vm16, fraw_h, pf, ss_in, W_out, nf_h, pOut);

    k_out_reduce<<<128, 256, 0, stream>>>(pOut, g_out, b_out, ss_out);

    dim3 gW(MGRID / 64, 2);
    k_out_write<<<gW, 256, 0, stream>>>(nf_h, W_out, ss_out, out);
}

// Round 6
// 98.755 us; speedup vs baseline: 3.5235x; 1.1220x over previous
//
#include <hip/hip_runtime.h>

#define EPSV 1e-5f
constexpr int NPTS  = 16384;
constexpr int MGRID = 65536;
constexpr int ZD = 11, YD = 200, XD = 176;
constexpr int NVOX = 2 * ZD * YD * XD;          // 774400
constexpr int NB_VM = (NVOX / 8 + 255) / 256;   // 379 blocks for vm16 compress

typedef _Float16 h2 __attribute__((ext_vector_type(2)));
struct alignas(16) H8 { h2 a, b, c, d; };       // 8 fp16 channels

#if __has_builtin(__builtin_amdgcn_fdot2)
#define FDOT2(a, b, c) __builtin_amdgcn_fdot2((a), (b), (c), false)
#else
#define FDOT2(a, b, c) ((c) + (float)(a).x * (float)(b).x + (float)(a).y * (float)(b).y)
#endif

// ---------------------------------------------------------------------------
// ws layout (bytes):
//   0          ss_in  : float[2][{scale,shift}][32]        (512 B)
//   4096       ss_out : float[2][{scale,shift}][64]        (1 KB)
//   8192       pIn    : float[2][256][64]                  (128 KB)
//   139264     fraw_h : _Float16[2][16385][32] raw, row0=pad (2 MB)
//   2236544    pf     : float[8+64][32]                    (9216 B)
//   2245760    vm16   : short[774400]                      (1.5 MB)
//   3794560    nf_h   : _Float16[2][65536][32]             (8.4 MB)
//   12183168   pOut   : float[2][4096][128]                (4 MB)
// ---------------------------------------------------------------------------

__device__ __forceinline__ h2 shfl_xor_h2(h2 v, int m) {
    union { h2 h; int i; } u; u.h = v;
    u.i = __shfl_xor(u.i, m, 64);
    return u.h;
}

// L1: fused prelude — vm16 compress | fin matmul (raw fp16 + stats partials) | pf
__global__ __launch_bounds__(256) void k_pre(
    const int* __restrict__ vm, const float* __restrict__ features,
    const float* __restrict__ Win, const float* __restrict__ Wpos,
    const float* __restrict__ g_pos, const float* __restrict__ b_pos,
    short* __restrict__ vm16, _Float16* __restrict__ fraw_h,
    float* __restrict__ pIn, float* __restrict__ pf)
{
    __shared__ float smem[2688];
    int bid = blockIdx.x, t = threadIdx.x;

    if (bid < NB_VM) {                       // ---- vm -> int16 (8 ints/thread)
        int i = bid * 256 + t;
        if (i < NVOX / 8) {
            int4 v0 = ((const int4*)vm)[i * 2];
            int4 v1 = ((const int4*)vm)[i * 2 + 1];
            uint4 o;
            o.x = (v0.x & 0xffff) | (v0.y << 16);
            o.y = (v0.z & 0xffff) | (v0.w << 16);
            o.z = (v1.x & 0xffff) | (v1.y << 16);
            o.w = (v1.z & 0xffff) | (v1.w << 16);
            ((uint4*)vm16)[i] = o;
        }
        return;
    }
    if (bid < NB_VM + 512) {                 // ---- fin: raw y fp16 + partials
        int b2 = bid - NB_VM;
        int k = b2 >> 8, bx = b2 & 255;
        float* Wls = smem;                   // [32][68]
        float* s_  = smem + 2176;
        float* q_  = smem + 2432;
        for (int idx = t; idx < 2048; idx += 256)
            Wls[(idx >> 6) * 68 + (idx & 63)] = Win[k * 2048 + idx];
        __syncthreads();
        int c = t & 31, g = t >> 5;
        float w[64];
#pragma unroll
        for (int i4 = 0; i4 < 16; ++i4) {
            float4 wv = *(const float4*)&Wls[c * 68 + i4 * 4];
            w[i4 * 4] = wv.x; w[i4 * 4 + 1] = wv.y; w[i4 * 4 + 2] = wv.z; w[i4 * 4 + 3] = wv.w;
        }
        int base = bx * 64;
        float ssum = 0.f, ssq = 0.f;
        for (int it = 0; it < 8; ++it) {
            int pt = base + it * 8 + g;
            const float4* fr = (const float4*)(features + (size_t)pt * 64);
            float y = 0.f;
#pragma unroll
            for (int i4 = 0; i4 < 16; ++i4) {
                float4 v = fr[i4];
                y += v.x * w[i4 * 4] + v.y * w[i4 * 4 + 1] + v.z * w[i4 * 4 + 2] + v.w * w[i4 * 4 + 3];
            }
            fraw_h[((size_t)k * (NPTS + 1) + pt + 1) * 32 + c] = (_Float16)y;
            ssum += y; ssq += y * y;
        }
        s_[t] = ssum; q_[t] = ssq;
        __syncthreads();
        if (t < 32) {
            float fs = 0.f, fq = 0.f;
#pragma unroll
            for (int gg = 0; gg < 8; ++gg) { fs += s_[gg * 32 + t]; fq += q_[gg * 32 + t]; }
            float* pb = pIn + ((size_t)k * 256 + bx) * 64;
            pb[t] = fs; pb[32 + t] = fq;
        }
        return;
    }
    // ---- pf: BN over offsets of off_xyz @ W_pos^T (f32, 1 block)
    float* praw = smem;
    int pfoff = 0;
    for (int k = 0; k < 2; ++k) {
        int r = k + 1, s = 2 * r, noff = s * s * s;
        for (int idx = t; idx < noff * 32; idx += 256) {
            int j = idx >> 5, c = idx & 31;
            int xi = j % s, yi = (j / s) % s, zi = j / (s * s);
            const float* W = Wpos + (k * 32 + c) * 3;
            praw[idx] = (float)(xi - r) * W[0] + (float)(yi - r) * W[1] + (float)(zi - r) * W[2];
        }
        __syncthreads();
        if (t < 32) {
            float sum = 0.f, sq = 0.f;
            for (int j = 0; j < noff; ++j) { float v = praw[j * 32 + t]; sum += v; sq += v * v; }
            float mu  = sum / (float)noff;
            float var = fmaxf(sq / (float)noff - mu * mu, 0.f);
            float rs  = rsqrtf(var + EPSV);
            float g = g_pos[k * 32 + t], b = b_pos[k * 32 + t];
            for (int j = 0; j < noff; ++j)
                pf[pfoff + j * 32 + t] = (praw[j * 32 + t] - mu) * rs * g + b;
        }
        __syncthreads();
        pfoff += noff * 32;
    }
}

// L2: parallel reduce pIn -> scale/shift ; one block per (k, c)
__global__ __launch_bounds__(256) void k_reduce_in(
    const float* __restrict__ pIn, const float* __restrict__ g_in,
    const float* __restrict__ b_in, float* __restrict__ ss_in,
    _Float16* __restrict__ fraw_h)
{
    __shared__ float ss[256], qq[256];
    int b = blockIdx.x;          // 64 blocks: k = b>>5, c = b&31
    int k = b >> 5, c = b & 31;
    int t = threadIdx.x;
    ss[t] = pIn[((size_t)k * 256 + t) * 64 + c];
    qq[t] = pIn[((size_t)k * 256 + t) * 64 + 32 + c];
    __syncthreads();
    if (t < 128) { ss[t] += ss[t + 128]; qq[t] += qq[t + 128]; } __syncthreads();
    if (t < 64)  { ss[t] += ss[t + 64];  qq[t] += qq[t + 64];  } __syncthreads();
    if (t < 32)  { ss[t] += ss[t + 32];  qq[t] += qq[t + 32];  } __syncthreads();
    if (t == 0) {
        float sv = 0.f, sq = 0.f;
#pragma unroll
        for (int i = 0; i < 32; ++i) { sv += ss[i]; sq += qq[i]; }
        float mu  = sv / (float)NPTS;
        float var = fmaxf(sq / (float)NPTS - mu * mu, 0.f);
        float rs  = rsqrtf(var + EPSV);
        float scale = g_in[k * 32 + c] * rs;
        float shift = b_in[k * 32 + c] - mu * scale;
        ss_in[k * 64 + c]      = scale;
        ss_in[k * 64 + 32 + c] = shift;
        float pad = (scale != 0.f) ? (-shift / scale) : 0.f;
        pad = fminf(fmaxf(pad, -60000.f), 60000.f);
        fraw_h[(size_t)k * (NPTS + 1) * 32 + c] = (_Float16)pad;   // row 0
    }
}

// L3: fused gather (BOTH k) + relu-max + dot2 stats partials.
// 256 threads = 16 points x (4 jg x 4 chan-chunks). All loads batched.
__global__ __launch_bounds__(256, 4) void k_gather(
    const int* __restrict__ nc, const short* __restrict__ vm16,
    const _Float16* __restrict__ fraw_h, const float* __restrict__ pf,
    const float* __restrict__ ss_in, const float* __restrict__ Wout,
    _Float16* __restrict__ nf_h, float* __restrict__ pOut)
{
    __shared__ __align__(16) _Float16 psum1[64 * 32];   // k=1 shift+pf fp16
    __shared__ __align__(16) _Float16 psum0[8 * 32];    // k=0
    __shared__ __align__(16) h2 Wh[2 * 64 * 17];        // fp16 W_out, pad 17
    __shared__ __align__(16) _Float16 nfl[2 * 16 * 32];
    __shared__ float s0_[256], q0_[256], s1_[256], q1_[256];
    int t = threadIdx.x, bx = blockIdx.x;

    for (int i = t; i < 2048; i += 256)
        psum1[i] = (_Float16)(pf[256 + i] + ss_in[64 + 32 + (i & 31)]);
    psum0[t] = (_Float16)(pf[t] + ss_in[32 + (t & 31)]);
    for (int i = t; i < 2048; i += 256) {
        int k = i >> 10, rem = i & 1023, c = rem >> 4, q = rem & 15;
        h2 v;
        v.x = (_Float16)Wout[k * 2048 + c * 32 + 2 * q];
        v.y = (_Float16)Wout[k * 2048 + c * 32 + 2 * q + 1];
        Wh[k * (64 * 17) + c * 17 + q] = v;
    }
    __syncthreads();

    int c4 = t & 3, jg = (t >> 2) & 3, lp = t >> 4;
    int pt = bx * 16 + lp;
    int4 cc = ((const int4*)nc)[pt];
    int bb = cc.x, xc = cc.y, yc = cc.z, zc = cc.w;
    // reference quirk: fastest mesh idx -> z coord, slowest -> x coord
    int Zo[4], Xq[4];
#pragma unroll
    for (int u = 0; u < 4; ++u) {
        int zq = min(max(zc + u - 2, 0), ZD - 1);
        Zo[u] = (bb * ZD + zq) * (YD * XD);
        Xq[u] = min(max(xc + u - 2, 0), XD - 1);
    }
    int Yo1 = min(max(yc + jg - 2, 0), YD - 1) * XD;
    int pidx1[16];
#pragma unroll
    for (int pp = 0; pp < 4; ++pp)
#pragma unroll
        for (int a = 0; a < 4; ++a)
            pidx1[pp * 4 + a] = (int)vm16[Zo[pp] + Yo1 + Xq[a]];
    int zq0 = min(max(zc + (jg & 1) - 1, 0), ZD - 1);
    int yo0 = min(max(yc + (jg >> 1) - 1, 0), YD - 1) * XD;
    int zo0 = (bb * ZD + zq0) * (YD * XD);
    int pidx0[2];
#pragma unroll
    for (int a = 0; a < 2; ++a)
        pidx0[a] = (int)vm16[zo0 + yo0 + min(max(xc + a - 1, 0), XD - 1)];

    const _Float16* fr1 = fraw_h + (size_t)(NPTS + 1) * 32;
    H8 g[16];
#pragma unroll
    for (int i = 0; i < 16; ++i)
        g[i] = *(const H8*)(fr1 + (size_t)(pidx1[i] + 1) * 32 + c4 * 8);
    H8 h0 = *(const H8*)(fraw_h + (size_t)(pidx0[0] + 1) * 32 + c4 * 8);
    H8 h1 = *(const H8*)(fraw_h + (size_t)(pidx0[1] + 1) * 32 + c4 * 8);

    h2 sc1[4], sc0[4];
#pragma unroll
    for (int i = 0; i < 4; ++i) {
        sc1[i].x = (_Float16)ss_in[64 + c4 * 8 + 2 * i];
        sc1[i].y = (_Float16)ss_in[64 + c4 * 8 + 2 * i + 1];
        sc0[i].x = (_Float16)ss_in[c4 * 8 + 2 * i];
        sc0[i].y = (_Float16)ss_in[c4 * 8 + 2 * i + 1];
    }
    h2 z; z.x = (_Float16)0.f; z.y = (_Float16)0.f;
    h2 b0 = z, b1 = z, b2 = z, b3 = z;       // k=1 acc (relu folds into max)
    h2 a0 = z, a1 = z, a2 = z, a3 = z;       // k=0 acc
#pragma unroll
    for (int i = 0; i < 16; ++i) {
        int o = (i & 3) * 16 + jg * 4 + (i >> 2);
        H8 pv = *(const H8*)(psum1 + o * 32 + c4 * 8);
        b0 = __builtin_elementwise_max(b0, g[i].a * sc1[0] + pv.a);
        b1 = __builtin_elementwise_max(b1, g[i].b * sc1[1] + pv.b);
        b2 = __builtin_elementwise_max(b2, g[i].c * sc1[2] + pv.c);
        b3 = __builtin_elementwise_max(b3, g[i].d * sc1[3] + pv.d);
    }
    {
        int o0 = (jg >> 1) * 2 + (jg & 1);
        H8 pv = *(const H8*)(psum0 + o0 * 32 + c4 * 8);
        a0 = __builtin_elementwise_max(a0, h0.a * sc0[0] + pv.a);
        a1 = __builtin_elementwise_max(a1, h0.b * sc0[1] + pv.b);
        a2 = __builtin_elementwise_max(a2, h0.c * sc0[2] + pv.c);
        a3 = __builtin_elementwise_max(a3, h0.d * sc0[3] + pv.d);
        H8 pv2 = *(const H8*)(psum0 + (4 + o0) * 32 + c4 * 8);
        a0 = __builtin_elementwise_max(a0, h1.a * sc0[0] + pv2.a);
        a1 = __builtin_elementwise_max(a1, h1.b * sc0[1] + pv2.b);
        a2 = __builtin_elementwise_max(a2, h1.c * sc0[2] + pv2.c);
        a3 = __builtin_elementwise_max(a3, h1.d * sc0[3] + pv2.d);
    }
#define RED2(v) v = __builtin_elementwise_max(v, shfl_xor_h2(v, 4)); \
                v = __builtin_elementwise_max(v, shfl_xor_h2(v, 8));
    RED2(b0) RED2(b1) RED2(b2) RED2(b3)
    RED2(a0) RED2(a1) RED2(a2) RED2(a3)
#undef RED2
    if (jg == 0) {
        H8 o1; o1.a = b0; o1.b = b1; o1.c = b2; o1.d = b3;
        H8 o0; o0.a = a0; o0.b = a1; o0.c = a2; o0.d = a3;
        *(H8*)(nf_h + ((size_t)MGRID + pt) * 32 + c4 * 8) = o1;   // k=1
        *(H8*)(nf_h + (size_t)pt * 32 + c4 * 8) = o0;             // k=0
        *(H8*)(nfl + (16 + lp) * 32 + c4 * 8) = o1;
        *(H8*)(nfl + lp * 32 + c4 * 8) = o0;
    }
    __syncthreads();

    // stats: y_k = nf_k . W_k[c] via v_dot2_f32_f16, per-block sum/sumsq
    int c = t & 63, pg = t >> 6;
    float s0 = 0.f, q0 = 0.f, s1 = 0.f, q1 = 0.f;
    const h2* w0 = &Wh[c * 17];
    const h2* w1 = &Wh[64 * 17 + c * 17];
#pragma unroll
    for (int i = 0; i < 4; ++i) {
        int p = pg * 4 + i;
        const H8* r0p = (const H8*)(nfl + p * 32);
        const H8* r1p = (const H8*)(nfl + (16 + p) * 32);
        H8 ra = r0p[0], rb = r0p[1], rc = r0p[2], rd = r0p[3];
        H8 sa = r1p[0], sb = r1p[1], sc_ = r1p[2], sd = r1p[3];
        h2 u0[16] = {ra.a, ra.b, ra.c, ra.d, rb.a, rb.b, rb.c, rb.d,
                     rc.a, rc.b, rc.c, rc.d, rd.a, rd.b, rd.c, rd.d};
        h2 u1[16] = {sa.a, sa.b, sa.c, sa.d, sb.a, sb.b, sb.c, sb.d,
                     sc_.a, sc_.b, sc_.c, sc_.d, sd.a, sd.b, sd.c, sd.d};
        float y0 = 0.f, y1 = 0.f;
#pragma unroll
        for (int iq = 0; iq < 16; ++iq) {
            y0 = FDOT2(u0[iq], w0[iq], y0);
            y1 = FDOT2(u1[iq], w1[iq], y1);
        }
        s0 += y0; q0 += y0 * y0; s1 += y1; q1 += y1 * y1;
    }
    s0_[t] = s0; q0_[t] = q0; s1_[t] = s1; q1_[t] = q1;
    __syncthreads();
    if (t < 128) {
        s0_[t] += s0_[t + 128]; q0_[t] += q0_[t + 128];
        s1_[t] += s1_[t + 128]; q1_[t] += q1_[t + 128];
    }
    __syncthreads();
    if (t < 64) {
        pOut[(size_t)bx * 128 + t]                       = s0_[t] + s0_[t + 64];
        pOut[(size_t)bx * 128 + 64 + t]                  = q0_[t] + q0_[t + 64];
        pOut[((size_t)4096 + bx) * 128 + t]              = s1_[t] + s1_[t + 64];
        pOut[((size_t)4096 + bx) * 128 + 64 + t]         = q1_[t] + q1_[t + 64];
    }
}

// L4: parallel reduce pOut -> scale/shift ; one block per (k, c)
__global__ __launch_bounds__(256) void k_out_reduce(
    const float* __restrict__ pOut, const float* __restrict__ g_out,
    const float* __restrict__ b_out, float* __restrict__ ss_out)
{
    __shared__ float ss[256], qq[256];
    int b = blockIdx.x;          // 128 blocks: k = b>>6, c = b&63
    int k = b >> 6, c = b & 63;
    int t = threadIdx.x;
    float sv = 0.f, sq = 0.f;
#pragma unroll
    for (int i = 0; i < 16; ++i) {
        size_t row = (size_t)k * 4096 + t + i * 256;
        sv += pOut[row * 128 + c];
        sq += pOut[row * 128 + 64 + c];
    }
    ss[t] = sv; qq[t] = sq;
    __syncthreads();
    if (t < 128) { ss[t] += ss[t + 128]; qq[t] += qq[t + 128]; } __syncthreads();
    if (t < 64)  { ss[t] += ss[t + 64];  qq[t] += qq[t + 64];  } __syncthreads();
    if (t < 32)  { ss[t] += ss[t + 32];  qq[t] += qq[t + 32];  } __syncthreads();
    if (t == 0) {
        float fs = 0.f, fq = 0.f;
#pragma unroll
        for (int i = 0; i < 32; ++i) { fs += ss[i]; fq += qq[i]; }
        float mu  = fs / (float)MGRID;
        float var = fmaxf(fq / (float)MGRID - mu * mu, 0.f);
        float rs  = rsqrtf(var + EPSV);
        float scale = g_out[k * 64 + c] * rs;
        float shift = b_out[k * 64 + c] - mu * scale;
        ss_out[k * 128 + c]      = scale;
        ss_out[k * 128 + 64 + c] = shift;
    }
}

// L5: out[:, k*64+c] = relu(y*scale + shift), dot2 matmul
__global__ __launch_bounds__(256) void k_out_write(
    const _Float16* __restrict__ nf_h, const float* __restrict__ Wout,
    const float* __restrict__ ss_out, float* __restrict__ out)
{
    __shared__ h2 Wh[64 * 17];
    int k = blockIdx.y, t = threadIdx.x;
    for (int i = t; i < 1024; i += 256) {
        int c = i >> 4, q = i & 15;
        h2 v;
        v.x = (_Float16)Wout[k * 2048 + c * 32 + 2 * q];
        v.y = (_Float16)Wout[k * 2048 + c * 32 + 2 * q + 1];
        Wh[c * 17 + q] = v;
    }
    __syncthreads();
    int c = t & 63, pl = t >> 6;
    float scale = ss_out[k * 128 + c], shift = ss_out[k * 128 + 64 + c];
    const h2* w = &Wh[c * 17];
    int base = blockIdx.x * 64;
    for (int it = 0; it < 16; ++it) {
        int pt = base + it * 4 + pl;
        const H8* row = (const H8*)(nf_h + ((size_t)k * MGRID + pt) * 32);
        H8 r0 = row[0], r1 = row[1], r2 = row[2], r3 = row[3];
        h2 hh[16] = {r0.a, r0.b, r0.c, r0.d, r1.a, r1.b, r1.c, r1.d,
                     r2.a, r2.b, r2.c, r2.d, r3.a, r3.b, r3.c, r3.d};
        float y = 0.f;
#pragma unroll
        for (int iq = 0; iq < 16; ++iq) y = FDOT2(hh[iq], w[iq], y);
        float o = y * scale + shift;
        out[(size_t)pt * 128 + k * 64 + c] = o > 0.f ? o : 0.f;
    }
}

extern "C" void kernel_launch(void* const* d_in, const int* in_sizes, int n_in,
                              void* d_out, int out_size, void* d_ws, size_t ws_size,
                              hipStream_t stream) {
    const int*   new_coords = (const int*)d_in[4];
    const float* features   = (const float*)d_in[5];
    const int*   vm         = (const int*)d_in[6];
    const float* W_in  = (const float*)d_in[7];
    const float* g_in  = (const float*)d_in[8];
    const float* b_in  = (const float*)d_in[9];
    const float* W_pos = (const float*)d_in[10];
    const float* g_pos = (const float*)d_in[11];
    const float* b_pos = (const float*)d_in[12];
    const float* W_out = (const float*)d_in[13];
    const float* g_out = (const float*)d_in[14];
    const float* b_out = (const float*)d_in[15];
    float* out = (float*)d_out;

    char* ws = (char*)d_ws;
    float*     ss_in  = (float*)(ws);
    float*     ss_out = (float*)(ws + 4096);
    float*     pIn    = (float*)(ws + 8192);
    _Float16*  fraw_h = (_Float16*)(ws + 139264);
    float*     pf     = (float*)(ws + 2236544);
    short*     vm16   = (short*)(ws + 2245760);
    _Float16*  nf_h   = (_Float16*)(ws + 3794560);
    float*     pOut   = (float*)(ws + 12183168);

    k_pre<<<NB_VM + 512 + 1, 256, 0, stream>>>(vm, features, W_in, W_pos, g_pos, b_pos,
                                               vm16, fraw_h, pIn, pf);
    k_reduce_in<<<64, 256, 0, stream>>>(pIn, g_in, b_in, ss_in, fraw_h);

    k_gather<<<MGRID / 16, 256, 0, stream>>>(new_coords, vm16, fraw_h, pf, ss_in,
                                             W_out, nf_h, pOut);

    k_out_reduce<<<128, 256, 0, stream>>>(pOut, g_out, b_out, ss_out);

    dim3 gW(MGRID / 64, 2);
    k_out_write<<<gW, 256, 0, stream>>>(nf_h, W_out, ss_out, out);
}

// Round 7
// 98.268 us; speedup vs baseline: 3.5410x; 1.0050x over previous
//
#include <hip/hip_runtime.h>

#define EPSV 1e-5f
constexpr int NPTS  = 16384;
constexpr int MGRID = 65536;
constexpr int ZD = 11, YD = 200, XD = 176;
constexpr int NVOX = 2 * ZD * YD * XD;          // 774400
constexpr int NB_VM = (NVOX / 8 + 255) / 256;   // 379 blocks for vm16 compress

typedef _Float16 h2  __attribute__((ext_vector_type(2)));
typedef _Float16 h8v __attribute__((ext_vector_type(8)));
struct alignas(16) H8 { h2 a, b, c, d; };       // 8 fp16 channels (LDS view)

#if __has_builtin(__builtin_amdgcn_fdot2)
#define FDOT2(a, b, c) __builtin_amdgcn_fdot2((a), (b), (c), false)
#else
#define FDOT2(a, b, c) ((c) + (float)(a).x * (float)(b).x + (float)(a).y * (float)(b).y)
#endif

// ---------------------------------------------------------------------------
// ws layout (bytes):
//   0          ss_in  : float[2][{scale,shift}][32]        (512 B)
//   4096       ss_out : float[2][{scale,shift}][64]        (1 KB)
//   8192       pIn    : float[2][256][64]                  (128 KB)
//   139264     fraw_h : _Float16[2][16385][32] raw, row0=pad (2 MB)
//   2236544    pf     : float[8+64][32]                    (9216 B)
//   2245760    vm16   : short[774400]                      (1.5 MB)
//   3794560    nf_h   : _Float16[2][65536][32]             (8.4 MB)
//   12183168   pOut   : float[2][4096][128]                (4 MB)
// ---------------------------------------------------------------------------

// ---- inline-asm batched loads: guarantees N loads in flight (the compiler
// ---- refused to at source level: VGPR_Count=56 in r6 proves re-serialization)
__device__ __forceinline__ h8v gload_h8(const _Float16* p) {
    h8v r;
    asm volatile("global_load_dwordx4 %0, %1, off" : "=v"(r) : "v"(p));
    return r;
}
__device__ __forceinline__ unsigned gload_u16(const short* p) {
    unsigned r;
    asm volatile("global_load_ushort %0, %1, off" : "=v"(r) : "v"(p));
    return r;
}
__device__ __forceinline__ void vm_wait0() {
    asm volatile("s_waitcnt vmcnt(0)" ::: "memory");
    __builtin_amdgcn_sched_barrier(0);   // rule #18: keep reg-only ops below
}
__device__ __forceinline__ h8v zero8() {
    h8v z;
#pragma unroll
    for (int i = 0; i < 8; ++i) z[i] = (_Float16)0.f;
    return z;
}
__device__ __forceinline__ h8v shfl_xor_h8(h8v v, int m) {
    union { h8v h; int4 i; } u; u.h = v;
    u.i.x = __shfl_xor(u.i.x, m, 64);
    u.i.y = __shfl_xor(u.i.y, m, 64);
    u.i.z = __shfl_xor(u.i.z, m, 64);
    u.i.w = __shfl_xor(u.i.w, m, 64);
    return u.h;
}

// L1: fused prelude — vm16 compress | fin matmul (raw fp16 + stats partials) | pf
__global__ __launch_bounds__(256) void k_pre(
    const int* __restrict__ vm, const float* __restrict__ features,
    const float* __restrict__ Win, const float* __restrict__ Wpos,
    const float* __restrict__ g_pos, const float* __restrict__ b_pos,
    short* __restrict__ vm16, _Float16* __restrict__ fraw_h,
    float* __restrict__ pIn, float* __restrict__ pf)
{
    __shared__ float smem[2688];
    int bid = blockIdx.x, t = threadIdx.x;

    if (bid < NB_VM) {                       // ---- vm -> int16 (8 ints/thread)
        int i = bid * 256 + t;
        if (i < NVOX / 8) {
            int4 v0 = ((const int4*)vm)[i * 2];
            int4 v1 = ((const int4*)vm)[i * 2 + 1];
            uint4 o;
            o.x = (v0.x & 0xffff) | (v0.y << 16);
            o.y = (v0.z & 0xffff) | (v0.w << 16);
            o.z = (v1.x & 0xffff) | (v1.y << 16);
            o.w = (v1.z & 0xffff) | (v1.w << 16);
            ((uint4*)vm16)[i] = o;
        }
        return;
    }
    if (bid < NB_VM + 512) {                 // ---- fin: raw y fp16 + partials
        int b2 = bid - NB_VM;
        int k = b2 >> 8, bx = b2 & 255;
        float* Wls = smem;                   // [32][68]
        float* s_  = smem + 2176;
        float* q_  = smem + 2432;
        for (int idx = t; idx < 2048; idx += 256)
            Wls[(idx >> 6) * 68 + (idx & 63)] = Win[k * 2048 + idx];
        __syncthreads();
        int c = t & 31, g = t >> 5;
        float w[64];
#pragma unroll
        for (int i4 = 0; i4 < 16; ++i4) {
            float4 wv = *(const float4*)&Wls[c * 68 + i4 * 4];
            w[i4 * 4] = wv.x; w[i4 * 4 + 1] = wv.y; w[i4 * 4 + 2] = wv.z; w[i4 * 4 + 3] = wv.w;
        }
        int base = bx * 64;
        float ssum = 0.f, ssq = 0.f;
        for (int it = 0; it < 8; ++it) {
            int pt = base + it * 8 + g;
            const float4* fr = (const float4*)(features + (size_t)pt * 64);
            float y = 0.f;
#pragma unroll
            for (int i4 = 0; i4 < 16; ++i4) {
                float4 v = fr[i4];
                y += v.x * w[i4 * 4] + v.y * w[i4 * 4 + 1] + v.z * w[i4 * 4 + 2] + v.w * w[i4 * 4 + 3];
            }
            fraw_h[((size_t)k * (NPTS + 1) + pt + 1) * 32 + c] = (_Float16)y;
            ssum += y; ssq += y * y;
        }
        s_[t] = ssum; q_[t] = ssq;
        __syncthreads();
        if (t < 32) {
            float fs = 0.f, fq = 0.f;
#pragma unroll
            for (int gg = 0; gg < 8; ++gg) { fs += s_[gg * 32 + t]; fq += q_[gg * 32 + t]; }
            float* pb = pIn + ((size_t)k * 256 + bx) * 64;
            pb[t] = fs; pb[32 + t] = fq;
        }
        return;
    }
    // ---- pf: BN over offsets of off_xyz @ W_pos^T (f32, 1 block)
    float* praw = smem;
    int pfoff = 0;
    for (int k = 0; k < 2; ++k) {
        int r = k + 1, s = 2 * r, noff = s * s * s;
        for (int idx = t; idx < noff * 32; idx += 256) {
            int j = idx >> 5, c = idx & 31;
            int xi = j % s, yi = (j / s) % s, zi = j / (s * s);
            const float* W = Wpos + (k * 32 + c) * 3;
            praw[idx] = (float)(xi - r) * W[0] + (float)(yi - r) * W[1] + (float)(zi - r) * W[2];
        }
        __syncthreads();
        if (t < 32) {
            float sum = 0.f, sq = 0.f;
            for (int j = 0; j < noff; ++j) { float v = praw[j * 32 + t]; sum += v; sq += v * v; }
            float mu  = sum / (float)noff;
            float var = fmaxf(sq / (float)noff - mu * mu, 0.f);
            float rs  = rsqrtf(var + EPSV);
            float g = g_pos[k * 32 + t], b = b_pos[k * 32 + t];
            for (int j = 0; j < noff; ++j)
                pf[pfoff + j * 32 + t] = (praw[j * 32 + t] - mu) * rs * g + b;
        }
        __syncthreads();
        pfoff += noff * 32;
    }
}

// L2: parallel reduce pIn -> scale/shift ; one block per (k, c)
__global__ __launch_bounds__(256) void k_reduce_in(
    const float* __restrict__ pIn, const float* __restrict__ g_in,
    const float* __restrict__ b_in, float* __restrict__ ss_in,
    _Float16* __restrict__ fraw_h)
{
    __shared__ float ss[256], qq[256];
    int b = blockIdx.x;          // 64 blocks: k = b>>5, c = b&31
    int k = b >> 5, c = b & 31;
    int t = threadIdx.x;
    ss[t] = pIn[((size_t)k * 256 + t) * 64 + c];
    qq[t] = pIn[((size_t)k * 256 + t) * 64 + 32 + c];
    __syncthreads();
    if (t < 128) { ss[t] += ss[t + 128]; qq[t] += qq[t + 128]; } __syncthreads();
    if (t < 64)  { ss[t] += ss[t + 64];  qq[t] += qq[t + 64];  } __syncthreads();
    if (t < 32)  { ss[t] += ss[t + 32];  qq[t] += qq[t + 32];  } __syncthreads();
    if (t == 0) {
        float sv = 0.f, sq = 0.f;
#pragma unroll
        for (int i = 0; i < 32; ++i) { sv += ss[i]; sq += qq[i]; }
        float mu  = sv / (float)NPTS;
        float var = fmaxf(sq / (float)NPTS - mu * mu, 0.f);
        float rs  = rsqrtf(var + EPSV);
        float scale = g_in[k * 32 + c] * rs;
        float shift = b_in[k * 32 + c] - mu * scale;
        ss_in[k * 64 + c]      = scale;
        ss_in[k * 64 + 32 + c] = shift;
        float pad = (scale != 0.f) ? (-shift / scale) : 0.f;
        pad = fminf(fmaxf(pad, -60000.f), 60000.f);
        fraw_h[(size_t)k * (NPTS + 1) * 32 + c] = (_Float16)pad;   // row 0
    }
}

// L3: fused gather (BOTH k) + relu-max + dot2 stats partials.
// 256 threads = 16 points x (4 jg x 4 chan-chunks). ASM-batched loads:
// 18 pidx loads in flight, then 18 row gathers in flight, per lane.
__global__ __launch_bounds__(256, 3) void k_gather(
    const int* __restrict__ nc, const short* __restrict__ vm16,
    const _Float16* __restrict__ fraw_h, const float* __restrict__ pf,
    const float* __restrict__ ss_in, const float* __restrict__ Wout,
    _Float16* __restrict__ nf_h, float* __restrict__ pOut)
{
    __shared__ __align__(16) _Float16 psum1[64 * 32];   // k=1 shift+pf fp16
    __shared__ __align__(16) _Float16 psum0[8 * 32];    // k=0
    __shared__ __align__(16) h2 Wh[2 * 64 * 17];        // fp16 W_out, pad 17
    __shared__ __align__(16) _Float16 nfl[2 * 16 * 32];
    __shared__ float s0_[256], q0_[256], s1_[256], q1_[256];
    int t = threadIdx.x, bx = blockIdx.x;
    int c4 = t & 3, jg = (t >> 2) & 3, lp = t >> 4;
    int pt = bx * 16 + lp;

    // ---- coords + all voxel-map addresses (consume cc BEFORE any asm load)
    int4 cc = ((const int4*)nc)[pt];
    int bb = cc.x, xc = cc.y, yc = cc.z, zc = cc.w;
    // reference quirk: fastest mesh idx -> z coord, slowest -> x coord
    int Zo[4], Xq[4];
#pragma unroll
    for (int u = 0; u < 4; ++u) {
        int zq = min(max(zc + u - 2, 0), ZD - 1);
        Zo[u] = (bb * ZD + zq) * (YD * XD);
        Xq[u] = min(max(xc + u - 2, 0), XD - 1);
    }
    int Yo1 = min(max(yc + jg - 2, 0), YD - 1) * XD;
    int zq0 = min(max(zc + (jg & 1) - 1, 0), ZD - 1);
    int yo0 = min(max(yc + (jg >> 1) - 1, 0), YD - 1) * XD;
    int zo0 = (bb * ZD + zq0) * (YD * XD);
    int x0a = min(max(xc - 1, 0), XD - 1);
    int x0b = min(max(xc, 0), XD - 1);
    __builtin_amdgcn_sched_barrier(0);   // pin addr computes above asm loads

    // ---- phase A: 18 pidx loads in flight (latency hides under LDS staging)
    unsigned u1[16], u0[2];
#pragma unroll
    for (int pp = 0; pp < 4; ++pp)
#pragma unroll
        for (int a = 0; a < 4; ++a)
            u1[pp * 4 + a] = gload_u16(vm16 + Zo[pp] + Yo1 + Xq[a]);
    u0[0] = gload_u16(vm16 + zo0 + yo0 + x0a);
    u0[1] = gload_u16(vm16 + zo0 + yo0 + x0b);

    // ---- LDS staging (independent of phase A results)
    for (int i = t; i < 2048; i += 256)
        psum1[i] = (_Float16)(pf[256 + i] + ss_in[64 + 32 + (i & 31)]);
    psum0[t] = (_Float16)(pf[t] + ss_in[32 + (t & 31)]);
    for (int i = t; i < 2048; i += 256) {
        int k = i >> 10, rem = i & 1023, c = rem >> 4, q = rem & 15;
        h2 v;
        v.x = (_Float16)Wout[k * 2048 + c * 32 + 2 * q];
        v.y = (_Float16)Wout[k * 2048 + c * 32 + 2 * q + 1];
        Wh[k * (64 * 17) + c * 17 + q] = v;
    }
    __syncthreads();
    vm_wait0();                          // pidx ready

    // ---- phase B: 18 row gathers in flight
    const _Float16* fr1 = fraw_h + (size_t)(NPTS + 1) * 32;
    h8v g1[16], g0[2];
#pragma unroll
    for (int i = 0; i < 16; ++i) {
        unsigned row = (u1[i] + 1) & 0xFFFFu;    // -1 (0xFFFF) -> pad row 0
        g1[i] = gload_h8(fr1 + (size_t)row * 32 + c4 * 8);
    }
#pragma unroll
    for (int a = 0; a < 2; ++a) {
        unsigned row = (u0[a] + 1) & 0xFFFFu;
        g0[a] = gload_h8(fraw_h + (size_t)row * 32 + c4 * 8);
    }
    vm_wait0();                          // rows ready

    // ---- phase C: scale + add(psum) + relu-max (relu folds into max)
    h8v sc1v, sc0v;
#pragma unroll
    for (int i = 0; i < 8; ++i) {
        sc1v[i] = (_Float16)ss_in[64 + c4 * 8 + i];
        sc0v[i] = (_Float16)ss_in[c4 * 8 + i];
    }
    h8v acc1 = zero8(), acc0 = zero8();
#pragma unroll
    for (int i = 0; i < 16; ++i) {
        int o = (i & 3) * 16 + jg * 4 + (i >> 2);
        h8v pv = *(const h8v*)(psum1 + o * 32 + c4 * 8);
        acc1 = __builtin_elementwise_max(acc1, g1[i] * sc1v + pv);
    }
    {
        h8v pv = *(const h8v*)(psum0 + jg * 32 + c4 * 8);
        acc0 = __builtin_elementwise_max(acc0, g0[0] * sc0v + pv);
        h8v pv2 = *(const h8v*)(psum0 + (4 + jg) * 32 + c4 * 8);
        acc0 = __builtin_elementwise_max(acc0, g0[1] * sc0v + pv2);
    }
    acc1 = __builtin_elementwise_max(acc1, shfl_xor_h8(acc1, 4));
    acc1 = __builtin_elementwise_max(acc1, shfl_xor_h8(acc1, 8));
    acc0 = __builtin_elementwise_max(acc0, shfl_xor_h8(acc0, 4));
    acc0 = __builtin_elementwise_max(acc0, shfl_xor_h8(acc0, 8));
    if (jg == 0) {
        *(h8v*)(nf_h + ((size_t)MGRID + pt) * 32 + c4 * 8) = acc1;   // k=1
        *(h8v*)(nf_h + (size_t)pt * 32 + c4 * 8) = acc0;             // k=0
        *(h8v*)(nfl + (16 + lp) * 32 + c4 * 8) = acc1;
        *(h8v*)(nfl + lp * 32 + c4 * 8) = acc0;
    }
    __syncthreads();

    // ---- stats: y_k = nf_k . W_k[c] via v_dot2_f32_f16, per-block sum/sumsq
    int c = t & 63, pg = t >> 6;
    float s0 = 0.f, q0 = 0.f, s1 = 0.f, q1 = 0.f;
    const h2* w0 = &Wh[c * 17];
    const h2* w1 = &Wh[64 * 17 + c * 17];
#pragma unroll
    for (int i = 0; i < 4; ++i) {
        int p = pg * 4 + i;
        const H8* r0p = (const H8*)(nfl + p * 32);
        const H8* r1p = (const H8*)(nfl + (16 + p) * 32);
        H8 ra = r0p[0], rb = r0p[1], rc = r0p[2], rd = r0p[3];
        H8 sa = r1p[0], sb = r1p[1], sc_ = r1p[2], sd = r1p[3];
        h2 u0v[16] = {ra.a, ra.b, ra.c, ra.d, rb.a, rb.b, rb.c, rb.d,
                      rc.a, rc.b, rc.c, rc.d, rd.a, rd.b, rd.c, rd.d};
        h2 u1v[16] = {sa.a, sa.b, sa.c, sa.d, sb.a, sb.b, sb.c, sb.d,
                      sc_.a, sc_.b, sc_.c, sc_.d, sd.a, sd.b, sd.c, sd.d};
        float y0 = 0.f, y1 = 0.f;
#pragma unroll
        for (int iq = 0; iq < 16; ++iq) {
            y0 = FDOT2(u0v[iq], w0[iq], y0);
            y1 = FDOT2(u1v[iq], w1[iq], y1);
        }
        s0 += y0; q0 += y0 * y0; s1 += y1; q1 += y1 * y1;
    }
    s0_[t] = s0; q0_[t] = q0; s1_[t] = s1; q1_[t] = q1;
    __syncthreads();
    if (t < 128) {
        s0_[t] += s0_[t + 128]; q0_[t] += q0_[t + 128];
        s1_[t] += s1_[t + 128]; q1_[t] += q1_[t + 128];
    }
    __syncthreads();
    if (t < 64) {
        pOut[(size_t)bx * 128 + t]               = s0_[t] + s0_[t + 64];
        pOut[(size_t)bx * 128 + 64 + t]          = q0_[t] + q0_[t + 64];
        pOut[((size_t)4096 + bx) * 128 + t]      = s1_[t] + s1_[t + 64];
        pOut[((size_t)4096 + bx) * 128 + 64 + t] = q1_[t] + q1_[t + 64];
    }
}

// L4: parallel reduce pOut -> scale/shift ; one block per (k, c)
__global__ __launch_bounds__(256) void k_out_reduce(
    const float* __restrict__ pOut, const float* __restrict__ g_out,
    const float* __restrict__ b_out, float* __restrict__ ss_out)
{
    __shared__ float ss[256], qq[256];
    int b = blockIdx.x;          // 128 blocks: k = b>>6, c = b&63
    int k = b >> 6, c = b & 63;
    int t = threadIdx.x;
    float sv = 0.f, sq = 0.f;
#pragma unroll
    for (int i = 0; i < 16; ++i) {
        size_t row = (size_t)k * 4096 + t + i * 256;
        sv += pOut[row * 128 + c];
        sq += pOut[row * 128 + 64 + c];
    }
    ss[t] = sv; qq[t] = sq;
    __syncthreads();
    if (t < 128) { ss[t] += ss[t + 128]; qq[t] += qq[t + 128]; } __syncthreads();
    if (t < 64)  { ss[t] += ss[t + 64];  qq[t] += qq[t + 64];  } __syncthreads();
    if (t < 32)  { ss[t] += ss[t + 32];  qq[t] += qq[t + 32];  } __syncthreads();
    if (t == 0) {
        float fs = 0.f, fq = 0.f;
#pragma unroll
        for (int i = 0; i < 32; ++i) { fs += ss[i]; fq += qq[i]; }
        float mu  = fs / (float)MGRID;
        float var = fmaxf(fq / (float)MGRID - mu * mu, 0.f);
        float rs  = rsqrtf(var + EPSV);
        float scale = g_out[k * 64 + c] * rs;
        float shift = b_out[k * 64 + c] - mu * scale;
        ss_out[k * 128 + c]      = scale;
        ss_out[k * 128 + 64 + c] = shift;
    }
}

// L5: out[:, k*64+c] = relu(y*scale + shift), dot2 matmul
__global__ __launch_bounds__(256) void k_out_write(
    const _Float16* __restrict__ nf_h, const float* __restrict__ Wout,
    const float* __restrict__ ss_out, float* __restrict__ out)
{
    __shared__ h2 Wh[64 * 17];
    int k = blockIdx.y, t = threadIdx.x;
    for (int i = t; i < 1024; i += 256) {
        int c = i >> 4, q = i & 15;
        h2 v;
        v.x = (_Float16)Wout[k * 2048 + c * 32 + 2 * q];
        v.y = (_Float16)Wout[k * 2048 + c * 32 + 2 * q + 1];
        Wh[c * 17 + q] = v;
    }
    __syncthreads();
    int c = t & 63, pl = t >> 6;
    float scale = ss_out[k * 128 + c], shift = ss_out[k * 128 + 64 + c];
    const h2* w = &Wh[c * 17];
    int base = blockIdx.x * 64;
    for (int it = 0; it < 16; ++it) {
        int pt = base + it * 4 + pl;
        const H8* row = (const H8*)(nf_h + ((size_t)k * MGRID + pt) * 32);
        H8 r0 = row[0], r1 = row[1], r2 = row[2], r3 = row[3];
        h2 hh[16] = {r0.a, r0.b, r0.c, r0.d, r1.a, r1.b, r1.c, r1.d,
                     r2.a, r2.b, r2.c, r2.d, r3.a, r3.b, r3.c, r3.d};
        float y = 0.f;
#pragma unroll
        for (int iq = 0; iq < 16; ++iq) y = FDOT2(hh[iq], w[iq], y);
        float o = y * scale + shift;
        out[(size_t)pt * 128 + k * 64 + c] = o > 0.f ? o : 0.f;
    }
}

extern "C" void kernel_launch(void* const* d_in, const int* in_sizes, int n_in,
                              void* d_out, int out_size, void* d_ws, size_t ws_size,
                              hipStream_t stream) {
    const int*   new_coords = (const int*)d_in[4];
    const float* features   = (const float*)d_in[5];
    const int*   vm         = (const int*)d_in[6];
    const float* W_in  = (const float*)d_in[7];
    const float* g_in  = (const float*)d_in[8];
    const float* b_in  = (const float*)d_in[9];
    const float* W_pos = (const float*)d_in[10];
    const float* g_pos = (const float*)d_in[11];
    const float* b_pos = (const float*)d_in[12];
    const float* W_out = (const float*)d_in[13];
    const float* g_out = (const float*)d_in[14];
    const float* b_out = (const float*)d_in[15];
    float* out = (float*)d_out;

    char* ws = (char*)d_ws;
    float*     ss_in  = (float*)(ws);
    float*     ss_out = (float*)(ws + 4096);
    float*     pIn    = (float*)(ws + 8192);
    _Float16*  fraw_h = (_Float16*)(ws + 139264);
    float*     pf     = (float*)(ws + 2236544);
    short*     vm16   = (short*)(ws + 2245760);
    _Float16*  nf_h   = (_Float16*)(ws + 3794560);
    float*     pOut   = (float*)(ws + 12183168);

    k_pre<<<NB_VM + 512 + 1, 256, 0, stream>>>(vm, features, W_in, W_pos, g_pos, b_pos,
                                               vm16, fraw_h, pIn, pf);
    k_reduce_in<<<64, 256, 0, stream>>>(pIn, g_in, b_in, ss_in, fraw_h);

    k_gather<<<MGRID / 16, 256, 0, stream>>>(new_coords, vm16, fraw_h, pf, ss_in,
                                             W_out, nf_h, pOut);

    k_out_reduce<<<128, 256, 0, stream>>>(pOut, g_out, b_out, ss_out);

    dim3 gW(MGRID / 64, 2);
    k_out_write<<<gW, 256, 0, stream>>>(nf_h, W_out, ss_out, out);
}

// Round 8
// 96.877 us; speedup vs baseline: 3.5918x; 1.0144x over previous
//
#include <hip/hip_runtime.h>

#define EPSV 1e-5f
constexpr int NPTS  = 16384;
constexpr int MGRID = 65536;
constexpr int ZD = 11, YD = 200, XD = 176;
constexpr int NVOX = 2 * ZD * YD * XD;          // 774400
constexpr int NB_VM = (NVOX / 8 + 255) / 256;   // 379 blocks for vm16 compress

typedef _Float16 h2  __attribute__((ext_vector_type(2)));
typedef _Float16 h8v __attribute__((ext_vector_type(8)));
struct alignas(16) H8 { h2 a, b, c, d; };       // 8 fp16 channels (LDS view)

#if __has_builtin(__builtin_amdgcn_fdot2)
#define FDOT2(a, b, c) __builtin_amdgcn_fdot2((a), (b), (c), false)
#else
#define FDOT2(a, b, c) ((c) + (float)(a).x * (float)(b).x + (float)(a).y * (float)(b).y)
#endif

// ---------------------------------------------------------------------------
// ws layout (bytes):
//   0          ss_in  : float[2][{scale,shift}][32]        (512 B)
//   4096       ss_out : float[2][{scale,shift}][64]        (1 KB)
//   8192       pIn    : float[2][256][64]                  (128 KB)
//   139264     fraw_h : _Float16[2][16385][32] raw, row0=pad (2 MB)
//   2236544    pf     : float[8+64][32]                    (9216 B)
//   2245760    vm16   : short[774400]                      (1.5 MB)
//   3794560    nf_h   : _Float16[2][65536][32]             (8.4 MB)
//   12183168   pOut   : float[2][4096][128]                (4 MB)
// ---------------------------------------------------------------------------

__device__ __forceinline__ h8v gload_h8(const _Float16* p) {
    h8v r;
    asm volatile("global_load_dwordx4 %0, %1, off" : "=v"(r) : "v"(p));
    return r;
}
__device__ __forceinline__ uint4 gload_u128(const void* p) {
    uint4 r;
    asm volatile("global_load_dwordx4 %0, %1, off" : "=v"(r) : "v"(p));
    return r;
}
__device__ __forceinline__ uint2 gload_u64(const void* p) {
    uint2 r;
    asm volatile("global_load_dwordx2 %0, %1, off" : "=v"(r) : "v"(p));
    return r;
}
__device__ __forceinline__ void vm_wait0() {
    asm volatile("s_waitcnt vmcnt(0)" ::: "memory");
    __builtin_amdgcn_sched_barrier(0);   // rule #18: keep reg-only ops below
}
__device__ __forceinline__ h8v zero8() {
    h8v z;
#pragma unroll
    for (int i = 0; i < 8; ++i) z[i] = (_Float16)0.f;
    return z;
}
__device__ __forceinline__ h8v shfl_xor_h8(h8v v, int m) {
    union { h8v h; int4 i; } u; u.h = v;
    u.i.x = __shfl_xor(u.i.x, m, 64);
    u.i.y = __shfl_xor(u.i.y, m, 64);
    u.i.z = __shfl_xor(u.i.z, m, 64);
    u.i.w = __shfl_xor(u.i.w, m, 64);
    return u.h;
}

// L1: fused prelude — vm16 compress | fin matmul (raw fp16 + stats partials) | pf
__global__ __launch_bounds__(256) void k_pre(
    const int* __restrict__ vm, const float* __restrict__ features,
    const float* __restrict__ Win, const float* __restrict__ Wpos,
    const float* __restrict__ g_pos, const float* __restrict__ b_pos,
    short* __restrict__ vm16, _Float16* __restrict__ fraw_h,
    float* __restrict__ pIn, float* __restrict__ pf)
{
    __shared__ float smem[2688];
    int bid = blockIdx.x, t = threadIdx.x;

    if (bid < NB_VM) {                       // ---- vm -> int16 (8 ints/thread)
        int i = bid * 256 + t;
        if (i < NVOX / 8) {
            int4 v0 = ((const int4*)vm)[i * 2];
            int4 v1 = ((const int4*)vm)[i * 2 + 1];
            uint4 o;
            o.x = (v0.x & 0xffff) | (v0.y << 16);
            o.y = (v0.z & 0xffff) | (v0.w << 16);
            o.z = (v1.x & 0xffff) | (v1.y << 16);
            o.w = (v1.z & 0xffff) | (v1.w << 16);
            ((uint4*)vm16)[i] = o;
        }
        return;
    }
    if (bid < NB_VM + 512) {                 // ---- fin: raw y fp16 + partials
        int b2 = bid - NB_VM;
        int k = b2 >> 8, bx = b2 & 255;
        float* Wls = smem;                   // [32][68]
        float* s_  = smem + 2176;
        float* q_  = smem + 2432;
        for (int idx = t; idx < 2048; idx += 256)
            Wls[(idx >> 6) * 68 + (idx & 63)] = Win[k * 2048 + idx];
        __syncthreads();
        int c = t & 31, g = t >> 5;
        float w[64];
#pragma unroll
        for (int i4 = 0; i4 < 16; ++i4) {
            float4 wv = *(const float4*)&Wls[c * 68 + i4 * 4];
            w[i4 * 4] = wv.x; w[i4 * 4 + 1] = wv.y; w[i4 * 4 + 2] = wv.z; w[i4 * 4 + 3] = wv.w;
        }
        int base = bx * 64;
        float ssum = 0.f, ssq = 0.f;
        for (int it = 0; it < 8; ++it) {
            int pt = base + it * 8 + g;
            const float4* fr = (const float4*)(features + (size_t)pt * 64);
            float y = 0.f;
#pragma unroll
            for (int i4 = 0; i4 < 16; ++i4) {
                float4 v = fr[i4];
                y += v.x * w[i4 * 4] + v.y * w[i4 * 4 + 1] + v.z * w[i4 * 4 + 2] + v.w * w[i4 * 4 + 3];
            }
            fraw_h[((size_t)k * (NPTS + 1) + pt + 1) * 32 + c] = (_Float16)y;
            ssum += y; ssq += y * y;
        }
        s_[t] = ssum; q_[t] = ssq;
        __syncthreads();
        if (t < 32) {
            float fs = 0.f, fq = 0.f;
#pragma unroll
            for (int gg = 0; gg < 8; ++gg) { fs += s_[gg * 32 + t]; fq += q_[gg * 32 + t]; }
            float* pb = pIn + ((size_t)k * 256 + bx) * 64;
            pb[t] = fs; pb[32 + t] = fq;
        }
        return;
    }
    // ---- pf: BN over offsets of off_xyz @ W_pos^T (f32, 1 block)
    float* praw = smem;
    int pfoff = 0;
    for (int k = 0; k < 2; ++k) {
        int r = k + 1, s = 2 * r, noff = s * s * s;
        for (int idx = t; idx < noff * 32; idx += 256) {
            int j = idx >> 5, c = idx & 31;
            int xi = j % s, yi = (j / s) % s, zi = j / (s * s);
            const float* W = Wpos + (k * 32 + c) * 3;
            praw[idx] = (float)(xi - r) * W[0] + (float)(yi - r) * W[1] + (float)(zi - r) * W[2];
        }
        __syncthreads();
        if (t < 32) {
            float sum = 0.f, sq = 0.f;
            for (int j = 0; j < noff; ++j) { float v = praw[j * 32 + t]; sum += v; sq += v * v; }
            float mu  = sum / (float)noff;
            float var = fmaxf(sq / (float)noff - mu * mu, 0.f);
            float rs  = rsqrtf(var + EPSV);
            float g = g_pos[k * 32 + t], b = b_pos[k * 32 + t];
            for (int j = 0; j < noff; ++j)
                pf[pfoff + j * 32 + t] = (praw[j * 32 + t] - mu) * rs * g + b;
        }
        __syncthreads();
        pfoff += noff * 32;
    }
}

// L2: parallel reduce pIn -> scale/shift ; one block per (k, c)
__global__ __launch_bounds__(256) void k_reduce_in(
    const float* __restrict__ pIn, const float* __restrict__ g_in,
    const float* __restrict__ b_in, float* __restrict__ ss_in,
    _Float16* __restrict__ fraw_h)
{
    __shared__ float ss[256], qq[256];
    int b = blockIdx.x;          // 64 blocks: k = b>>5, c = b&31
    int k = b >> 5, c = b & 31;
    int t = threadIdx.x;
    ss[t] = pIn[((size_t)k * 256 + t) * 64 + c];
    qq[t] = pIn[((size_t)k * 256 + t) * 64 + 32 + c];
    __syncthreads();
    if (t < 128) { ss[t] += ss[t + 128]; qq[t] += qq[t + 128]; } __syncthreads();
    if (t < 64)  { ss[t] += ss[t + 64];  qq[t] += qq[t + 64];  } __syncthreads();
    if (t < 32)  { ss[t] += ss[t + 32];  qq[t] += qq[t + 32];  } __syncthreads();
    if (t == 0) {
        float sv = 0.f, sq = 0.f;
#pragma unroll
        for (int i = 0; i < 32; ++i) { sv += ss[i]; sq += qq[i]; }
        float mu  = sv / (float)NPTS;
        float var = fmaxf(sq / (float)NPTS - mu * mu, 0.f);
        float rs  = rsqrtf(var + EPSV);
        float scale = g_in[k * 32 + c] * rs;
        float shift = b_in[k * 32 + c] - mu * scale;
        ss_in[k * 64 + c]      = scale;
        ss_in[k * 64 + 32 + c] = shift;
        float pad = (scale != 0.f) ? (-shift / scale) : 0.f;
        pad = fminf(fmaxf(pad, -60000.f), 60000.f);
        fraw_h[(size_t)k * (NPTS + 1) * 32 + c] = (_Float16)pad;   // row 0
    }
}

// L3: fused gather (BOTH k) + relu-max + dot2 stats partials.
// 256 threads = 16 points x (4 jg x 4 chan-chunks).
// vm16 read as PACKED dwordx4 (8 shorts covering the 4 clamped x-positions):
// 5 vm transactions/lane instead of 18 -> attacks the TA-throughput bound.
__global__ __launch_bounds__(256, 3) void k_gather(
    const int* __restrict__ nc, const short* __restrict__ vm16,
    const _Float16* __restrict__ fraw_h, const float* __restrict__ pf,
    const float* __restrict__ ss_in, const float* __restrict__ Wout,
    _Float16* __restrict__ nf_h, float* __restrict__ pOut)
{
    __shared__ __align__(16) _Float16 psum1[64 * 40];   // stride 40: kills 4-way bank conflict
    __shared__ __align__(16) _Float16 psum0[8 * 40];
    __shared__ __align__(16) h2 Wh[2 * 64 * 17];        // fp16 W_out, pad 17
    __shared__ __align__(16) _Float16 nfl[2 * 16 * 32];
    __shared__ float s0_[256], q0_[256], s1_[256], q1_[256];
    int t = threadIdx.x, bx = blockIdx.x;
    int c4 = t & 3, jg = (t >> 2) & 3, lp = t >> 4;
    int pt = bx * 16 + lp;

    // ---- coords + packed vm addresses (consume cc BEFORE any asm load)
    int4 cc = ((const int4*)nc)[pt];
    int bb = cc.x, xc = cc.y, yc = cc.z, zc = cc.w;
    // reference quirk: fastest mesh idx -> z coord, slowest -> x coord
    int Zo[4];
#pragma unroll
    for (int u = 0; u < 4; ++u) {
        int zq = min(max(zc + u - 2, 0), ZD - 1);
        Zo[u] = (bb * ZD + zq) * (YD * XD);
    }
    int Yo1 = min(max(yc + jg - 2, 0), YD - 1) * XD;
    int ax1 = (min(max(xc - 2, 0), XD - 4)) & ~1;       // pack base (even)
    int Xoff[4];
#pragma unroll
    for (int a = 0; a < 4; ++a)
        Xoff[a] = min(max(xc - 2 + a, 0), XD - 1) - ax1;   // in [0,4] (proof in notes)
    int zq0 = min(max(zc + (jg & 1) - 1, 0), ZD - 1);
    int yo0 = min(max(yc + (jg >> 1) - 1, 0), YD - 1) * XD;
    int zo0 = (bb * ZD + zq0) * (YD * XD);
    int x0a = min(max(xc - 1, 0), XD - 1);
    int x0b = min(max(xc, 0), XD - 1);
    int ax0 = x0a & ~1;
    int X0a = x0a - ax0, X0b = x0b - ax0;               // in [0,2]
    __builtin_amdgcn_sched_barrier(0);

    // ---- phase A: 5 packed vm loads in flight (latency hides under staging)
    uint4 pk[4];
#pragma unroll
    for (int u = 0; u < 4; ++u)
        pk[u] = gload_u128(vm16 + Zo[u] + Yo1 + ax1);
    uint2 pk0 = gload_u64(vm16 + zo0 + yo0 + ax0);

    // ---- LDS staging (independent of phase A)
    for (int i = t; i < 2048; i += 256) {
        int o = i >> 5, ch = i & 31;
        psum1[o * 40 + ch] = (_Float16)(pf[256 + i] + ss_in[96 + ch]);
    }
    {
        int o = t >> 5, ch = t & 31;
        psum0[o * 40 + ch] = (_Float16)(pf[t] + ss_in[32 + ch]);
    }
    for (int i = t; i < 2048; i += 256) {
        int k = i >> 10, rem = i & 1023, c = rem >> 4, q = rem & 15;
        h2 v;
        v.x = (_Float16)Wout[k * 2048 + c * 32 + 2 * q];
        v.y = (_Float16)Wout[k * 2048 + c * 32 + 2 * q + 1];
        Wh[k * (64 * 17) + c * 17 + q] = v;
    }
    __syncthreads();
    vm_wait0();                          // packs ready

    // ---- phase B: extract pidx from packs, issue 18 row gathers
    const _Float16* fr1 = fraw_h + (size_t)(NPTS + 1) * 32;
    h8v g1[16], g0[2];
#pragma unroll
    for (int u = 0; u < 4; ++u) {
        unsigned long long lo = (unsigned long long)pk[u].x | ((unsigned long long)pk[u].y << 32);
        unsigned long long hi = (unsigned long long)pk[u].z | ((unsigned long long)pk[u].w << 32);
#pragma unroll
        for (int a = 0; a < 4; ++a) {
            int off = Xoff[a];
            unsigned long long sel = (off & 4) ? hi : lo;
            unsigned row = ((unsigned)(sel >> ((off & 3) * 16)) + 1) & 0xFFFFu;  // -1 -> pad row 0
            g1[u * 4 + a] = gload_h8(fr1 + (size_t)row * 32 + c4 * 8);
        }
    }
    {
        unsigned long long l0 = (unsigned long long)pk0.x | ((unsigned long long)pk0.y << 32);
        unsigned r0 = ((unsigned)(l0 >> (X0a * 16)) + 1) & 0xFFFFu;
        unsigned r1 = ((unsigned)(l0 >> (X0b * 16)) + 1) & 0xFFFFu;
        g0[0] = gload_h8(fraw_h + (size_t)r0 * 32 + c4 * 8);
        g0[1] = gload_h8(fraw_h + (size_t)r1 * 32 + c4 * 8);
    }
    vm_wait0();                          // rows ready

    // ---- phase C: scale + add(psum) + relu-max (relu folds into max)
    h8v sc1v, sc0v;
#pragma unroll
    for (int i = 0; i < 8; ++i) {
        sc1v[i] = (_Float16)ss_in[64 + c4 * 8 + i];
        sc0v[i] = (_Float16)ss_in[c4 * 8 + i];
    }
    h8v acc1 = zero8(), acc0 = zero8();
#pragma unroll
    for (int i = 0; i < 16; ++i) {
        int o = (i & 3) * 16 + jg * 4 + (i >> 2);
        h8v pv = *(const h8v*)(psum1 + o * 40 + c4 * 8);
        acc1 = __builtin_elementwise_max(acc1, g1[i] * sc1v + pv);
    }
    {
        h8v pv = *(const h8v*)(psum0 + jg * 40 + c4 * 8);
        acc0 = __builtin_elementwise_max(acc0, g0[0] * sc0v + pv);
        h8v pv2 = *(const h8v*)(psum0 + (4 + jg) * 40 + c4 * 8);
        acc0 = __builtin_elementwise_max(acc0, g0[1] * sc0v + pv2);
    }
    acc1 = __builtin_elementwise_max(acc1, shfl_xor_h8(acc1, 4));
    acc1 = __builtin_elementwise_max(acc1, shfl_xor_h8(acc1, 8));
    acc0 = __builtin_elementwise_max(acc0, shfl_xor_h8(acc0, 4));
    acc0 = __builtin_elementwise_max(acc0, shfl_xor_h8(acc0, 8));
    if (jg == 0) {
        *(h8v*)(nf_h + ((size_t)MGRID + pt) * 32 + c4 * 8) = acc1;   // k=1
        *(h8v*)(nf_h + (size_t)pt * 32 + c4 * 8) = acc0;             // k=0
        *(h8v*)(nfl + (16 + lp) * 32 + c4 * 8) = acc1;
        *(h8v*)(nfl + lp * 32 + c4 * 8) = acc0;
    }
    __syncthreads();

    // ---- stats: y_k = nf_k . W_k[c] via v_dot2_f32_f16, per-block sum/sumsq
    int c = t & 63, pg = t >> 6;
    float s0 = 0.f, q0 = 0.f, s1 = 0.f, q1 = 0.f;
    const h2* w0 = &Wh[c * 17];
    const h2* w1 = &Wh[64 * 17 + c * 17];
#pragma unroll
    for (int i = 0; i < 4; ++i) {
        int p = pg * 4 + i;
        const H8* r0p = (const H8*)(nfl + p * 32);
        const H8* r1p = (const H8*)(nfl + (16 + p) * 32);
        H8 ra = r0p[0], rb = r0p[1], rc = r0p[2], rd = r0p[3];
        H8 sa = r1p[0], sb = r1p[1], sc_ = r1p[2], sd = r1p[3];
        h2 u0v[16] = {ra.a, ra.b, ra.c, ra.d, rb.a, rb.b, rb.c, rb.d,
                      rc.a, rc.b, rc.c, rc.d, rd.a, rd.b, rd.c, rd.d};
        h2 u1v[16] = {sa.a, sa.b, sa.c, sa.d, sb.a, sb.b, sb.c, sb.d,
                      sc_.a, sc_.b, sc_.c, sc_.d, sd.a, sd.b, sd.c, sd.d};
        float y0 = 0.f, y1 = 0.f;
#pragma unroll
        for (int iq = 0; iq < 16; ++iq) {
            y0 = FDOT2(u0v[iq], w0[iq], y0);
            y1 = FDOT2(u1v[iq], w1[iq], y1);
        }
        s0 += y0; q0 += y0 * y0; s1 += y1; q1 += y1 * y1;
    }
    s0_[t] = s0; q0_[t] = q0; s1_[t] = s1; q1_[t] = q1;
    __syncthreads();
    if (t < 128) {
        s0_[t] += s0_[t + 128]; q0_[t] += q0_[t + 128];
        s1_[t] += s1_[t + 128]; q1_[t] += q1_[t + 128];
    }
    __syncthreads();
    if (t < 64) {
        pOut[(size_t)bx * 128 + t]               = s0_[t] + s0_[t + 64];
        pOut[(size_t)bx * 128 + 64 + t]          = q0_[t] + q0_[t + 64];
        pOut[((size_t)4096 + bx) * 128 + t]      = s1_[t] + s1_[t + 64];
        pOut[((size_t)4096 + bx) * 128 + 64 + t] = q1_[t] + q1_[t + 64];
    }
}

// L4: parallel reduce pOut -> scale/shift ; one block per (k, c)
__global__ __launch_bounds__(256) void k_out_reduce(
    const float* __restrict__ pOut, const float* __restrict__ g_out,
    const float* __restrict__ b_out, float* __restrict__ ss_out)
{
    __shared__ float ss[256], qq[256];
    int b = blockIdx.x;          // 128 blocks: k = b>>6, c = b&63
    int k = b >> 6, c = b & 63;
    int t = threadIdx.x;
    float sv = 0.f, sq = 0.f;
#pragma unroll
    for (int i = 0; i < 16; ++i) {
        size_t row = (size_t)k * 4096 + t + i * 256;
        sv += pOut[row * 128 + c];
        sq += pOut[row * 128 + 64 + c];
    }
    ss[t] = sv; qq[t] = sq;
    __syncthreads();
    if (t < 128) { ss[t] += ss[t + 128]; qq[t] += qq[t + 128]; } __syncthreads();
    if (t < 64)  { ss[t] += ss[t + 64];  qq[t] += qq[t + 64];  } __syncthreads();
    if (t < 32)  { ss[t] += ss[t + 32];  qq[t] += qq[t + 32];  } __syncthreads();
    if (t == 0) {
        float fs = 0.f, fq = 0.f;
#pragma unroll
        for (int i = 0; i < 32; ++i) { fs += ss[i]; fq += qq[i]; }
        float mu  = fs / (float)MGRID;
        float var = fmaxf(fq / (float)MGRID - mu * mu, 0.f);
        float rs  = rsqrtf(var + EPSV);
        float scale = g_out[k * 64 + c] * rs;
        float shift = b_out[k * 64 + c] - mu * scale;
        ss_out[k * 128 + c]      = scale;
        ss_out[k * 128 + 64 + c] = shift;
    }
}

// L5: out[:, k*64+c] = relu(y*scale + shift), dot2 matmul
__global__ __launch_bounds__(256) void k_out_write(
    const _Float16* __restrict__ nf_h, const float* __restrict__ Wout,
    const float* __restrict__ ss_out, float* __restrict__ out)
{
    __shared__ h2 Wh[64 * 17];
    int k = blockIdx.y, t = threadIdx.x;
    for (int i = t; i < 1024; i += 256) {
        int c = i >> 4, q = i & 15;
        h2 v;
        v.x = (_Float16)Wout[k * 2048 + c * 32 + 2 * q];
        v.y = (_Float16)Wout[k * 2048 + c * 32 + 2 * q + 1];
        Wh[c * 17 + q] = v;
    }
    __syncthreads();
    int c = t & 63, pl = t >> 6;
    float scale = ss_out[k * 128 + c], shift = ss_out[k * 128 + 64 + c];
    const h2* w = &Wh[c * 17];
    int base = blockIdx.x * 64;
    for (int it = 0; it < 16; ++it) {
        int pt = base + it * 4 + pl;
        const H8* row = (const H8*)(nf_h + ((size_t)k * MGRID + pt) * 32);
        H8 r0 = row[0], r1 = row[1], r2 = row[2], r3 = row[3];
        h2 hh[16] = {r0.a, r0.b, r0.c, r0.d, r1.a, r1.b, r1.c, r1.d,
                     r2.a, r2.b, r2.c, r2.d, r3.a, r3.b, r3.c, r3.d};
        float y = 0.f;
#pragma unroll
        for (int iq = 0; iq < 16; ++iq) y = FDOT2(hh[iq], w[iq], y);
        float o = y * scale + shift;
        out[(size_t)pt * 128 + k * 64 + c] = o > 0.f ? o : 0.f;
    }
}

extern "C" void kernel_launch(void* const* d_in, const int* in_sizes, int n_in,
                              void* d_out, int out_size, void* d_ws, size_t ws_size,
                              hipStream_t stream) {
    const int*   new_coords = (const int*)d_in[4];
    const float* features   = (const float*)d_in[5];
    const int*   vm         = (const int*)d_in[6];
    const float* W_in  = (const float*)d_in[7];
    const float* g_in  = (const float*)d_in[8];
    const float* b_in  = (const float*)d_in[9];
    const float* W_pos = (const float*)d_in[10];
    const float* g_pos = (const float*)d_in[11];
    const float* b_pos = (const float*)d_in[12];
    const float* W_out = (const float*)d_in[13];
    const float* g_out = (const float*)d_in[14];
    const float* b_out = (const float*)d_in[15];
    float* out = (float*)d_out;

    char* ws = (char*)d_ws;
    float*     ss_in  = (float*)(ws);
    float*     ss_out = (float*)(ws + 4096);
    float*     pIn    = (float*)(ws + 8192);
    _Float16*  fraw_h = (_Float16*)(ws + 139264);
    float*     pf     = (float*)(ws + 2236544);
    short*     vm16   = (short*)(ws + 2245760);
    _Float16*  nf_h   = (_Float16*)(ws + 3794560);
    float*     pOut   = (float*)(ws + 12183168);

    k_pre<<<NB_VM + 512 + 1, 256, 0, stream>>>(vm, features, W_in, W_pos, g_pos, b_pos,
                                               vm16, fraw_h, pIn, pf);
    k_reduce_in<<<64, 256, 0, stream>>>(pIn, g_in, b_in, ss_in, fraw_h);

    k_gather<<<MGRID / 16, 256, 0, stream>>>(new_coords, vm16, fraw_h, pf, ss_in,
                                             W_out, nf_h, pOut);

    k_out_reduce<<<128, 256, 0, stream>>>(pOut, g_out, b_out, ss_out);

    dim3 gW(MGRID / 64, 2);
    k_out_write<<<gW, 256, 0, stream>>>(nf_h, W_out, ss_out, out);
}

// Round 9
// 96.441 us; speedup vs baseline: 3.6081x; 1.0045x over previous
//
#include <hip/hip_runtime.h>

#define EPSV 1e-5f
constexpr int NPTS  = 16384;
constexpr int MGRID = 65536;
constexpr int ZD = 11, YD = 200, XD = 176;
constexpr int NVOX = 2 * ZD * YD * XD;          // 774400
constexpr int NB_VM = (NVOX / 8 + 255) / 256;   // 379 blocks for vm16 compress

typedef _Float16 h2  __attribute__((ext_vector_type(2)));
typedef _Float16 h8v __attribute__((ext_vector_type(8)));
struct alignas(16) H8 { h2 a, b, c, d; };       // 8 fp16 channels (LDS view)

#if __has_builtin(__builtin_amdgcn_fdot2)
#define FDOT2(a, b, c) __builtin_amdgcn_fdot2((a), (b), (c), false)
#else
#define FDOT2(a, b, c) ((c) + (float)(a).x * (float)(b).x + (float)(a).y * (float)(b).y)
#endif

// ---------------------------------------------------------------------------
// ws layout (bytes):
//   0          ss_in  : float[2][{scale,shift}][32]        (512 B)
//   4096       ss_out : float[2][{scale,shift}][64]        (1 KB)
//   8192       pIn    : float[2][256][64]                  (128 KB)
//   139264     fraw_h : _Float16[2][16385][32] raw, row0=pad (2 MB)
//   2236544    pf     : float[8+64][32]                    (9216 B)
//   2245760    vm16   : short[774400]                      (1.5 MB)
//   3794560    nf_h   : _Float16[2][65536][32]             (8.4 MB)
//   12183168   pOut   : float[2][4096][128]                (4 MB)
// ---------------------------------------------------------------------------

__device__ __forceinline__ h8v gload_h8(const _Float16* p) {
    h8v r;
    asm volatile("global_load_dwordx4 %0, %1, off" : "=v"(r) : "v"(p));
    return r;
}
__device__ __forceinline__ uint4 gload_u128(const void* p) {
    uint4 r;
    asm volatile("global_load_dwordx4 %0, %1, off" : "=v"(r) : "v"(p));
    return r;
}
__device__ __forceinline__ uint2 gload_u64(const void* p) {
    uint2 r;
    asm volatile("global_load_dwordx2 %0, %1, off" : "=v"(r) : "v"(p));
    return r;
}
__device__ __forceinline__ void vm_wait0() {
    asm volatile("s_waitcnt vmcnt(0)" ::: "memory");
    __builtin_amdgcn_sched_barrier(0);   // rule #18: keep reg-only ops below
}
__device__ __forceinline__ h8v zero8() {
    h8v z;
#pragma unroll
    for (int i = 0; i < 8; ++i) z[i] = (_Float16)0.f;
    return z;
}
__device__ __forceinline__ h8v shfl_xor_h8(h8v v, int m) {
    union { h8v h; int4 i; } u; u.h = v;
    u.i.x = __shfl_xor(u.i.x, m, 64);
    u.i.y = __shfl_xor(u.i.y, m, 64);
    u.i.z = __shfl_xor(u.i.z, m, 64);
    u.i.w = __shfl_xor(u.i.w, m, 64);
    return u.h;
}

// L1: fused prelude — vm16 compress | fin matmul (raw fp16 + stats partials) | pf
__global__ __launch_bounds__(256) void k_pre(
    const int* __restrict__ vm, const float* __restrict__ features,
    const float* __restrict__ Win, const float* __restrict__ Wpos,
    const float* __restrict__ g_pos, const float* __restrict__ b_pos,
    short* __restrict__ vm16, _Float16* __restrict__ fraw_h,
    float* __restrict__ pIn, float* __restrict__ pf)
{
    __shared__ float smem[2688];
    int bid = blockIdx.x, t = threadIdx.x;

    if (bid < NB_VM) {                       // ---- vm -> int16 (8 ints/thread)
        int i = bid * 256 + t;
        if (i < NVOX / 8) {
            int4 v0 = ((const int4*)vm)[i * 2];
            int4 v1 = ((const int4*)vm)[i * 2 + 1];
            uint4 o;
            o.x = (v0.x & 0xffff) | (v0.y << 16);
            o.y = (v0.z & 0xffff) | (v0.w << 16);
            o.z = (v1.x & 0xffff) | (v1.y << 16);
            o.w = (v1.z & 0xffff) | (v1.w << 16);
            ((uint4*)vm16)[i] = o;
        }
        return;
    }
    if (bid < NB_VM + 512) {                 // ---- fin: raw y fp16 + partials
        int b2 = bid - NB_VM;
        int k = b2 >> 8, bx = b2 & 255;
        float* Wls = smem;                   // [32][68]
        float* s_  = smem + 2176;
        float* q_  = smem + 2432;
        for (int idx = t; idx < 2048; idx += 256)
            Wls[(idx >> 6) * 68 + (idx & 63)] = Win[k * 2048 + idx];
        __syncthreads();
        int c = t & 31, g = t >> 5;
        float w[64];
#pragma unroll
        for (int i4 = 0; i4 < 16; ++i4) {
            float4 wv = *(const float4*)&Wls[c * 68 + i4 * 4];
            w[i4 * 4] = wv.x; w[i4 * 4 + 1] = wv.y; w[i4 * 4 + 2] = wv.z; w[i4 * 4 + 3] = wv.w;
        }
        int base = bx * 64;
        float ssum = 0.f, ssq = 0.f;
        for (int it = 0; it < 8; ++it) {
            int pt = base + it * 8 + g;
            const float4* fr = (const float4*)(features + (size_t)pt * 64);
            float y = 0.f;
#pragma unroll
            for (int i4 = 0; i4 < 16; ++i4) {
                float4 v = fr[i4];
                y += v.x * w[i4 * 4] + v.y * w[i4 * 4 + 1] + v.z * w[i4 * 4 + 2] + v.w * w[i4 * 4 + 3];
            }
            fraw_h[((size_t)k * (NPTS + 1) + pt + 1) * 32 + c] = (_Float16)y;
            ssum += y; ssq += y * y;
        }
        s_[t] = ssum; q_[t] = ssq;
        __syncthreads();
        if (t < 32) {
            float fs = 0.f, fq = 0.f;
#pragma unroll
            for (int gg = 0; gg < 8; ++gg) { fs += s_[gg * 32 + t]; fq += q_[gg * 32 + t]; }
            float* pb = pIn + ((size_t)k * 256 + bx) * 64;
            pb[t] = fs; pb[32 + t] = fq;
        }
        return;
    }
    // ---- pf: BN over offsets of off_xyz @ W_pos^T (f32, 1 block)
    float* praw = smem;
    int pfoff = 0;
    for (int k = 0; k < 2; ++k) {
        int r = k + 1, s = 2 * r, noff = s * s * s;
        for (int idx = t; idx < noff * 32; idx += 256) {
            int j = idx >> 5, c = idx & 31;
            int xi = j % s, yi = (j / s) % s, zi = j / (s * s);
            const float* W = Wpos + (k * 32 + c) * 3;
            praw[idx] = (float)(xi - r) * W[0] + (float)(yi - r) * W[1] + (float)(zi - r) * W[2];
        }
        __syncthreads();
        if (t < 32) {
            float sum = 0.f, sq = 0.f;
            for (int j = 0; j < noff; ++j) { float v = praw[j * 32 + t]; sum += v; sq += v * v; }
            float mu  = sum / (float)noff;
            float var = fmaxf(sq / (float)noff - mu * mu, 0.f);
            float rs  = rsqrtf(var + EPSV);
            float g = g_pos[k * 32 + t], b = b_pos[k * 32 + t];
            for (int j = 0; j < noff; ++j)
                pf[pfoff + j * 32 + t] = (praw[j * 32 + t] - mu) * rs * g + b;
        }
        __syncthreads();
        pfoff += noff * 32;
    }
}

// L2: parallel reduce pIn -> scale/shift ; one block per (k, c)
__global__ __launch_bounds__(256) void k_reduce_in(
    const float* __restrict__ pIn, const float* __restrict__ g_in,
    const float* __restrict__ b_in, float* __restrict__ ss_in,
    _Float16* __restrict__ fraw_h)
{
    __shared__ float ss[256], qq[256];
    int b = blockIdx.x;          // 64 blocks: k = b>>5, c = b&31
    int k = b >> 5, c = b & 31;
    int t = threadIdx.x;
    ss[t] = pIn[((size_t)k * 256 + t) * 64 + c];
    qq[t] = pIn[((size_t)k * 256 + t) * 64 + 32 + c];
    __syncthreads();
    if (t < 128) { ss[t] += ss[t + 128]; qq[t] += qq[t + 128]; } __syncthreads();
    if (t < 64)  { ss[t] += ss[t + 64];  qq[t] += qq[t + 64];  } __syncthreads();
    if (t < 32)  { ss[t] += ss[t + 32];  qq[t] += qq[t + 32];  } __syncthreads();
    if (t == 0) {
        float sv = 0.f, sq = 0.f;
#pragma unroll
        for (int i = 0; i < 32; ++i) { sv += ss[i]; sq += qq[i]; }
        float mu  = sv / (float)NPTS;
        float var = fmaxf(sq / (float)NPTS - mu * mu, 0.f);
        float rs  = rsqrtf(var + EPSV);
        float scale = g_in[k * 32 + c] * rs;
        float shift = b_in[k * 32 + c] - mu * scale;
        ss_in[k * 64 + c]      = scale;
        ss_in[k * 64 + 32 + c] = shift;
        float pad = (scale != 0.f) ? (-shift / scale) : 0.f;
        pad = fminf(fmaxf(pad, -60000.f), 60000.f);
        fraw_h[(size_t)k * (NPTS + 1) * 32 + c] = (_Float16)pad;   // row 0
    }
}

// L3: fused gather (BOTH k) + relu-max + dot2 stats partials.
// 256 threads = 16 points x (4 jg x 4 chan-chunks). Packed vm loads (5/lane).
// LDS trimmed to 16.5KB (stats arrays overlay psum) + no launch_bounds cap
// -> 6-8 blocks/CU instead of 3: covers the two vmcnt(0) drain phases.
__global__ __launch_bounds__(256) void k_gather(
    const int* __restrict__ nc, const short* __restrict__ vm16,
    const _Float16* __restrict__ fraw_h, const float* __restrict__ pf,
    const float* __restrict__ ss_in, const float* __restrict__ Wout,
    _Float16* __restrict__ nf_h, float* __restrict__ pOut)
{
    // LDS plan (16512 B):
    //   [0,     5760)  psum1[64*40] fp16 ++ psum0[8*40] fp16   (phase C only)
    //   [0,     4096)  s0_/q0_/s1_/q1_ [256] f32 each          (stats, overlay)
    //   [5760, 14464)  Wh: h2[2*64*17]
    //   [14464,16512)  nfl: fp16[2*16*32]
    __shared__ __align__(16) char smem[16512];
    _Float16* psum1 = (_Float16*)smem;                  // stride 40 halves
    _Float16* psum0 = (_Float16*)(smem + 5120);
    float* s0_ = (float*)smem;
    float* q0_ = (float*)(smem + 1024);
    float* s1_ = (float*)(smem + 2048);
    float* q1_ = (float*)(smem + 3072);
    h2*      Wh  = (h2*)(smem + 5760);
    _Float16* nfl = (_Float16*)(smem + 14464);

    int t = threadIdx.x, bx = blockIdx.x;
    int c4 = t & 3, jg = (t >> 2) & 3, lp = t >> 4;
    int pt = bx * 16 + lp;

    // ---- coords + packed vm addresses (consume cc BEFORE any asm load)
    int4 cc = ((const int4*)nc)[pt];
    int bb = cc.x, xc = cc.y, yc = cc.z, zc = cc.w;
    // reference quirk: fastest mesh idx -> z coord, slowest -> x coord
    int Zo[4];
#pragma unroll
    for (int u = 0; u < 4; ++u) {
        int zq = min(max(zc + u - 2, 0), ZD - 1);
        Zo[u] = (bb * ZD + zq) * (YD * XD);
    }
    int Yo1 = min(max(yc + jg - 2, 0), YD - 1) * XD;
    int ax1 = (min(max(xc - 2, 0), XD - 4)) & ~1;       // pack base (even)
    int Xoff[4];
#pragma unroll
    for (int a = 0; a < 4; ++a)
        Xoff[a] = min(max(xc - 2 + a, 0), XD - 1) - ax1;   // in [0,4]
    int zq0 = min(max(zc + (jg & 1) - 1, 0), ZD - 1);
    int yo0 = min(max(yc + (jg >> 1) - 1, 0), YD - 1) * XD;
    int zo0 = (bb * ZD + zq0) * (YD * XD);
    int x0a = min(max(xc - 1, 0), XD - 1);
    int x0b = min(max(xc, 0), XD - 1);
    int ax0 = x0a & ~1;
    int X0a = x0a - ax0, X0b = x0b - ax0;               // in [0,2]
    __builtin_amdgcn_sched_barrier(0);

    // ---- phase A: 5 packed vm loads in flight (latency hides under staging)
    uint4 pk[4];
#pragma unroll
    for (int u = 0; u < 4; ++u)
        pk[u] = gload_u128(vm16 + Zo[u] + Yo1 + ax1);
    uint2 pk0 = gload_u64(vm16 + zo0 + yo0 + ax0);

    // ---- LDS staging (independent of phase A)
    for (int i = t; i < 2048; i += 256) {
        int o = i >> 5, ch = i & 31;
        psum1[o * 40 + ch] = (_Float16)(pf[256 + i] + ss_in[96 + ch]);
    }
    {
        int o = t >> 5, ch = t & 31;
        psum0[o * 40 + ch] = (_Float16)(pf[t] + ss_in[32 + ch]);
    }
    for (int i = t; i < 2048; i += 256) {
        int k = i >> 10, rem = i & 1023, c = rem >> 4, q = rem & 15;
        h2 v;
        v.x = (_Float16)Wout[k * 2048 + c * 32 + 2 * q];
        v.y = (_Float16)Wout[k * 2048 + c * 32 + 2 * q + 1];
        Wh[k * (64 * 17) + c * 17 + q] = v;
    }
    __syncthreads();
    vm_wait0();                          // packs ready

    // ---- phase B: extract pidx from packs, issue 18 row gathers
    const _Float16* fr1 = fraw_h + (size_t)(NPTS + 1) * 32;
    h8v g1[16], g0[2];
#pragma unroll
    for (int u = 0; u < 4; ++u) {
        unsigned long long lo = (unsigned long long)pk[u].x | ((unsigned long long)pk[u].y << 32);
        unsigned long long hi = (unsigned long long)pk[u].z | ((unsigned long long)pk[u].w << 32);
#pragma unroll
        for (int a = 0; a < 4; ++a) {
            int off = Xoff[a];
            unsigned long long sel = (off & 4) ? hi : lo;
            unsigned row = ((unsigned)(sel >> ((off & 3) * 16)) + 1) & 0xFFFFu;  // -1 -> pad row 0
            g1[u * 4 + a] = gload_h8(fr1 + (size_t)row * 32 + c4 * 8);
        }
    }
    {
        unsigned long long l0 = (unsigned long long)pk0.x | ((unsigned long long)pk0.y << 32);
        unsigned r0 = ((unsigned)(l0 >> (X0a * 16)) + 1) & 0xFFFFu;
        unsigned r1 = ((unsigned)(l0 >> (X0b * 16)) + 1) & 0xFFFFu;
        g0[0] = gload_h8(fraw_h + (size_t)r0 * 32 + c4 * 8);
        g0[1] = gload_h8(fraw_h + (size_t)r1 * 32 + c4 * 8);
    }
    vm_wait0();                          // rows ready

    // ---- phase C: scale + add(psum) + relu-max (relu folds into max)
    h8v sc1v, sc0v;
#pragma unroll
    for (int i = 0; i < 8; ++i) {
        sc1v[i] = (_Float16)ss_in[64 + c4 * 8 + i];
        sc0v[i] = (_Float16)ss_in[c4 * 8 + i];
    }
    h8v acc1 = zero8(), acc0 = zero8();
#pragma unroll
    for (int i = 0; i < 16; ++i) {
        int o = (i & 3) * 16 + jg * 4 + (i >> 2);
        h8v pv = *(const h8v*)(psum1 + o * 40 + c4 * 8);
        acc1 = __builtin_elementwise_max(acc1, g1[i] * sc1v + pv);
    }
    {
        h8v pv = *(const h8v*)(psum0 + jg * 40 + c4 * 8);
        acc0 = __builtin_elementwise_max(acc0, g0[0] * sc0v + pv);
        h8v pv2 = *(const h8v*)(psum0 + (4 + jg) * 40 + c4 * 8);
        acc0 = __builtin_elementwise_max(acc0, g0[1] * sc0v + pv2);
    }
    acc1 = __builtin_elementwise_max(acc1, shfl_xor_h8(acc1, 4));
    acc1 = __builtin_elementwise_max(acc1, shfl_xor_h8(acc1, 8));
    acc0 = __builtin_elementwise_max(acc0, shfl_xor_h8(acc0, 4));
    acc0 = __builtin_elementwise_max(acc0, shfl_xor_h8(acc0, 8));
    if (jg == 0) {
        *(h8v*)(nf_h + ((size_t)MGRID + pt) * 32 + c4 * 8) = acc1;   // k=1
        *(h8v*)(nf_h + (size_t)pt * 32 + c4 * 8) = acc0;             // k=0
        *(h8v*)(nfl + (16 + lp) * 32 + c4 * 8) = acc1;
        *(h8v*)(nfl + lp * 32 + c4 * 8) = acc0;
    }
    __syncthreads();     // psum dead from here; s_/q_ overlay becomes live

    // ---- stats: y_k = nf_k . W_k[c] via v_dot2_f32_f16, per-block sum/sumsq
    int c = t & 63, pg = t >> 6;
    float s0 = 0.f, q0 = 0.f, s1 = 0.f, q1 = 0.f;
    const h2* w0 = &Wh[c * 17];
    const h2* w1 = &Wh[64 * 17 + c * 17];
#pragma unroll
    for (int i = 0; i < 4; ++i) {
        int p = pg * 4 + i;
        const H8* r0p = (const H8*)(nfl + p * 32);
        const H8* r1p = (const H8*)(nfl + (16 + p) * 32);
        H8 ra = r0p[0], rb = r0p[1], rc = r0p[2], rd = r0p[3];
        H8 sa = r1p[0], sb = r1p[1], sc_ = r1p[2], sd = r1p[3];
        h2 u0v[16] = {ra.a, ra.b, ra.c, ra.d, rb.a, rb.b, rb.c, rb.d,
                      rc.a, rc.b, rc.c, rc.d, rd.a, rd.b, rd.c, rd.d};
        h2 u1v[16] = {sa.a, sa.b, sa.c, sa.d, sb.a, sb.b, sb.c, sb.d,
                      sc_.a, sc_.b, sc_.c, sc_.d, sd.a, sd.b, sd.c, sd.d};
        float y0 = 0.f, y1 = 0.f;
#pragma unroll
        for (int iq = 0; iq < 16; ++iq) {
            y0 = FDOT2(u0v[iq], w0[iq], y0);
            y1 = FDOT2(u1v[iq], w1[iq], y1);
        }
        s0 += y0; q0 += y0 * y0; s1 += y1; q1 += y1 * y1;
    }
    s0_[t] = s0; q0_[t] = q0; s1_[t] = s1; q1_[t] = q1;
    __syncthreads();
    if (t < 128) {
        s0_[t] += s0_[t + 128]; q0_[t] += q0_[t + 128];
        s1_[t] += s1_[t + 128]; q1_[t] += q1_[t + 128];
    }
    __syncthreads();
    if (t < 64) {
        pOut[(size_t)bx * 128 + t]               = s0_[t] + s0_[t + 64];
        pOut[(size_t)bx * 128 + 64 + t]          = q0_[t] + q0_[t + 64];
        pOut[((size_t)4096 + bx) * 128 + t]      = s1_[t] + s1_[t + 64];
        pOut[((size_t)4096 + bx) * 128 + 64 + t] = q1_[t] + q1_[t + 64];
    }
}

// L4: parallel reduce pOut -> scale/shift ; one block per (k, c)
__global__ __launch_bounds__(256) void k_out_reduce(
    const float* __restrict__ pOut, const float* __restrict__ g_out,
    const float* __restrict__ b_out, float* __restrict__ ss_out)
{
    __shared__ float ss[256], qq[256];
    int b = blockIdx.x;          // 128 blocks: k = b>>6, c = b&63
    int k = b >> 6, c = b & 63;
    int t = threadIdx.x;
    float sv = 0.f, sq = 0.f;
#pragma unroll
    for (int i = 0; i < 16; ++i) {
        size_t row = (size_t)k * 4096 + t + i * 256;
        sv += pOut[row * 128 + c];
        sq += pOut[row * 128 + 64 + c];
    }
    ss[t] = sv; qq[t] = sq;
    __syncthreads();
    if (t < 128) { ss[t] += ss[t + 128]; qq[t] += qq[t + 128]; } __syncthreads();
    if (t < 64)  { ss[t] += ss[t + 64];  qq[t] += qq[t + 64];  } __syncthreads();
    if (t < 32)  { ss[t] += ss[t + 32];  qq[t] += qq[t + 32];  } __syncthreads();
    if (t == 0) {
        float fs = 0.f, fq = 0.f;
#pragma unroll
        for (int i = 0; i < 32; ++i) { fs += ss[i]; fq += qq[i]; }
        float mu  = fs / (float)MGRID;
        float var = fmaxf(fq / (float)MGRID - mu * mu, 0.f);
        float rs  = rsqrtf(var + EPSV);
        float scale = g_out[k * 64 + c] * rs;
        float shift = b_out[k * 64 + c] - mu * scale;
        ss_out[k * 128 + c]      = scale;
        ss_out[k * 128 + 64 + c] = shift;
    }
}

// L5: out[:, k*64+c] = relu(y*scale + shift), dot2 matmul
__global__ __launch_bounds__(256) void k_out_write(
    const _Float16* __restrict__ nf_h, const float* __restrict__ Wout,
    const float* __restrict__ ss_out, float* __restrict__ out)
{
    __shared__ h2 Wh[64 * 17];
    int k = blockIdx.y, t = threadIdx.x;
    for (int i = t; i < 1024; i += 256) {
        int c = i >> 4, q = i & 15;
        h2 v;
        v.x = (_Float16)Wout[k * 2048 + c * 32 + 2 * q];
        v.y = (_Float16)Wout[k * 2048 + c * 32 + 2 * q + 1];
        Wh[c * 17 + q] = v;
    }
    __syncthreads();
    int c = t & 63, pl = t >> 6;
    float scale = ss_out[k * 128 + c], shift = ss_out[k * 128 + 64 + c];
    const h2* w = &Wh[c * 17];
    int base = blockIdx.x * 64;
    for (int it = 0; it < 16; ++it) {
        int pt = base + it * 4 + pl;
        const H8* row = (const H8*)(nf_h + ((size_t)k * MGRID + pt) * 32);
        H8 r0 = row[0], r1 = row[1], r2 = row[2], r3 = row[3];
        h2 hh[16] = {r0.a, r0.b, r0.c, r0.d, r1.a, r1.b, r1.c, r1.d,
                     r2.a, r2.b, r2.c, r2.d, r3.a, r3.b, r3.c, r3.d};
        float y = 0.f;
#pragma unroll
        for (int iq = 0; iq < 16; ++iq) y = FDOT2(hh[iq], w[iq], y);
        float o = y * scale + shift;
        out[(size_t)pt * 128 + k * 64 + c] = o > 0.f ? o : 0.f;
    }
}

extern "C" void kernel_launch(void* const* d_in, const int* in_sizes, int n_in,
                              void* d_out, int out_size, void* d_ws, size_t ws_size,
                              hipStream_t stream) {
    const int*   new_coords = (const int*)d_in[4];
    const float* features   = (const float*)d_in[5];
    const int*   vm         = (const int*)d_in[6];
    const float* W_in  = (const float*)d_in[7];
    const float* g_in  = (const float*)d_in[8];
    const float* b_in  = (const float*)d_in[9];
    const float* W_pos = (const float*)d_in[10];
    const float* g_pos = (const float*)d_in[11];
    const float* b_pos = (const float*)d_in[12];
    const float* W_out = (const float*)d_in[13];
    const float* g_out = (const float*)d_in[14];
    const float* b_out = (const float*)d_in[15];
    float* out = (float*)d_out;

    char* ws = (char*)d_ws;
    float*     ss_in  = (float*)(ws);
    float*     ss_out = (float*)(ws + 4096);
    float*     pIn    = (float*)(ws + 8192);
    _Float16*  fraw_h = (_Float16*)(ws + 139264);
    float*     pf     = (float*)(ws + 2236544);
    short*     vm16   = (short*)(ws + 2245760);
    _Float16*  nf_h   = (_Float16*)(ws + 3794560);
    float*     pOut   = (float*)(ws + 12183168);

    k_pre<<<NB_VM + 512 + 1, 256, 0, stream>>>(vm, features, W_in, W_pos, g_pos, b_pos,
                                               vm16, fraw_h, pIn, pf);
    k_reduce_in<<<64, 256, 0, stream>>>(pIn, g_in, b_in, ss_in, fraw_h);

    k_gather<<<MGRID / 16, 256, 0, stream>>>(new_coords, vm16, fraw_h, pf, ss_in,
                                             W_out, nf_h, pOut);

    k_out_reduce<<<128, 256, 0, stream>>>(pOut, g_out, b_out, ss_out);

    dim3 gW(MGRID / 64, 2);
    k_out_write<<<gW, 256, 0, stream>>>(nf_h, W_out, ss_out, out);
}

// Round 10
// 89.829 us; speedup vs baseline: 3.8736x; 1.0736x over previous
//
#include <hip/hip_runtime.h>

#define EPSV 1e-5f
constexpr int NPTS  = 16384;
constexpr int MGRID = 65536;
constexpr int ZD = 11, YD = 200, XD = 176;
constexpr int NVOX = 2 * ZD * YD * XD;          // 774400
constexpr int NB_VM = (NVOX / 8 + 255) / 256;   // 379 blocks for vm16 compress

typedef _Float16 h2  __attribute__((ext_vector_type(2)));
typedef _Float16 h8v __attribute__((ext_vector_type(8)));
struct alignas(16) H8 { h2 a, b, c, d; };       // 8 fp16 channels (LDS view)

#if __has_builtin(__builtin_amdgcn_fdot2)
#define FDOT2(a, b, c) __builtin_amdgcn_fdot2((a), (b), (c), false)
#else
#define FDOT2(a, b, c) ((c) + (float)(a).x * (float)(b).x + (float)(a).y * (float)(b).y)
#endif

// ---------------------------------------------------------------------------
// ws layout (bytes):
//   0          ss_in  : float[2][{scale,shift}][32]        (512 B)
//   4096       ss_out : float[2][{scale,shift}][64]        (1 KB)
//   8192       pIn    : float[2][256][64]                  (128 KB)
//   139264     fraw_h : _Float16[2][16385][32] raw, row0=pad (2 MB)
//   2236544    pf     : float[8+64][32]                    (9216 B)
//   2245760    vm16   : short[774400]                      (1.5 MB)
//   3794560    nf_h   : _Float16[2][65536][32]             (8.4 MB)
//   12183168   pOut   : float[2][512][128]                 (512 KB)
// ---------------------------------------------------------------------------

__device__ __forceinline__ h8v gload_h8(const _Float16* p) {
    h8v r;
    asm volatile("global_load_dwordx4 %0, %1, off" : "=v"(r) : "v"(p));
    return r;
}
__device__ __forceinline__ uint4 gload_u128(const void* p) {
    uint4 r;
    asm volatile("global_load_dwordx4 %0, %1, off" : "=v"(r) : "v"(p));
    return r;
}
__device__ __forceinline__ uint2 gload_u64(const void* p) {
    uint2 r;
    asm volatile("global_load_dwordx2 %0, %1, off" : "=v"(r) : "v"(p));
    return r;
}
__device__ __forceinline__ void vm_wait0() {
    asm volatile("s_waitcnt vmcnt(0)" ::: "memory");
    __builtin_amdgcn_sched_barrier(0);   // rule #18: keep reg-only ops below
}
__device__ __forceinline__ h8v zero8() {
    h8v z;
#pragma unroll
    for (int i = 0; i < 8; ++i) z[i] = (_Float16)0.f;
    return z;
}
__device__ __forceinline__ h8v shfl_xor_h8(h8v v, int m) {
    union { h8v h; int4 i; } u; u.h = v;
    u.i.x = __shfl_xor(u.i.x, m, 64);
    u.i.y = __shfl_xor(u.i.y, m, 64);
    u.i.z = __shfl_xor(u.i.z, m, 64);
    u.i.w = __shfl_xor(u.i.w, m, 64);
    return u.h;
}

// L1: fused prelude — vm16 compress | fin matmul (raw fp16 + stats partials) | pf
__global__ __launch_bounds__(256) void k_pre(
    const int* __restrict__ vm, const float* __restrict__ features,
    const float* __restrict__ Win, const float* __restrict__ Wpos,
    const float* __restrict__ g_pos, const float* __restrict__ b_pos,
    short* __restrict__ vm16, _Float16* __restrict__ fraw_h,
    float* __restrict__ pIn, float* __restrict__ pf)
{
    __shared__ float smem[2688];
    int bid = blockIdx.x, t = threadIdx.x;

    if (bid < NB_VM) {                       // ---- vm -> int16 (8 ints/thread)
        int i = bid * 256 + t;
        if (i < NVOX / 8) {
            int4 v0 = ((const int4*)vm)[i * 2];
            int4 v1 = ((const int4*)vm)[i * 2 + 1];
            uint4 o;
            o.x = (v0.x & 0xffff) | (v0.y << 16);
            o.y = (v0.z & 0xffff) | (v0.w << 16);
            o.z = (v1.x & 0xffff) | (v1.y << 16);
            o.w = (v1.z & 0xffff) | (v1.w << 16);
            ((uint4*)vm16)[i] = o;
        }
        return;
    }
    if (bid < NB_VM + 512) {                 // ---- fin: raw y fp16 + partials
        int b2 = bid - NB_VM;
        int k = b2 >> 8, bx = b2 & 255;
        float* Wls = smem;                   // [32][68]
        float* s_  = smem + 2176;
        float* q_  = smem + 2432;
        for (int idx = t; idx < 2048; idx += 256)
            Wls[(idx >> 6) * 68 + (idx & 63)] = Win[k * 2048 + idx];
        __syncthreads();
        int c = t & 31, g = t >> 5;
        float w[64];
#pragma unroll
        for (int i4 = 0; i4 < 16; ++i4) {
            float4 wv = *(const float4*)&Wls[c * 68 + i4 * 4];
            w[i4 * 4] = wv.x; w[i4 * 4 + 1] = wv.y; w[i4 * 4 + 2] = wv.z; w[i4 * 4 + 3] = wv.w;
        }
        int base = bx * 64;
        float ssum = 0.f, ssq = 0.f;
        for (int it = 0; it < 8; ++it) {
            int pt = base + it * 8 + g;
            const float4* fr = (const float4*)(features + (size_t)pt * 64);
            float y = 0.f;
#pragma unroll
            for (int i4 = 0; i4 < 16; ++i4) {
                float4 v = fr[i4];
                y += v.x * w[i4 * 4] + v.y * w[i4 * 4 + 1] + v.z * w[i4 * 4 + 2] + v.w * w[i4 * 4 + 3];
            }
            fraw_h[((size_t)k * (NPTS + 1) + pt + 1) * 32 + c] = (_Float16)y;
            ssum += y; ssq += y * y;
        }
        s_[t] = ssum; q_[t] = ssq;
        __syncthreads();
        if (t < 32) {
            float fs = 0.f, fq = 0.f;
#pragma unroll
            for (int gg = 0; gg < 8; ++gg) { fs += s_[gg * 32 + t]; fq += q_[gg * 32 + t]; }
            float* pb = pIn + ((size_t)k * 256 + bx) * 64;
            pb[t] = fs; pb[32 + t] = fq;
        }
        return;
    }
    // ---- pf: BN over offsets of off_xyz @ W_pos^T (f32, 1 block)
    float* praw = smem;
    int pfoff = 0;
    for (int k = 0; k < 2; ++k) {
        int r = k + 1, s = 2 * r, noff = s * s * s;
        for (int idx = t; idx < noff * 32; idx += 256) {
            int j = idx >> 5, c = idx & 31;
            int xi = j % s, yi = (j / s) % s, zi = j / (s * s);
            const float* W = Wpos + (k * 32 + c) * 3;
            praw[idx] = (float)(xi - r) * W[0] + (float)(yi - r) * W[1] + (float)(zi - r) * W[2];
        }
        __syncthreads();
        if (t < 32) {
            float sum = 0.f, sq = 0.f;
            for (int j = 0; j < noff; ++j) { float v = praw[j * 32 + t]; sum += v; sq += v * v; }
            float mu  = sum / (float)noff;
            float var = fmaxf(sq / (float)noff - mu * mu, 0.f);
            float rs  = rsqrtf(var + EPSV);
            float g = g_pos[k * 32 + t], b = b_pos[k * 32 + t];
            for (int j = 0; j < noff; ++j)
                pf[pfoff + j * 32 + t] = (praw[j * 32 + t] - mu) * rs * g + b;
        }
        __syncthreads();
        pfoff += noff * 32;
    }
}

// L2: parallel reduce pIn -> scale/shift ; one block per (k, c)
__global__ __launch_bounds__(256) void k_reduce_in(
    const float* __restrict__ pIn, const float* __restrict__ g_in,
    const float* __restrict__ b_in, float* __restrict__ ss_in,
    _Float16* __restrict__ fraw_h)
{
    __shared__ float ss[256], qq[256];
    int b = blockIdx.x;          // 64 blocks: k = b>>5, c = b&31
    int k = b >> 5, c = b & 31;
    int t = threadIdx.x;
    ss[t] = pIn[((size_t)k * 256 + t) * 64 + c];
    qq[t] = pIn[((size_t)k * 256 + t) * 64 + 32 + c];
    __syncthreads();
    if (t < 128) { ss[t] += ss[t + 128]; qq[t] += qq[t + 128]; } __syncthreads();
    if (t < 64)  { ss[t] += ss[t + 64];  qq[t] += qq[t + 64];  } __syncthreads();
    if (t < 32)  { ss[t] += ss[t + 32];  qq[t] += qq[t + 32];  } __syncthreads();
    if (t == 0) {
        float sv = 0.f, sq = 0.f;
#pragma unroll
        for (int i = 0; i < 32; ++i) { sv += ss[i]; sq += qq[i]; }
        float mu  = sv / (float)NPTS;
        float var = fmaxf(sq / (float)NPTS - mu * mu, 0.f);
        float rs  = rsqrtf(var + EPSV);
        float scale = g_in[k * 32 + c] * rs;
        float shift = b_in[k * 32 + c] - mu * scale;
        ss_in[k * 64 + c]      = scale;
        ss_in[k * 64 + 32 + c] = shift;
        float pad = (scale != 0.f) ? (-shift / scale) : 0.f;
        pad = fminf(fmaxf(pad, -60000.f), 60000.f);
        fraw_h[(size_t)k * (NPTS + 1) * 32 + c] = (_Float16)pad;   // row 0
    }
}

// L3: LEAN gather (BOTH k) + relu-max ONLY. Stats moved to k_out_stats.
// 256 threads = 16 points x (4 jg x 4 chan-chunks). Packed vm loads (5/lane).
// LDS = 5.8 KB (psum only) -> max occupancy; minimal instruction overhead
// competing with the L1 gather stream.
__global__ __launch_bounds__(256) void k_gather(
    const int* __restrict__ nc, const short* __restrict__ vm16,
    const _Float16* __restrict__ fraw_h, const float* __restrict__ pf,
    const float* __restrict__ ss_in, _Float16* __restrict__ nf_h)
{
    __shared__ __align__(16) _Float16 psum1[64 * 40];   // stride 40: conflict-free
    __shared__ __align__(16) _Float16 psum0[8 * 40];
    int t = threadIdx.x, bx = blockIdx.x;
    int c4 = t & 3, jg = (t >> 2) & 3, lp = t >> 4;
    int pt = bx * 16 + lp;

    // ---- coords + packed vm addresses (consume cc BEFORE any asm load)
    int4 cc = ((const int4*)nc)[pt];
    int bb = cc.x, xc = cc.y, yc = cc.z, zc = cc.w;
    // reference quirk: fastest mesh idx -> z coord, slowest -> x coord
    int Zo[4];
#pragma unroll
    for (int u = 0; u < 4; ++u) {
        int zq = min(max(zc + u - 2, 0), ZD - 1);
        Zo[u] = (bb * ZD + zq) * (YD * XD);
    }
    int Yo1 = min(max(yc + jg - 2, 0), YD - 1) * XD;
    int ax1 = (min(max(xc - 2, 0), XD - 4)) & ~1;       // pack base (even)
    int Xoff[4];
#pragma unroll
    for (int a = 0; a < 4; ++a)
        Xoff[a] = min(max(xc - 2 + a, 0), XD - 1) - ax1;   // in [0,4]
    int zq0 = min(max(zc + (jg & 1) - 1, 0), ZD - 1);
    int yo0 = min(max(yc + (jg >> 1) - 1, 0), YD - 1) * XD;
    int zo0 = (bb * ZD + zq0) * (YD * XD);
    int x0a = min(max(xc - 1, 0), XD - 1);
    int x0b = min(max(xc, 0), XD - 1);
    int ax0 = x0a & ~1;
    int X0a = x0a - ax0, X0b = x0b - ax0;               // in [0,2]
    __builtin_amdgcn_sched_barrier(0);

    // ---- phase A: 5 packed vm loads in flight (latency hides under staging)
    uint4 pk[4];
#pragma unroll
    for (int u = 0; u < 4; ++u)
        pk[u] = gload_u128(vm16 + Zo[u] + Yo1 + ax1);
    uint2 pk0 = gload_u64(vm16 + zo0 + yo0 + ax0);

    // ---- LDS staging (independent of phase A)
    for (int i = t; i < 2048; i += 256) {
        int o = i >> 5, ch = i & 31;
        psum1[o * 40 + ch] = (_Float16)(pf[256 + i] + ss_in[96 + ch]);
    }
    {
        int o = t >> 5, ch = t & 31;
        psum0[o * 40 + ch] = (_Float16)(pf[t] + ss_in[32 + ch]);
    }
    __syncthreads();
    vm_wait0();                          // packs ready

    // ---- phase B: extract pidx from packs, issue 18 row gathers
    const _Float16* fr1 = fraw_h + (size_t)(NPTS + 1) * 32;
    h8v g1[16], g0[2];
#pragma unroll
    for (int u = 0; u < 4; ++u) {
        unsigned long long lo = (unsigned long long)pk[u].x | ((unsigned long long)pk[u].y << 32);
        unsigned long long hi = (unsigned long long)pk[u].z | ((unsigned long long)pk[u].w << 32);
#pragma unroll
        for (int a = 0; a < 4; ++a) {
            int off = Xoff[a];
            unsigned long long sel = (off & 4) ? hi : lo;
            unsigned row = ((unsigned)(sel >> ((off & 3) * 16)) + 1) & 0xFFFFu;  // -1 -> pad row 0
            g1[u * 4 + a] = gload_h8(fr1 + (size_t)row * 32 + c4 * 8);
        }
    }
    {
        unsigned long long l0 = (unsigned long long)pk0.x | ((unsigned long long)pk0.y << 32);
        unsigned r0 = ((unsigned)(l0 >> (X0a * 16)) + 1) & 0xFFFFu;
        unsigned r1 = ((unsigned)(l0 >> (X0b * 16)) + 1) & 0xFFFFu;
        g0[0] = gload_h8(fraw_h + (size_t)r0 * 32 + c4 * 8);
        g0[1] = gload_h8(fraw_h + (size_t)r1 * 32 + c4 * 8);
    }
    vm_wait0();                          // rows ready

    // ---- phase C: scale + add(psum) + relu-max (relu folds into max)
    h8v sc1v, sc0v;
#pragma unroll
    for (int i = 0; i < 8; ++i) {
        sc1v[i] = (_Float16)ss_in[64 + c4 * 8 + i];
        sc0v[i] = (_Float16)ss_in[c4 * 8 + i];
    }
    h8v acc1 = zero8(), acc0 = zero8();
#pragma unroll
    for (int i = 0; i < 16; ++i) {
        int o = (i & 3) * 16 + jg * 4 + (i >> 2);
        h8v pv = *(const h8v*)(psum1 + o * 40 + c4 * 8);
        acc1 = __builtin_elementwise_max(acc1, g1[i] * sc1v + pv);
    }
    {
        h8v pv = *(const h8v*)(psum0 + jg * 40 + c4 * 8);
        acc0 = __builtin_elementwise_max(acc0, g0[0] * sc0v + pv);
        h8v pv2 = *(const h8v*)(psum0 + (4 + jg) * 40 + c4 * 8);
        acc0 = __builtin_elementwise_max(acc0, g0[1] * sc0v + pv2);
    }
    acc1 = __builtin_elementwise_max(acc1, shfl_xor_h8(acc1, 4));
    acc1 = __builtin_elementwise_max(acc1, shfl_xor_h8(acc1, 8));
    acc0 = __builtin_elementwise_max(acc0, shfl_xor_h8(acc0, 4));
    acc0 = __builtin_elementwise_max(acc0, shfl_xor_h8(acc0, 8));
    if (jg == 0) {
        *(h8v*)(nf_h + ((size_t)MGRID + pt) * 32 + c4 * 8) = acc1;   // k=1
        *(h8v*)(nf_h + (size_t)pt * 32 + c4 * 8) = acc0;             // k=0
    }
}

// L4: out-matmul stats partials; 128 points/block, grid (512, 2)
__global__ __launch_bounds__(256) void k_out_stats(
    const _Float16* __restrict__ nf_h, const float* __restrict__ Wout,
    float* __restrict__ pOut)
{
    __shared__ __align__(16) _Float16 nfs[128 * 32];   // 8 KB
    __shared__ h2 Wh[64 * 17];                          // 4.3 KB
    __shared__ float s_[256], q_[256];
    int k = blockIdx.y, t = threadIdx.x, bx = blockIdx.x;
    const _Float16* src = nf_h + ((size_t)k * MGRID + (size_t)bx * 128) * 32;
    ((uint4*)nfs)[t]       = ((const uint4*)src)[t];
    ((uint4*)nfs)[256 + t] = ((const uint4*)src)[256 + t];
    for (int i = t; i < 1024; i += 256) {
        int c = i >> 4, q = i & 15;
        h2 v;
        v.x = (_Float16)Wout[k * 2048 + c * 32 + 2 * q];
        v.y = (_Float16)Wout[k * 2048 + c * 32 + 2 * q + 1];
        Wh[c * 17 + q] = v;
    }
    __syncthreads();
    int c = t & 63, pg = t >> 6;
    h2 w[16];
#pragma unroll
    for (int i = 0; i < 16; ++i) w[i] = Wh[c * 17 + i];
    float sum = 0.f, sq = 0.f;
    for (int i = 0; i < 32; ++i) {
        const h2* row = (const h2*)(nfs + (pg * 32 + i) * 32);
        float y = 0.f;
#pragma unroll
        for (int iq = 0; iq < 16; ++iq) y = FDOT2(row[iq], w[iq], y);
        sum += y; sq += y * y;
    }
    s_[t] = sum; q_[t] = sq;
    __syncthreads();
    if (t < 128) { s_[t] += s_[t + 128]; q_[t] += q_[t + 128]; }
    __syncthreads();
    if (t < 64) {
        pOut[((size_t)k * 512 + bx) * 128 + t]      = s_[t] + s_[t + 64];
        pOut[((size_t)k * 512 + bx) * 128 + 64 + t] = q_[t] + q_[t + 64];
    }
}

// L5: parallel reduce pOut -> scale/shift ; one block per (k, c)
__global__ __launch_bounds__(256) void k_out_reduce(
    const float* __restrict__ pOut, const float* __restrict__ g_out,
    const float* __restrict__ b_out, float* __restrict__ ss_out)
{
    __shared__ float ss[256], qq[256];
    int b = blockIdx.x;          // 128 blocks: k = b>>6, c = b&63
    int k = b >> 6, c = b & 63;
    int t = threadIdx.x;
    float sv = 0.f, sq = 0.f;
#pragma unroll
    for (int i = 0; i < 2; ++i) {
        size_t row = (size_t)k * 512 + t + i * 256;
        sv += pOut[row * 128 + c];
        sq += pOut[row * 128 + 64 + c];
    }
    ss[t] = sv; qq[t] = sq;
    __syncthreads();
    if (t < 128) { ss[t] += ss[t + 128]; qq[t] += qq[t + 128]; } __syncthreads();
    if (t < 64)  { ss[t] += ss[t + 64];  qq[t] += qq[t + 64];  } __syncthreads();
    if (t < 32)  { ss[t] += ss[t + 32];  qq[t] += qq[t + 32];  } __syncthreads();
    if (t == 0) {
        float fs = 0.f, fq = 0.f;
#pragma unroll
        for (int i = 0; i < 32; ++i) { fs += ss[i]; fq += qq[i]; }
        float mu  = fs / (float)MGRID;
        float var = fmaxf(fq / (float)MGRID - mu * mu, 0.f);
        float rs  = rsqrtf(var + EPSV);
        float scale = g_out[k * 64 + c] * rs;
        float shift = b_out[k * 64 + c] - mu * scale;
        ss_out[k * 128 + c]      = scale;
        ss_out[k * 128 + 64 + c] = shift;
    }
}

// L6: out[:, k*64+c] = relu(y*scale + shift), dot2 matmul
__global__ __launch_bounds__(256) void k_out_write(
    const _Float16* __restrict__ nf_h, const float* __restrict__ Wout,
    const float* __restrict__ ss_out, float* __restrict__ out)
{
    __shared__ h2 Wh[64 * 17];
    int k = blockIdx.y, t = threadIdx.x;
    for (int i = t; i < 1024; i += 256) {
        int c = i >> 4, q = i & 15;
        h2 v;
        v.x = (_Float16)Wout[k * 2048 + c * 32 + 2 * q];
        v.y = (_Float16)Wout[k * 2048 + c * 32 + 2 * q + 1];
        Wh[c * 17 + q] = v;
    }
    __syncthreads();
    int c = t & 63, pl = t >> 6;
    float scale = ss_out[k * 128 + c], shift = ss_out[k * 128 + 64 + c];
    const h2* w = &Wh[c * 17];
    int base = blockIdx.x * 64;
    for (int it = 0; it < 16; ++it) {
        int pt = base + it * 4 + pl;
        const H8* row = (const H8*)(nf_h + ((size_t)k * MGRID + pt) * 32);
        H8 r0 = row[0], r1 = row[1], r2 = row[2], r3 = row[3];
        h2 hh[16] = {r0.a, r0.b, r0.c, r0.d, r1.a, r1.b, r1.c, r1.d,
                     r2.a, r2.b, r2.c, r2.d, r3.a, r3.b, r3.c, r3.d};
        float y = 0.f;
#pragma unroll
        for (int iq = 0; iq < 16; ++iq) y = FDOT2(hh[iq], w[iq], y);
        float o = y * scale + shift;
        out[(size_t)pt * 128 + k * 64 + c] = o > 0.f ? o : 0.f;
    }
}

extern "C" void kernel_launch(void* const* d_in, const int* in_sizes, int n_in,
                              void* d_out, int out_size, void* d_ws, size_t ws_size,
                              hipStream_t stream) {
    const int*   new_coords = (const int*)d_in[4];
    const float* features   = (const float*)d_in[5];
    const int*   vm         = (const int*)d_in[6];
    const float* W_in  = (const float*)d_in[7];
    const float* g_in  = (const float*)d_in[8];
    const float* b_in  = (const float*)d_in[9];
    const float* W_pos = (const float*)d_in[10];
    const float* g_pos = (const float*)d_in[11];
    const float* b_pos = (const float*)d_in[12];
    const float* W_out = (const float*)d_in[13];
    const float* g_out = (const float*)d_in[14];
    const float* b_out = (const float*)d_in[15];
    float* out = (float*)d_out;

    char* ws = (char*)d_ws;
    float*     ss_in  = (float*)(ws);
    float*     ss_out = (float*)(ws + 4096);
    float*     pIn    = (float*)(ws + 8192);
    _Float16*  fraw_h = (_Float16*)(ws + 139264);
    float*     pf     = (float*)(ws + 2236544);
    short*     vm16   = (short*)(ws + 2245760);
    _Float16*  nf_h   = (_Float16*)(ws + 3794560);
    float*     pOut   = (float*)(ws + 12183168);

    k_pre<<<NB_VM + 512 + 1, 256, 0, stream>>>(vm, features, W_in, W_pos, g_pos, b_pos,
                                               vm16, fraw_h, pIn, pf);
    k_reduce_in<<<64, 256, 0, stream>>>(pIn, g_in, b_in, ss_in, fraw_h);

    k_gather<<<MGRID / 16, 256, 0, stream>>>(new_coords, vm16, fraw_h, pf, ss_in, nf_h);

    dim3 gS(512, 2);
    k_out_stats<<<gS, 256, 0, stream>>>(nf_h, W_out, pOut);

    k_out_reduce<<<128, 256, 0, stream>>>(pOut, g_out, b_out, ss_out);

    dim3 gW(MGRID / 64, 2);
    k_out_write<<<gW, 256, 0, stream>>>(nf_h, W_out, ss_out, out);
}